// Round 2
// baseline (412.367 us; speedup 1.0000x reference)
//
#include <hip/hip_runtime.h>
#include <hip/hip_bf16.h>

#define N_NODES 50000
#define N_PER   12500
#define E_EDGES 600000
#define HDIM    128

#define NBLK_FC    ((N_PER + 63) / 64)            // 196
#define MASK31  0x7fffffff

// counting-sort tiling: zero device atomics anywhere.
#define HQ 32                    // edge slices
#define HP 4                     // node ranges (12500 nodes -> 50 KB LDS table)
#define HSLICE (E_EDGES / HQ)    // 18750 exactly
#define NBLK_SCAT (HQ * HP)      // 128 scatter blocks

typedef __attribute__((ext_vector_type(8))) short bfrag;   // 8 bf16 (4 VGPRs)
typedef __attribute__((ext_vector_type(4))) float ffrag;   // 4 fp32 acc

__device__ __forceinline__ unsigned short f2bf(float f) {
    union { float f; unsigned u; } x; x.f = f;
    unsigned r = x.u + 0x7fffu + ((x.u >> 16) & 1u);   // RTNE
    return (unsigned short)(r >> 16);
}
__device__ __forceinline__ float lo_bf(unsigned v) { return __uint_as_float(v << 16); }
__device__ __forceinline__ float hi_bf(unsigned v) { return __uint_as_float(v & 0xffff0000u); }
__device__ __forceinline__ unsigned pack2(float a, float b) {
    return (unsigned)f2bf(a) | ((unsigned)f2bf(b) << 16);
}
__device__ __forceinline__ float onrm_of(int deg) {
    return rsqrtf(fmaxf((float)deg, 1.0f));
}

__device__ __forceinline__ void acc8_add(float* acc, uint4 v) {
    acc[0] += lo_bf(v.x); acc[1] += hi_bf(v.x);
    acc[2] += lo_bf(v.y); acc[3] += hi_bf(v.y);
    acc[4] += lo_bf(v.z); acc[5] += hi_bf(v.z);
    acc[6] += lo_bf(v.w); acc[7] += hi_bf(v.w);
}
__device__ __forceinline__ void acc8_addw(float* acc, uint4 v, float w) {
    acc[0] += lo_bf(v.x) * w; acc[1] += hi_bf(v.x) * w;
    acc[2] += lo_bf(v.y) * w; acc[3] += hi_bf(v.y) * w;
    acc[4] += lo_bf(v.z) * w; acc[5] += hi_bf(v.z) * w;
    acc[6] += lo_bf(v.w) * w; acc[7] += hi_bf(v.w) * w;
}

// ---------------------------------------------------------------------------
// K0 prep: blocks [0,384): 3 tiled LDS histograms, uint16 partials:
//   which=0: src (deg_out, consumed by scale_kernel)
//   which=1: dst (fwd bucket placement + deg_in)
//   which=2: src where t in {6,14,30} (bwd bucket placement + degB)
// blocks [384,416): weight fragment packing. No init pass needed anymore.
// ---------------------------------------------------------------------------
__global__ __launch_bounds__(256) void prep_kernel(
    const float* __restrict__ W0, const float* __restrict__ W1,
    const float* __restrict__ W2, const float* __restrict__ W3,
    const float* __restrict__ Wg,
    const int* __restrict__ src, const int* __restrict__ dst,
    const int* __restrict__ ef,
    unsigned short* __restrict__ Wp,
    unsigned short* __restrict__ partialS,
    unsigned short* __restrict__ partialD,
    unsigned short* __restrict__ partialB) {
    __shared__ int hist[N_PER];                 // 50 KB
    int b = blockIdx.x;
    if (b < 3 * NBLK_SCAT) {
        const int which = b / NBLK_SCAT;
        const int r = b - which * NBLK_SCAT;
        const int q = r >> 2;                   // edge slice
        const int p = r & 3;                    // node range
        const int g0 = p * N_PER;
        for (int j = threadIdx.x; j < N_PER; j += 256) hist[j] = 0;
        __syncthreads();
        const int e0 = q * HSLICE;
        if (which == 0) {
            for (int i = e0 + threadIdx.x; i < e0 + HSLICE; i += 256) {
                unsigned rr = (unsigned)(src[i] - g0);
                if (rr < (unsigned)N_PER) atomicAdd(&hist[rr], 1);
            }
        } else if (which == 1) {
            for (int i = e0 + threadIdx.x; i < e0 + HSLICE; i += 256) {
                unsigned rr = (unsigned)(dst[i] - g0);
                if (rr < (unsigned)N_PER) atomicAdd(&hist[rr], 1);
            }
        } else {
            for (int i = e0 + threadIdx.x; i < e0 + HSLICE; i += 256) {
                int t = ef[i];
                if (t == 6 || t == 14 || t == 30) {
                    unsigned rr = (unsigned)(src[i] - g0);
                    if (rr < (unsigned)N_PER) atomicAdd(&hist[rr], 1);
                }
            }
        }
        __syncthreads();
        unsigned short* out =
            (which == 0 ? partialS : which == 1 ? partialD : partialB)
            + (size_t)q * N_NODES + g0;
        for (int j = threadIdx.x; j < N_PER; j += 256)
            out[j] = (unsigned short)hist[j];
    } else {
        int tid = (b - 3 * NBLK_SCAT) * 256 + threadIdx.x;
        const float* W; int D, base, off;
        if      (tid < 2048) { W = W0; D = 128; base = 0;    off = 0;     }
        else if (tid < 4096) { W = W1; D = 128; base = 2048; off = 16384; }
        else if (tid < 5120) { W = W2; D = 64;  base = 4096; off = 32768; }
        else if (tid < 6144) { W = W3; D = 64;  base = 5120; off = 40960; }
        else                 { W = Wg; D = 128; base = 6144; off = 49152; }
        int t2 = tid - base;
        int KT = D / 32;
        int l = t2 & 63;
        int tt = t2 >> 6;
        int kt = tt % KT, n0 = tt / KT;
        int n = n0 * 16 + (l & 15);
        int kb = kt * 32 + (l >> 4) * 8;
#pragma unroll
        for (int j = 0; j < 8; ++j)
            Wp[(size_t)off + (size_t)t2 * 8 + j] = f2bf(W[(size_t)(kb + j) * 128 + n]);
    }
}

// ---------------------------------------------------------------------------
// P1: per-node exclusive prefix over the 32 slice-planes (in place),
//     totals -> degD / degB. Fully coalesced (plane-major layout).
// ---------------------------------------------------------------------------
__global__ __launch_bounds__(256) void plane_prefix_kernel(
    unsigned short* __restrict__ partialD, unsigned short* __restrict__ partialB,
    int* __restrict__ degD, int* __restrict__ degB) {
    int n = blockIdx.x * 256 + threadIdx.x;
    if (n >= N_NODES) return;
    int run = 0;
#pragma unroll
    for (int q = 0; q < HQ; ++q) {
        size_t ix = (size_t)q * N_NODES + n;
        int c = partialD[ix];
        partialD[ix] = (unsigned short)run;
        run += c;
    }
    degD[n] = run;
    run = 0;
#pragma unroll
    for (int q = 0; q < HQ; ++q) {
        size_t ix = (size_t)q * N_NODES + n;
        int c = partialB[ix];
        partialB[ix] = (unsigned short)run;
        run += c;
    }
    degB[n] = run;
}

// ---------------------------------------------------------------------------
// P2: absolute CSR bases via single-block scans (block 0: fwd, block 1: bwd).
//     1024 threads, 49 nodes/thread, two-pass (second deg read is L2-hot).
// ---------------------------------------------------------------------------
__global__ __launch_bounds__(1024) void scan_kernel(
    const int* __restrict__ degD, int* __restrict__ scanD,
    const int* __restrict__ degB, int* __restrict__ scanB) {
    const int* deg = blockIdx.x ? degB : degD;
    int* sc = blockIdx.x ? scanB : scanD;
    __shared__ int part[1024];
    const int t = threadIdx.x;
    const int n0 = t * 49;                 // 49*1024 = 50176 >= 50000
    int s = 0;
    for (int i = 0; i < 49; ++i) {
        int n = n0 + i;
        s += (n < N_NODES) ? deg[n] : 0;
    }
    part[t] = s;
    __syncthreads();
    for (int off = 1; off < 1024; off <<= 1) {
        int x = (t >= off) ? part[t - off] : 0;
        __syncthreads();
        part[t] += x;
        __syncthreads();
    }
    int run = (t == 0) ? 0 : part[t - 1];
    for (int i = 0; i < 49; ++i) {
        int n = n0 + i;
        if (n < N_NODES) { sc[n] = run; run += deg[n]; }
    }
}

// ---------------------------------------------------------------------------
// FC MFMA body: out = bf16(X(rows x D) @ W + bias); X fp32.
// ---------------------------------------------------------------------------
template<int D>
__device__ __forceinline__ void fc_body(
    int blk, int tid,
    const float* __restrict__ X,
    const unsigned short* __restrict__ Wp,
    const float* __restrict__ bias,
    unsigned short* __restrict__ outbf,
    int rows)
{
    constexpr int KT = D / 32;
    const int lane = tid & 63;
    const int wave = tid >> 6;
    const int m = lane & 15, q = lane >> 4;
    const int rbase = blk * 64 + wave * 16;
    const int row = rbase + m;

    bfrag afr[KT];
#pragma unroll
    for (int kt = 0; kt < KT; ++kt) {
        bfrag a;
        if (row < rows) {
            const float* xp = X + (size_t)row * D + kt * 32 + q * 8;
            float4 u0 = *(const float4*)xp;
            float4 u1 = *(const float4*)(xp + 4);
            a[0] = (short)f2bf(u0.x); a[1] = (short)f2bf(u0.y);
            a[2] = (short)f2bf(u0.z); a[3] = (short)f2bf(u0.w);
            a[4] = (short)f2bf(u1.x); a[5] = (short)f2bf(u1.y);
            a[6] = (short)f2bf(u1.z); a[7] = (short)f2bf(u1.w);
        } else {
#pragma unroll
            for (int t = 0; t < 8; ++t) a[t] = 0;
        }
        afr[kt] = a;
    }

    ffrag acc[8];
#pragma unroll
    for (int n0 = 0; n0 < 8; ++n0)
#pragma unroll
        for (int t = 0; t < 4; ++t) acc[n0][t] = 0.f;

#pragma unroll
    for (int n0 = 0; n0 < 8; ++n0)
#pragma unroll
        for (int kt = 0; kt < KT; ++kt) {
            bfrag bfr = *(const bfrag*)(Wp + ((size_t)(n0 * KT + kt) * 64 + lane) * 8);
            acc[n0] = __builtin_amdgcn_mfma_f32_16x16x32_bf16(afr[kt], bfr, acc[n0], 0, 0, 0);
        }

#pragma unroll
    for (int n0 = 0; n0 < 8; ++n0) {
        const int col = n0 * 16 + m;
        const float bj = bias[col];
#pragma unroll
        for (int r = 0; r < 4; ++r) {
            int orow = rbase + q * 4 + r;
            if (orow < rows)
                outbf[(size_t)orow * 128 + col] = f2bf(acc[n0][r] + bj);
        }
    }
}

// ---------------------------------------------------------------------------
// K1 mega-kernel: blocks [0,128): counting-sort scatter (LDS atomics only,
// deterministic CSR slots, ZERO device atomics) + blocks [128,912): FC GEMMs.
// ---------------------------------------------------------------------------
__global__ __launch_bounds__(256) void mega_kernel(
    const int* __restrict__ src, const int* __restrict__ dst,
    const int* __restrict__ ef,
    const unsigned short* __restrict__ prefD,
    const unsigned short* __restrict__ prefB,
    const int* __restrict__ scanD, const int* __restrict__ scanB,
    int* __restrict__ bucket, int* __restrict__ bucketB,
    const float* __restrict__ f0, const float* __restrict__ f1,
    const float* __restrict__ f2, const float* __restrict__ f3,
    const unsigned short* __restrict__ Wp,
    const float* __restrict__ b0, const float* __restrict__ b1,
    const float* __restrict__ b2, const float* __restrict__ b3,
    unsigned short* __restrict__ Abf)
{
    __shared__ int offD[N_PER];        // absolute fwd slot per in-range node
    __shared__ int offB[N_PER / 2];    // 2 nodes/int (abs bwd slot < 65536)
    const int b = blockIdx.x;
    if (b < NBLK_SCAT) {
        const int q = b >> 2;
        const int p = b & 3;
        const int g0 = p * N_PER;
        for (int j = threadIdx.x; j < N_PER; j += 256)
            offD[j] = scanD[g0 + j] + (int)prefD[(size_t)q * N_NODES + g0 + j];
        for (int w = threadIdx.x; w < N_PER / 2; w += 256) {
            int lo = scanB[g0 + 2 * w]     + (int)prefB[(size_t)q * N_NODES + g0 + 2 * w];
            int hi = scanB[g0 + 2 * w + 1] + (int)prefB[(size_t)q * N_NODES + g0 + 2 * w + 1];
            offB[w] = lo | (hi << 16);
        }
        __syncthreads();
        const int e0 = q * HSLICE;
        for (int i = e0 + threadIdx.x; i < e0 + HSLICE; i += 256) {
            int s = src[i], d = dst[i], t = ef[i];
            unsigned rd = (unsigned)(d - g0);
            if (rd < (unsigned)N_PER) {
                int slot = atomicAdd(&offD[rd], 1);               // LDS atomic
                bucket[slot] = s | ((t <= 4) ? 0x80000000 : 0);
            }
            if (t == 6 || t == 14 || t == 30) {
                unsigned rs = (unsigned)(s - g0);
                if (rs < (unsigned)N_PER) {
                    unsigned inc = (rs & 1) ? 0x10000u : 1u;
                    unsigned old = atomicAdd((unsigned*)&offB[rs >> 1], inc);
                    int slot = (rs & 1) ? (int)(old >> 16) : (int)(old & 0xFFFFu);
                    bucketB[slot] = d;
                }
            }
        }
    } else {
        int fb = b - NBLK_SCAT;
        int which = fb / NBLK_FC;
        int blk = fb - which * NBLK_FC;
        if (which == 0)
            fc_body<128>(blk, threadIdx.x, f0, Wp,         b0, Abf + (size_t)0 * N_PER * HDIM, N_PER);
        else if (which == 1)
            fc_body<128>(blk, threadIdx.x, f1, Wp + 16384, b1, Abf + (size_t)1 * N_PER * HDIM, N_PER);
        else if (which == 2)
            fc_body<64>(blk, threadIdx.x, f2, Wp + 32768, b2, Abf + (size_t)2 * N_PER * HDIM, N_PER);
        else
            fc_body<64>(blk, threadIdx.x, f3, Wp + 40960, b3, Abf + (size_t)3 * N_PER * HDIM, N_PER);
    }
}

// ---------------------------------------------------------------------------
// K2: deg_out[n] = sum of 32 uint16 partials; A[n] *= onrm(deg_out[n]);
//     caches onrm in onrm_buf for K3.
// ---------------------------------------------------------------------------
__global__ __launch_bounds__(256) void scale_kernel(
    uint4* __restrict__ A, const unsigned short* __restrict__ partialS,
    float* __restrict__ onrm_buf) {
    int idx = blockIdx.x * blockDim.x + threadIdx.x;
    int n = idx >> 4, j8 = idx & 15;
    int d = (int)partialS[(size_t)j8 * N_NODES + n]
          + (int)partialS[(size_t)(j8 + 16) * N_NODES + n];
    d += __shfl_xor(d, 1);
    d += __shfl_xor(d, 2);
    d += __shfl_xor(d, 4);
    d += __shfl_xor(d, 8);
    float on = onrm_of(d);
    if (j8 == 0) onrm_buf[n] = on;
    uint4 v = A[(size_t)n * 16 + j8];
    uint4 o;
    o.x = pack2(lo_bf(v.x) * on, hi_bf(v.x) * on);
    o.y = pack2(lo_bf(v.y) * on, hi_bf(v.y) * on);
    o.z = pack2(lo_bf(v.z) * on, hi_bf(v.z) * on);
    o.w = pack2(lo_bf(v.w) * on, hi_bf(v.w) * on);
    A[(size_t)n * 16 + j8] = o;
}

// ---------------------------------------------------------------------------
// K3: layer-0 gather from dense CSR (A pre-scaled), unroll-4.
//   B[n] = bf16( relu( (sum A[s]) * inrm(n) + b_g0 ) * onrm(n) )
// ---------------------------------------------------------------------------
__global__ __launch_bounds__(256) void agg0_kernel(
    const uint4* __restrict__ A,
    const int* __restrict__ bucket, const int* __restrict__ scanD,
    const int* __restrict__ degD,
    const float* __restrict__ onrm_buf, const float* __restrict__ b_g0,
    uint4* __restrict__ B) {
    int idx = blockIdx.x * blockDim.x + threadIdx.x;
    int n = idx >> 4, j8 = idx & 15;
    const int cnt = degD[n];
    const int* bk = bucket + scanD[n];
    float acc[8] = {0.f, 0.f, 0.f, 0.f, 0.f, 0.f, 0.f, 0.f};
    int i = 0;
    for (; i + 4 <= cnt; i += 4) {
        int s0 = bk[i] & MASK31,     s1 = bk[i + 1] & MASK31;
        int s2 = bk[i + 2] & MASK31, s3 = bk[i + 3] & MASK31;
        uint4 v0 = A[(size_t)s0 * 16 + j8];
        uint4 v1 = A[(size_t)s1 * 16 + j8];
        uint4 v2 = A[(size_t)s2 * 16 + j8];
        uint4 v3 = A[(size_t)s3 * 16 + j8];
        acc8_add(acc, v0); acc8_add(acc, v1);
        acc8_add(acc, v2); acc8_add(acc, v3);
    }
    for (; i < cnt; ++i) {
        int s = bk[i] & MASK31;
        acc8_add(acc, A[(size_t)s * 16 + j8]);
    }
    float inr = onrm_of(cnt);
    float onr = onrm_buf[n];
    const float* bg = b_g0 + j8 * 8;
    float r[8];
#pragma unroll
    for (int k = 0; k < 8; ++k)
        r[k] = fmaxf(acc[k] * inr + bg[k], 0.f) * onr;
    uint4 o;
    o.x = pack2(r[0], r[1]); o.y = pack2(r[2], r[3]);
    o.z = pack2(r[4], r[5]); o.w = pack2(r[6], r[7]);
    B[(size_t)n * 16 + j8] = o;
}

// ---------------------------------------------------------------------------
// K4: fused layer-1 gather (dense CSR, unroll-2) + MFMA GEMM.
// ---------------------------------------------------------------------------
__global__ __launch_bounds__(256) void gemm1_fused_kernel(
    const unsigned short* __restrict__ Bbf,
    const int* __restrict__ bucket, const int* __restrict__ scanD,
    const int* __restrict__ degD,
    const unsigned short* __restrict__ Wp, const float* __restrict__ bias,
    unsigned short* __restrict__ outbf)
{
    const int lane = threadIdx.x & 63;
    const int wave = threadIdx.x >> 6;
    const int m = lane & 15, q = lane >> 4;
    const int rbase = blockIdx.x * 64 + wave * 16;
    const int node = rbase + m;

    float ga[32];
#pragma unroll
    for (int i = 0; i < 32; ++i) ga[i] = 0.f;

    if (node < N_NODES) {
        const int cnt = degD[node];
        const int* bk = bucket + scanD[node];
        int i = 0;
        for (; i + 2 <= cnt; i += 2) {
            int s0 = bk[i] & MASK31, s1 = bk[i + 1] & MASK31;
            const uint4* r0 = (const uint4*)(Bbf + (size_t)s0 * 128);
            const uint4* r1 = (const uint4*)(Bbf + (size_t)s1 * 128);
            uint4 a0 = r0[0 * 4 + q], a1 = r0[1 * 4 + q], a2 = r0[2 * 4 + q], a3 = r0[3 * 4 + q];
            uint4 c0 = r1[0 * 4 + q], c1 = r1[1 * 4 + q], c2 = r1[2 * 4 + q], c3 = r1[3 * 4 + q];
            acc8_add(ga +  0, a0); acc8_add(ga +  8, a1);
            acc8_add(ga + 16, a2); acc8_add(ga + 24, a3);
            acc8_add(ga +  0, c0); acc8_add(ga +  8, c1);
            acc8_add(ga + 16, c2); acc8_add(ga + 24, c3);
        }
        for (; i < cnt; ++i) {
            int s = bk[i] & MASK31;
            const uint4* rp = (const uint4*)(Bbf + (size_t)s * 128);
#pragma unroll
            for (int kt = 0; kt < 4; ++kt) acc8_add(ga + kt * 8, rp[kt * 4 + q]);
        }
    }

    bfrag afr[4];
#pragma unroll
    for (int kt = 0; kt < 4; ++kt)
#pragma unroll
        for (int j = 0; j < 8; ++j)
            afr[kt][j] = (short)f2bf(ga[kt * 8 + j]);

    ffrag acc[8];
#pragma unroll
    for (int n0 = 0; n0 < 8; ++n0)
#pragma unroll
        for (int t = 0; t < 4; ++t) acc[n0][t] = 0.f;

#pragma unroll
    for (int n0 = 0; n0 < 8; ++n0)
#pragma unroll
        for (int kt = 0; kt < 4; ++kt) {
            bfrag bfr = *(const bfrag*)(Wp + ((size_t)(n0 * 4 + kt) * 64 + lane) * 8);
            acc[n0] = __builtin_amdgcn_mfma_f32_16x16x32_bf16(afr[kt], bfr, acc[n0], 0, 0, 0);
        }

    float ir[4];
#pragma unroll
    for (int r = 0; r < 4; ++r) {
        int orow = rbase + q * 4 + r;
        ir[r] = (orow < N_NODES) ? onrm_of(degD[orow]) : 0.f;
    }
#pragma unroll
    for (int n0 = 0; n0 < 8; ++n0) {
        const int col = n0 * 16 + m;
        const float bj = bias[col];
#pragma unroll
        for (int r = 0; r < 4; ++r) {
            int orow = rbase + q * 4 + r;
            if (orow < N_NODES)
                outbf[(size_t)orow * 128 + col] = f2bf(fmaxf(acc[n0][r] * ir[r] + bj, 0.f));
        }
    }
}

// ---------------------------------------------------------------------------
// K5: final edge-typed gather (dense CSR fwd + bwd) -> fp32 out.
// ---------------------------------------------------------------------------
__global__ __launch_bounds__(256) void final_kernel(
    const uint4* __restrict__ H,
    const int* __restrict__ bucket, const int* __restrict__ scanD,
    const int* __restrict__ degD,
    const int* __restrict__ bucketB, const int* __restrict__ scanB,
    const int* __restrict__ degB,
    float4* __restrict__ out4) {
    int idx = blockIdx.x * blockDim.x + threadIdx.x;
    int n = idx >> 4, j8 = idx & 15;
    float acc[8] = {0.f, 0.f, 0.f, 0.f, 0.f, 0.f, 0.f, 0.f};
    const int cnt = degD[n];
    const int* bk = bucket + scanD[n];
    int i = 0;
    for (; i + 4 <= cnt; i += 4) {
        int c0 = bk[i], c1 = bk[i + 1], c2 = bk[i + 2], c3 = bk[i + 3];
        uint4 v0 = H[(size_t)(c0 & MASK31) * 16 + j8];
        uint4 v1 = H[(size_t)(c1 & MASK31) * 16 + j8];
        uint4 v2 = H[(size_t)(c2 & MASK31) * 16 + j8];
        uint4 v3 = H[(size_t)(c3 & MASK31) * 16 + j8];
        acc8_addw(acc, v0, (c0 < 0) ? 2.0f : 1.0f);
        acc8_addw(acc, v1, (c1 < 0) ? 2.0f : 1.0f);
        acc8_addw(acc, v2, (c2 < 0) ? 2.0f : 1.0f);
        acc8_addw(acc, v3, (c3 < 0) ? 2.0f : 1.0f);
    }
    for (; i < cnt; ++i) {
        int c = bk[i];
        acc8_addw(acc, H[(size_t)(c & MASK31) * 16 + j8], (c < 0) ? 2.0f : 1.0f);
    }
    const int cb = degB[n];
    const int* bkB = bucketB + scanB[n];
    for (int k = 0; k < cb; ++k) {
        int d = bkB[k];
        acc8_add(acc, H[(size_t)d * 16 + j8]);
    }
    float4 o0 = {acc[0], acc[1], acc[2], acc[3]};
    float4 o1 = {acc[4], acc[5], acc[6], acc[7]};
    out4[(size_t)n * 32 + j8 * 2]     = o0;
    out4[(size_t)n * 32 + j8 * 2 + 1] = o1;
}

extern "C" void kernel_launch(void* const* d_in, const int* in_sizes, int n_in,
                              void* d_out, int out_size, void* d_ws, size_t ws_size,
                              hipStream_t stream) {
    const float* feat[4]  = {(const float*)d_in[0], (const float*)d_in[3],
                             (const float*)d_in[6], (const float*)d_in[9]};
    const float* W_fc[4]  = {(const float*)d_in[1], (const float*)d_in[4],
                             (const float*)d_in[7], (const float*)d_in[10]};
    const float* b_fc[4]  = {(const float*)d_in[2], (const float*)d_in[5],
                             (const float*)d_in[8], (const float*)d_in[11]};
    const int*   src      = (const int*)d_in[12];
    const int*   dst      = (const int*)d_in[13];
    const int*   efeat    = (const int*)d_in[14];
    const float* b_g0     = (const float*)d_in[15];
    const float* W_g1     = (const float*)d_in[16];
    const float* b_g1     = (const float*)d_in[17];
    float* out = (float*)d_out;

    // ---- workspace layout, ~41 MB ----
    char* p = (char*)d_ws;
    unsigned short* Abf = (unsigned short*)p; p += (size_t)N_NODES * HDIM * 2;  // 12.8 MB
    unsigned short* Bbf = (unsigned short*)p; p += (size_t)N_NODES * HDIM * 2;  // 12.8 MB
    unsigned short* Wp  = (unsigned short*)p; p += (size_t)65536 * 2;           // 128 KB
    int* bucket  = (int*)p; p += (size_t)E_EDGES * 4;            // 2.4 MB (dense CSR)
    int* bucketB = (int*)p; p += (size_t)E_EDGES * 4;            // 2.4 MB (dense CSR)
    unsigned short* partialS = (unsigned short*)p; p += (size_t)HQ * N_NODES * 2; // 3.2 MB
    unsigned short* partialD = (unsigned short*)p; p += (size_t)HQ * N_NODES * 2; // 3.2 MB
    unsigned short* partialB = (unsigned short*)p; p += (size_t)HQ * N_NODES * 2; // 3.2 MB
    int* degD  = (int*)p; p += (size_t)N_NODES * 4;              // 200 KB
    int* degB  = (int*)p; p += (size_t)N_NODES * 4;
    int* scanD = (int*)p; p += (size_t)N_NODES * 4;
    int* scanB = (int*)p; p += (size_t)N_NODES * 4;
    float* onrm_buf = (float*)p; p += (size_t)N_NODES * 4;

    const unsigned short* Wpg = Wp + 49152;

    // K0: 3 histograms + weight packing (no init pass, no device atomics)
    prep_kernel<<<3 * NBLK_SCAT + 32, 256, 0, stream>>>(
        W_fc[0], W_fc[1], W_fc[2], W_fc[3], W_g1, src, dst, efeat,
        Wp, partialS, partialD, partialB);

    // P1: per-node prefix over slice planes -> degD/degB
    plane_prefix_kernel<<<(N_NODES + 255) / 256, 256, 0, stream>>>(
        partialD, partialB, degD, degB);

    // P2: absolute CSR bases
    scan_kernel<<<2, 1024, 0, stream>>>(degD, scanD, degB, scanB);

    // K1: counting-sort scatter (LDS atomics only) + 4 FC GEMMs
    mega_kernel<<<NBLK_SCAT + 4 * NBLK_FC, 256, 0, stream>>>(
        src, dst, efeat, partialD, partialB, scanD, scanB, bucket, bucketB,
        feat[0], feat[1], feat[2], feat[3], Wp,
        b_fc[0], b_fc[1], b_fc[2], b_fc[3], Abf);

    const int grid_node = (N_NODES * 16) / 256;   // 3125 exact

    // K2: deg_out partial-sum + A *= onrm(deg_out), cache onrm for K3
    scale_kernel<<<grid_node, 256, 0, stream>>>((uint4*)Abf, partialS, onrm_buf);

    // K3: layer0 CSR gather
    agg0_kernel<<<grid_node, 256, 0, stream>>>(
        (const uint4*)Abf, bucket, scanD, degD, onrm_buf, b_g0, (uint4*)Bbf);

    // K4: fused layer1 CSR gather + GEMM
    gemm1_fused_kernel<<<(N_NODES + 63) / 64, 256, 0, stream>>>(
        Bbf, bucket, scanD, degD, Wpg, b_g1, Abf);

    // K5: final edge-typed CSR gather into fp32 d_out
    final_kernel<<<grid_node, 256, 0, stream>>>(
        (const uint4*)Abf, bucket, scanD, degD, bucketB, scanB, degB, (float4*)out);
}

// Round 4
// 320.461 us; speedup vs baseline: 1.2868x; 1.2868x over previous
//
#include <hip/hip_runtime.h>
#include <hip/hip_bf16.h>

#define N_NODES 50000
#define N_PER   12500
#define E_EDGES 600000
#define HDIM    128

#define NBLK_FC    ((N_PER + 63) / 64)            // 196
#define NBLK_NODE  ((N_NODES + 255) / 256)        // 196
#define MASK31  0x7fffffff

// counting-sort tiling: zero device atomics anywhere.
#define HQ 32                    // edge slices
#define HP 4                     // node ranges (12500 nodes -> 50 KB LDS table)
#define HSLICE (E_EDGES / HQ)    // 18750 exactly
#define NBLK_SCAT (HQ * HP)      // 128 scatter blocks

typedef __attribute__((ext_vector_type(8))) short bfrag;   // 8 bf16 (4 VGPRs)
typedef __attribute__((ext_vector_type(4))) float ffrag;   // 4 fp32 acc

__device__ __forceinline__ unsigned short f2bf(float f) {
    union { float f; unsigned u; } x; x.f = f;
    unsigned r = x.u + 0x7fffu + ((x.u >> 16) & 1u);   // RTNE
    return (unsigned short)(r >> 16);
}
__device__ __forceinline__ float lo_bf(unsigned v) { return __uint_as_float(v << 16); }
__device__ __forceinline__ float hi_bf(unsigned v) { return __uint_as_float(v & 0xffff0000u); }
__device__ __forceinline__ unsigned pack2(float a, float b) {
    return (unsigned)f2bf(a) | ((unsigned)f2bf(b) << 16);
}
__device__ __forceinline__ float onrm_of(int deg) {
    return rsqrtf(fmaxf((float)deg, 1.0f));
}

__device__ __forceinline__ void acc8_add(float* acc, uint4 v) {
    acc[0] += lo_bf(v.x); acc[1] += hi_bf(v.x);
    acc[2] += lo_bf(v.y); acc[3] += hi_bf(v.y);
    acc[4] += lo_bf(v.z); acc[5] += hi_bf(v.z);
    acc[6] += lo_bf(v.w); acc[7] += hi_bf(v.w);
}
__device__ __forceinline__ void acc8_addw(float* acc, uint4 v, float w) {
    acc[0] += lo_bf(v.x) * w; acc[1] += hi_bf(v.x) * w;
    acc[2] += lo_bf(v.y) * w; acc[3] += hi_bf(v.y) * w;
    acc[4] += lo_bf(v.z) * w; acc[5] += hi_bf(v.z) * w;
    acc[6] += lo_bf(v.w) * w; acc[7] += hi_bf(v.w) * w;
}

// ---------------------------------------------------------------------------
// K0 prep:
//   blocks [0,128):   packed histogram — dst counts (low16) | bwd-src (high16)
//   blocks [128,256): src histogram (deg_out -> partialS, raw counts)
//   blocks [256,288): weight fragment packing
// ---------------------------------------------------------------------------
__global__ __launch_bounds__(256) void prep_kernel(
    const float* __restrict__ W0, const float* __restrict__ W1,
    const float* __restrict__ W2, const float* __restrict__ W3,
    const float* __restrict__ Wg,
    const int* __restrict__ src, const int* __restrict__ dst,
    const int* __restrict__ ef,
    unsigned short* __restrict__ Wp,
    unsigned short* __restrict__ partialS,
    unsigned short* __restrict__ partialD,
    unsigned short* __restrict__ partialB) {
    __shared__ unsigned hist[N_PER];            // 50 KB
    int b = blockIdx.x;
    if (b < NBLK_SCAT) {                        // packed D|B histogram
        const int q = b >> 2;
        const int p = b & 3;
        const int g0 = p * N_PER;
        for (int j = threadIdx.x; j < N_PER; j += 256) hist[j] = 0;
        __syncthreads();
        const int e0 = q * HSLICE;
        for (int i = e0 + threadIdx.x; i < e0 + HSLICE; i += 256) {
            int d = dst[i], t = ef[i], s = src[i];
            unsigned rd = (unsigned)(d - g0);
            if (rd < (unsigned)N_PER) atomicAdd(&hist[rd], 1u);
            if (t == 6 || t == 14 || t == 30) {
                unsigned rs = (unsigned)(s - g0);
                if (rs < (unsigned)N_PER) atomicAdd(&hist[rs], 0x10000u);
            }
        }
        __syncthreads();
        for (int j = threadIdx.x; j < N_PER; j += 256) {
            unsigned h = hist[j];
            partialD[(size_t)q * N_NODES + g0 + j] = (unsigned short)(h & 0xffffu);
            partialB[(size_t)q * N_NODES + g0 + j] = (unsigned short)(h >> 16);
        }
    } else if (b < 2 * NBLK_SCAT) {             // src histogram (deg_out)
        const int r = b - NBLK_SCAT;
        const int q = r >> 2;
        const int p = r & 3;
        const int g0 = p * N_PER;
        for (int j = threadIdx.x; j < N_PER; j += 256) hist[j] = 0;
        __syncthreads();
        const int e0 = q * HSLICE;
        for (int i = e0 + threadIdx.x; i < e0 + HSLICE; i += 256) {
            unsigned rr = (unsigned)(src[i] - g0);
            if (rr < (unsigned)N_PER) atomicAdd(&hist[rr], 1u);
        }
        __syncthreads();
        for (int j = threadIdx.x; j < N_PER; j += 256)
            partialS[(size_t)q * N_NODES + g0 + j] = (unsigned short)hist[j];
    } else {                                    // weight packing
        int tid = (b - 2 * NBLK_SCAT) * 256 + threadIdx.x;
        const float* W; int D, base, off;
        if      (tid < 2048) { W = W0; D = 128; base = 0;    off = 0;     }
        else if (tid < 4096) { W = W1; D = 128; base = 2048; off = 16384; }
        else if (tid < 5120) { W = W2; D = 64;  base = 4096; off = 32768; }
        else if (tid < 6144) { W = W3; D = 64;  base = 5120; off = 40960; }
        else                 { W = Wg; D = 128; base = 6144; off = 49152; }
        int t2 = tid - base;
        int KT = D / 32;
        int l = t2 & 63;
        int tt = t2 >> 6;
        int kt = tt % KT, n0 = tt / KT;
        int n = n0 * 16 + (l & 15);
        int kb = kt * 32 + (l >> 4) * 8;
#pragma unroll
        for (int j = 0; j < 8; ++j)
            Wp[(size_t)off + (size_t)t2 * 8 + j] = f2bf(W[(size_t)(kb + j) * 128 + n]);
    }
}

// ---------------------------------------------------------------------------
// P1: per-node exclusive prefix over the 32 slice-planes (in place) -> deg,
//     PLUS in-block 256-node exclusive scan -> scanD/scanB (block-local) and
//     per-block totals. All wide & coalesced.
// ---------------------------------------------------------------------------
__global__ __launch_bounds__(256) void plane_prefix_kernel(
    unsigned short* __restrict__ partialD, unsigned short* __restrict__ partialB,
    int* __restrict__ degD, int* __restrict__ degB,
    int* __restrict__ scanD, int* __restrict__ scanB,
    int* __restrict__ blocksumD, int* __restrict__ blocksumB) {
    const int t = threadIdx.x;
    const int n = blockIdx.x * 256 + t;
    int dD = 0, dB = 0;
    if (n < N_NODES) {
        int run = 0;
#pragma unroll
        for (int q = 0; q < HQ; ++q) {
            size_t ix = (size_t)q * N_NODES + n;
            int c = partialD[ix];
            partialD[ix] = (unsigned short)run;
            run += c;
        }
        dD = run; degD[n] = run;
        run = 0;
#pragma unroll
        for (int q = 0; q < HQ; ++q) {
            size_t ix = (size_t)q * N_NODES + n;
            int c = partialB[ix];
            partialB[ix] = (unsigned short)run;
            run += c;
        }
        dB = run; degB[n] = run;
    }
    __shared__ int sD[256], sB[256];
    sD[t] = dD; sB[t] = dB;
    __syncthreads();
    for (int off = 1; off < 256; off <<= 1) {     // Hillis-Steele inclusive
        int xD = (t >= off) ? sD[t - off] : 0;
        int xB = (t >= off) ? sB[t - off] : 0;
        __syncthreads();
        sD[t] += xD; sB[t] += xB;
        __syncthreads();
    }
    if (n < N_NODES) {
        scanD[n] = sD[t] - dD;                    // block-local exclusive
        scanB[n] = sB[t] - dB;
    }
    if (t == 255) {
        blocksumD[blockIdx.x] = sD[255];
        blocksumB[blockIdx.x] = sB[255];
    }
}

// ---------------------------------------------------------------------------
// P2: add block bases: scan[n] += sum(blocksum[0..bid)). 196 wide blocks,
//     each reduces <=196 block sums in LDS. Replaces the 93 us serial scan.
// ---------------------------------------------------------------------------
__global__ __launch_bounds__(256) void base_add_kernel(
    const int* __restrict__ blocksumD, const int* __restrict__ blocksumB,
    int* __restrict__ scanD, int* __restrict__ scanB) {
    __shared__ int sD[256], sB[256];
    const int t = threadIdx.x;
    const int bid = blockIdx.x;
    sD[t] = (t < bid) ? blocksumD[t] : 0;   // bid <= 195 so t < bid < 196 valid
    sB[t] = (t < bid) ? blocksumB[t] : 0;
    __syncthreads();
    for (int off = 128; off >= 1; off >>= 1) {
        if (t < off) { sD[t] += sD[t + off]; sB[t] += sB[t + off]; }
        __syncthreads();
    }
    const int n = bid * 256 + t;
    if (n < N_NODES) { scanD[n] += sD[0]; scanB[n] += sB[0]; }
}

// ---------------------------------------------------------------------------
// FC MFMA body: out = bf16(X(rows x D) @ W + bias); X fp32.
// ---------------------------------------------------------------------------
template<int D>
__device__ __forceinline__ void fc_body(
    int blk, int tid,
    const float* __restrict__ X,
    const unsigned short* __restrict__ Wp,
    const float* __restrict__ bias,
    unsigned short* __restrict__ outbf,
    int rows)
{
    constexpr int KT = D / 32;
    const int lane = tid & 63;
    const int wave = tid >> 6;
    const int m = lane & 15, q = lane >> 4;
    const int rbase = blk * 64 + wave * 16;
    const int row = rbase + m;

    bfrag afr[KT];
#pragma unroll
    for (int kt = 0; kt < KT; ++kt) {
        bfrag a;
        if (row < rows) {
            const float* xp = X + (size_t)row * D + kt * 32 + q * 8;
            float4 u0 = *(const float4*)xp;
            float4 u1 = *(const float4*)(xp + 4);
            a[0] = (short)f2bf(u0.x); a[1] = (short)f2bf(u0.y);
            a[2] = (short)f2bf(u0.z); a[3] = (short)f2bf(u0.w);
            a[4] = (short)f2bf(u1.x); a[5] = (short)f2bf(u1.y);
            a[6] = (short)f2bf(u1.z); a[7] = (short)f2bf(u1.w);
        } else {
#pragma unroll
            for (int t = 0; t < 8; ++t) a[t] = 0;
        }
        afr[kt] = a;
    }

    ffrag acc[8];
#pragma unroll
    for (int n0 = 0; n0 < 8; ++n0)
#pragma unroll
        for (int t = 0; t < 4; ++t) acc[n0][t] = 0.f;

#pragma unroll
    for (int n0 = 0; n0 < 8; ++n0)
#pragma unroll
        for (int kt = 0; kt < KT; ++kt) {
            bfrag bfr = *(const bfrag*)(Wp + ((size_t)(n0 * KT + kt) * 64 + lane) * 8);
            acc[n0] = __builtin_amdgcn_mfma_f32_16x16x32_bf16(afr[kt], bfr, acc[n0], 0, 0, 0);
        }

#pragma unroll
    for (int n0 = 0; n0 < 8; ++n0) {
        const int col = n0 * 16 + m;
        const float bj = bias[col];
#pragma unroll
        for (int r = 0; r < 4; ++r) {
            int orow = rbase + q * 4 + r;
            if (orow < rows)
                outbf[(size_t)orow * 128 + col] = f2bf(acc[n0][r] + bj);
        }
    }
}

// ---------------------------------------------------------------------------
// K1 mega-kernel: blocks [0,128): counting-sort scatter (LDS atomics only,
// 50 KB packed rel-offset table -> 3 blocks/CU) + blocks [128,912): FC GEMMs.
// Absolute CSR base read per edge from L2 (scanD/scanB, 200 KB each).
// ---------------------------------------------------------------------------
__global__ __launch_bounds__(256) void mega_kernel(
    const int* __restrict__ src, const int* __restrict__ dst,
    const int* __restrict__ ef,
    const unsigned short* __restrict__ prefD,
    const unsigned short* __restrict__ prefB,
    const int* __restrict__ scanD, const int* __restrict__ scanB,
    int* __restrict__ bucket, int* __restrict__ bucketB,
    const float* __restrict__ f0, const float* __restrict__ f1,
    const float* __restrict__ f2, const float* __restrict__ f3,
    const unsigned short* __restrict__ Wp,
    const float* __restrict__ b0, const float* __restrict__ b1,
    const float* __restrict__ b2, const float* __restrict__ b3,
    unsigned short* __restrict__ Abf)
{
    __shared__ unsigned offP[N_PER];   // low16: fwd rel slot, high16: bwd rel
    const int b = blockIdx.x;
    if (b < NBLK_SCAT) {
        const int q = b >> 2;
        const int p = b & 3;
        const int g0 = p * N_PER;
        for (int j = threadIdx.x; j < N_PER; j += 256)
            offP[j] = (unsigned)prefD[(size_t)q * N_NODES + g0 + j]
                    | ((unsigned)prefB[(size_t)q * N_NODES + g0 + j] << 16);
        __syncthreads();
        const int e0 = q * HSLICE;
        for (int i = e0 + threadIdx.x; i < e0 + HSLICE; i += 256) {
            int s = src[i], d = dst[i], t = ef[i];
            unsigned rd = (unsigned)(d - g0);
            if (rd < (unsigned)N_PER) {
                unsigned old = atomicAdd(&offP[rd], 1u);          // LDS atomic
                bucket[scanD[d] + (int)(old & 0xffffu)] =
                    s | ((t <= 4) ? 0x80000000 : 0);
            }
            if (t == 6 || t == 14 || t == 30) {
                unsigned rs = (unsigned)(s - g0);
                if (rs < (unsigned)N_PER) {
                    unsigned old = atomicAdd(&offP[rs], 0x10000u);
                    bucketB[scanB[s] + (int)(old >> 16)] = d;
                }
            }
        }
    } else {
        int fb = b - NBLK_SCAT;
        int which = fb / NBLK_FC;
        int blk = fb - which * NBLK_FC;
        if (which == 0)
            fc_body<128>(blk, threadIdx.x, f0, Wp,         b0, Abf + (size_t)0 * N_PER * HDIM, N_PER);
        else if (which == 1)
            fc_body<128>(blk, threadIdx.x, f1, Wp + 16384, b1, Abf + (size_t)1 * N_PER * HDIM, N_PER);
        else if (which == 2)
            fc_body<64>(blk, threadIdx.x, f2, Wp + 32768, b2, Abf + (size_t)2 * N_PER * HDIM, N_PER);
        else
            fc_body<64>(blk, threadIdx.x, f3, Wp + 40960, b3, Abf + (size_t)3 * N_PER * HDIM, N_PER);
    }
}

// ---------------------------------------------------------------------------
// K2: deg_out[n] = sum of 32 uint16 partials; A[n] *= onrm(deg_out[n]);
//     caches onrm in onrm_buf for K3.
// ---------------------------------------------------------------------------
__global__ __launch_bounds__(256) void scale_kernel(
    uint4* __restrict__ A, const unsigned short* __restrict__ partialS,
    float* __restrict__ onrm_buf) {
    int idx = blockIdx.x * blockDim.x + threadIdx.x;
    int n = idx >> 4, j8 = idx & 15;
    int d = (int)partialS[(size_t)j8 * N_NODES + n]
          + (int)partialS[(size_t)(j8 + 16) * N_NODES + n];
    d += __shfl_xor(d, 1);
    d += __shfl_xor(d, 2);
    d += __shfl_xor(d, 4);
    d += __shfl_xor(d, 8);
    float on = onrm_of(d);
    if (j8 == 0) onrm_buf[n] = on;
    uint4 v = A[(size_t)n * 16 + j8];
    uint4 o;
    o.x = pack2(lo_bf(v.x) * on, hi_bf(v.x) * on);
    o.y = pack2(lo_bf(v.y) * on, hi_bf(v.y) * on);
    o.z = pack2(lo_bf(v.z) * on, hi_bf(v.z) * on);
    o.w = pack2(lo_bf(v.w) * on, hi_bf(v.w) * on);
    A[(size_t)n * 16 + j8] = o;
}

// ---------------------------------------------------------------------------
// K3: layer-0 gather from dense CSR (A pre-scaled), unroll-4.
//   B[n] = bf16( relu( (sum A[s]) * inrm(n) + b_g0 ) * onrm(n) )
// ---------------------------------------------------------------------------
__global__ __launch_bounds__(256) void agg0_kernel(
    const uint4* __restrict__ A,
    const int* __restrict__ bucket, const int* __restrict__ scanD,
    const int* __restrict__ degD,
    const float* __restrict__ onrm_buf, const float* __restrict__ b_g0,
    uint4* __restrict__ B) {
    int idx = blockIdx.x * blockDim.x + threadIdx.x;
    int n = idx >> 4, j8 = idx & 15;
    const int cnt = degD[n];
    const int* bk = bucket + scanD[n];
    float acc[8] = {0.f, 0.f, 0.f, 0.f, 0.f, 0.f, 0.f, 0.f};
    int i = 0;
    for (; i + 4 <= cnt; i += 4) {
        int s0 = bk[i] & MASK31,     s1 = bk[i + 1] & MASK31;
        int s2 = bk[i + 2] & MASK31, s3 = bk[i + 3] & MASK31;
        uint4 v0 = A[(size_t)s0 * 16 + j8];
        uint4 v1 = A[(size_t)s1 * 16 + j8];
        uint4 v2 = A[(size_t)s2 * 16 + j8];
        uint4 v3 = A[(size_t)s3 * 16 + j8];
        acc8_add(acc, v0); acc8_add(acc, v1);
        acc8_add(acc, v2); acc8_add(acc, v3);
    }
    for (; i < cnt; ++i) {
        int s = bk[i] & MASK31;
        acc8_add(acc, A[(size_t)s * 16 + j8]);
    }
    float inr = onrm_of(cnt);
    float onr = onrm_buf[n];
    const float* bg = b_g0 + j8 * 8;
    float r[8];
#pragma unroll
    for (int k = 0; k < 8; ++k)
        r[k] = fmaxf(acc[k] * inr + bg[k], 0.f) * onr;
    uint4 o;
    o.x = pack2(r[0], r[1]); o.y = pack2(r[2], r[3]);
    o.z = pack2(r[4], r[5]); o.w = pack2(r[6], r[7]);
    B[(size_t)n * 16 + j8] = o;
}

// ---------------------------------------------------------------------------
// K4: fused layer-1 gather (dense CSR, unroll-2) + MFMA GEMM.
// ---------------------------------------------------------------------------
__global__ __launch_bounds__(256) void gemm1_fused_kernel(
    const unsigned short* __restrict__ Bbf,
    const int* __restrict__ bucket, const int* __restrict__ scanD,
    const int* __restrict__ degD,
    const unsigned short* __restrict__ Wp, const float* __restrict__ bias,
    unsigned short* __restrict__ outbf)
{
    const int lane = threadIdx.x & 63;
    const int wave = threadIdx.x >> 6;
    const int m = lane & 15, q = lane >> 4;
    const int rbase = blockIdx.x * 64 + wave * 16;
    const int node = rbase + m;

    float ga[32];
#pragma unroll
    for (int i = 0; i < 32; ++i) ga[i] = 0.f;

    if (node < N_NODES) {
        const int cnt = degD[node];
        const int* bk = bucket + scanD[node];
        int i = 0;
        for (; i + 2 <= cnt; i += 2) {
            int s0 = bk[i] & MASK31, s1 = bk[i + 1] & MASK31;
            const uint4* r0 = (const uint4*)(Bbf + (size_t)s0 * 128);
            const uint4* r1 = (const uint4*)(Bbf + (size_t)s1 * 128);
            uint4 a0 = r0[0 * 4 + q], a1 = r0[1 * 4 + q], a2 = r0[2 * 4 + q], a3 = r0[3 * 4 + q];
            uint4 c0 = r1[0 * 4 + q], c1 = r1[1 * 4 + q], c2 = r1[2 * 4 + q], c3 = r1[3 * 4 + q];
            acc8_add(ga +  0, a0); acc8_add(ga +  8, a1);
            acc8_add(ga + 16, a2); acc8_add(ga + 24, a3);
            acc8_add(ga +  0, c0); acc8_add(ga +  8, c1);
            acc8_add(ga + 16, c2); acc8_add(ga + 24, c3);
        }
        for (; i < cnt; ++i) {
            int s = bk[i] & MASK31;
            const uint4* rp = (const uint4*)(Bbf + (size_t)s * 128);
#pragma unroll
            for (int kt = 0; kt < 4; ++kt) acc8_add(ga + kt * 8, rp[kt * 4 + q]);
        }
    }

    bfrag afr[4];
#pragma unroll
    for (int kt = 0; kt < 4; ++kt)
#pragma unroll
        for (int j = 0; j < 8; ++j)
            afr[kt][j] = (short)f2bf(ga[kt * 8 + j]);

    ffrag acc[8];
#pragma unroll
    for (int n0 = 0; n0 < 8; ++n0)
#pragma unroll
        for (int t = 0; t < 4; ++t) acc[n0][t] = 0.f;

#pragma unroll
    for (int n0 = 0; n0 < 8; ++n0)
#pragma unroll
        for (int kt = 0; kt < 4; ++kt) {
            bfrag bfr = *(const bfrag*)(Wp + ((size_t)(n0 * 4 + kt) * 64 + lane) * 8);
            acc[n0] = __builtin_amdgcn_mfma_f32_16x16x32_bf16(afr[kt], bfr, acc[n0], 0, 0, 0);
        }

    float ir[4];
#pragma unroll
    for (int r = 0; r < 4; ++r) {
        int orow = rbase + q * 4 + r;
        ir[r] = (orow < N_NODES) ? onrm_of(degD[orow]) : 0.f;
    }
#pragma unroll
    for (int n0 = 0; n0 < 8; ++n0) {
        const int col = n0 * 16 + m;
        const float bj = bias[col];
#pragma unroll
        for (int r = 0; r < 4; ++r) {
            int orow = rbase + q * 4 + r;
            if (orow < N_NODES)
                outbf[(size_t)orow * 128 + col] = f2bf(fmaxf(acc[n0][r] * ir[r] + bj, 0.f));
        }
    }
}

// ---------------------------------------------------------------------------
// K5: final edge-typed gather (dense CSR fwd + bwd) -> fp32 out.
// ---------------------------------------------------------------------------
__global__ __launch_bounds__(256) void final_kernel(
    const uint4* __restrict__ H,
    const int* __restrict__ bucket, const int* __restrict__ scanD,
    const int* __restrict__ degD,
    const int* __restrict__ bucketB, const int* __restrict__ scanB,
    const int* __restrict__ degB,
    float4* __restrict__ out4) {
    int idx = blockIdx.x * blockDim.x + threadIdx.x;
    int n = idx >> 4, j8 = idx & 15;
    float acc[8] = {0.f, 0.f, 0.f, 0.f, 0.f, 0.f, 0.f, 0.f};
    const int cnt = degD[n];
    const int* bk = bucket + scanD[n];
    int i = 0;
    for (; i + 4 <= cnt; i += 4) {
        int c0 = bk[i], c1 = bk[i + 1], c2 = bk[i + 2], c3 = bk[i + 3];
        uint4 v0 = H[(size_t)(c0 & MASK31) * 16 + j8];
        uint4 v1 = H[(size_t)(c1 & MASK31) * 16 + j8];
        uint4 v2 = H[(size_t)(c2 & MASK31) * 16 + j8];
        uint4 v3 = H[(size_t)(c3 & MASK31) * 16 + j8];
        acc8_addw(acc, v0, (c0 < 0) ? 2.0f : 1.0f);
        acc8_addw(acc, v1, (c1 < 0) ? 2.0f : 1.0f);
        acc8_addw(acc, v2, (c2 < 0) ? 2.0f : 1.0f);
        acc8_addw(acc, v3, (c3 < 0) ? 2.0f : 1.0f);
    }
    for (; i < cnt; ++i) {
        int c = bk[i];
        acc8_addw(acc, H[(size_t)(c & MASK31) * 16 + j8], (c < 0) ? 2.0f : 1.0f);
    }
    const int cb = degB[n];
    const int* bkB = bucketB + scanB[n];
    for (int k = 0; k < cb; ++k) {
        int d = bkB[k];
        acc8_add(acc, H[(size_t)d * 16 + j8]);
    }
    float4 o0 = {acc[0], acc[1], acc[2], acc[3]};
    float4 o1 = {acc[4], acc[5], acc[6], acc[7]};
    out4[(size_t)n * 32 + j8 * 2]     = o0;
    out4[(size_t)n * 32 + j8 * 2 + 1] = o1;
}

extern "C" void kernel_launch(void* const* d_in, const int* in_sizes, int n_in,
                              void* d_out, int out_size, void* d_ws, size_t ws_size,
                              hipStream_t stream) {
    const float* feat[4]  = {(const float*)d_in[0], (const float*)d_in[3],
                             (const float*)d_in[6], (const float*)d_in[9]};
    const float* W_fc[4]  = {(const float*)d_in[1], (const float*)d_in[4],
                             (const float*)d_in[7], (const float*)d_in[10]};
    const float* b_fc[4]  = {(const float*)d_in[2], (const float*)d_in[5],
                             (const float*)d_in[8], (const float*)d_in[11]};
    const int*   src      = (const int*)d_in[12];
    const int*   dst      = (const int*)d_in[13];
    const int*   efeat    = (const int*)d_in[14];
    const float* b_g0     = (const float*)d_in[15];
    const float* W_g1     = (const float*)d_in[16];
    const float* b_g1     = (const float*)d_in[17];
    float* out = (float*)d_out;

    // ---- workspace layout, ~41 MB ----
    char* p = (char*)d_ws;
    unsigned short* Abf = (unsigned short*)p; p += (size_t)N_NODES * HDIM * 2;  // 12.8 MB
    unsigned short* Bbf = (unsigned short*)p; p += (size_t)N_NODES * HDIM * 2;  // 12.8 MB
    unsigned short* Wp  = (unsigned short*)p; p += (size_t)65536 * 2;           // 128 KB
    int* bucket  = (int*)p; p += (size_t)E_EDGES * 4;            // 2.4 MB (dense CSR)
    int* bucketB = (int*)p; p += (size_t)E_EDGES * 4;            // 2.4 MB (dense CSR)
    unsigned short* partialS = (unsigned short*)p; p += (size_t)HQ * N_NODES * 2; // 3.2 MB
    unsigned short* partialD = (unsigned short*)p; p += (size_t)HQ * N_NODES * 2; // 3.2 MB
    unsigned short* partialB = (unsigned short*)p; p += (size_t)HQ * N_NODES * 2; // 3.2 MB
    int* degD  = (int*)p; p += (size_t)N_NODES * 4;              // 200 KB
    int* degB  = (int*)p; p += (size_t)N_NODES * 4;
    int* scanD = (int*)p; p += (size_t)N_NODES * 4;
    int* scanB = (int*)p; p += (size_t)N_NODES * 4;
    float* onrm_buf = (float*)p; p += (size_t)N_NODES * 4;
    int* blocksumD = (int*)p; p += 256 * 4;
    int* blocksumB = (int*)p; p += 256 * 4;

    const unsigned short* Wpg = Wp + 49152;

    // K0: packed D|B histogram + S histogram + weight packing
    prep_kernel<<<2 * NBLK_SCAT + 32, 256, 0, stream>>>(
        W_fc[0], W_fc[1], W_fc[2], W_fc[3], W_g1, src, dst, efeat,
        Wp, partialS, partialD, partialB);

    // P1: plane prefix -> deg; in-block node scan -> local scan + block sums
    plane_prefix_kernel<<<NBLK_NODE, 256, 0, stream>>>(
        partialD, partialB, degD, degB, scanD, scanB, blocksumD, blocksumB);

    // P2: wide base add (replaces serial scan)
    base_add_kernel<<<NBLK_NODE, 256, 0, stream>>>(
        blocksumD, blocksumB, scanD, scanB);

    // K1: counting-sort scatter (LDS atomics only, 50 KB) + 4 FC GEMMs
    mega_kernel<<<NBLK_SCAT + 4 * NBLK_FC, 256, 0, stream>>>(
        src, dst, efeat, partialD, partialB, scanD, scanB, bucket, bucketB,
        feat[0], feat[1], feat[2], feat[3], Wp,
        b_fc[0], b_fc[1], b_fc[2], b_fc[3], Abf);

    const int grid_node = (N_NODES * 16) / 256;   // 3125 exact

    // K2: deg_out partial-sum + A *= onrm(deg_out), cache onrm for K3
    scale_kernel<<<grid_node, 256, 0, stream>>>((uint4*)Abf, partialS, onrm_buf);

    // K3: layer0 CSR gather
    agg0_kernel<<<grid_node, 256, 0, stream>>>(
        (const uint4*)Abf, bucket, scanD, degD, onrm_buf, b_g0, (uint4*)Bbf);

    // K4: fused layer1 CSR gather + GEMM
    gemm1_fused_kernel<<<(N_NODES + 63) / 64, 256, 0, stream>>>(
        Bbf, bucket, scanD, degD, Wpg, b_g1, Abf);

    // K5: final edge-typed CSR gather into fp32 d_out
    final_kernel<<<grid_node, 256, 0, stream>>>(
        (const uint4*)Abf, bucket, scanD, degD, bucketB, scanB, degB, (float4*)out);
}

// Round 5
// 274.921 us; speedup vs baseline: 1.4999x; 1.1656x over previous
//
#include <hip/hip_runtime.h>
#include <hip/hip_bf16.h>

#define N_NODES 50000
#define N_PER   12500
#define E_EDGES 600000
#define HDIM    128

#define NBLK_FC    ((N_PER + 63) / 64)            // 196
#define NBLK_NODE  ((N_NODES + 255) / 256)        // 196
#define MASK31  0x7fffffff

// counting-sort tiling: zero device atomics anywhere.
#define HQD 64                   // D|B edge slices
#define HSL_D (E_EDGES / HQD)    // 9375
#define NBLK_DB (HQD * 4)        // 256 scatter/hist blocks
#define HQS 32                   // S (deg_out) edge slices
#define HSL_S (E_EDGES / HQS)    // 18750
#define NBLK_S (HQS * 4)         // 128

typedef __attribute__((ext_vector_type(8))) short bfrag;   // 8 bf16 (4 VGPRs)
typedef __attribute__((ext_vector_type(4))) float ffrag;   // 4 fp32 acc

__device__ __forceinline__ unsigned short f2bf(float f) {
    union { float f; unsigned u; } x; x.f = f;
    unsigned r = x.u + 0x7fffu + ((x.u >> 16) & 1u);   // RTNE
    return (unsigned short)(r >> 16);
}
__device__ __forceinline__ float lo_bf(unsigned v) { return __uint_as_float(v << 16); }
__device__ __forceinline__ float hi_bf(unsigned v) { return __uint_as_float(v & 0xffff0000u); }
__device__ __forceinline__ unsigned pack2(float a, float b) {
    return (unsigned)f2bf(a) | ((unsigned)f2bf(b) << 16);
}
__device__ __forceinline__ float onrm_of(int deg) {
    return rsqrtf(fmaxf((float)deg, 1.0f));
}

__device__ __forceinline__ void acc8_add(float* acc, uint4 v) {
    acc[0] += lo_bf(v.x); acc[1] += hi_bf(v.x);
    acc[2] += lo_bf(v.y); acc[3] += hi_bf(v.y);
    acc[4] += lo_bf(v.z); acc[5] += hi_bf(v.z);
    acc[6] += lo_bf(v.w); acc[7] += hi_bf(v.w);
}
__device__ __forceinline__ void acc8_addw(float* acc, uint4 v, float w) {
    acc[0] += lo_bf(v.x) * w; acc[1] += hi_bf(v.x) * w;
    acc[2] += lo_bf(v.y) * w; acc[3] += hi_bf(v.y) * w;
    acc[4] += lo_bf(v.z) * w; acc[5] += hi_bf(v.z) * w;
    acc[6] += lo_bf(v.w) * w; acc[7] += hi_bf(v.w) * w;
}

// ---------------------------------------------------------------------------
// K0 prep:
//   blocks [0,256):   packed histogram @HQD=64 — dst (low16) | bwd-src (high16)
//   blocks [256,384): src histogram @HQS=32 (deg_out -> partialS)
//   blocks [384,416): weight fragment packing
// ---------------------------------------------------------------------------
__global__ __launch_bounds__(256) void prep_kernel(
    const float* __restrict__ W0, const float* __restrict__ W1,
    const float* __restrict__ W2, const float* __restrict__ W3,
    const float* __restrict__ Wg,
    const int* __restrict__ src, const int* __restrict__ dst,
    const int* __restrict__ ef,
    unsigned short* __restrict__ Wp,
    unsigned short* __restrict__ partialS,
    unsigned short* __restrict__ partialD,
    unsigned char*  __restrict__ partialB) {
    __shared__ unsigned hist[N_PER];            // 50 KB
    int b = blockIdx.x;
    if (b < NBLK_DB) {                          // packed D|B histogram
        const int q = b >> 2;
        const int p = b & 3;
        const int g0 = p * N_PER;
        for (int j = threadIdx.x; j < N_PER; j += 256) hist[j] = 0;
        __syncthreads();
        const int e0 = q * HSL_D;
        for (int i = e0 + threadIdx.x; i < e0 + HSL_D; i += 256) {
            int d = dst[i], t = ef[i], s = src[i];
            unsigned rd = (unsigned)(d - g0);
            if (rd < (unsigned)N_PER) atomicAdd(&hist[rd], 1u);
            if (t == 6 || t == 14 || t == 30) {
                unsigned rs = (unsigned)(s - g0);
                if (rs < (unsigned)N_PER) atomicAdd(&hist[rs], 0x10000u);
            }
        }
        __syncthreads();
        for (int j = threadIdx.x; j < N_PER; j += 256) {
            unsigned h = hist[j];
            partialD[(size_t)q * N_NODES + g0 + j] = (unsigned short)(h & 0xffffu);
            partialB[(size_t)q * N_NODES + g0 + j] = (unsigned char)(h >> 16);
        }
    } else if (b < NBLK_DB + NBLK_S) {          // src histogram (deg_out)
        const int r = b - NBLK_DB;
        const int q = r >> 2;
        const int p = r & 3;
        const int g0 = p * N_PER;
        for (int j = threadIdx.x; j < N_PER; j += 256) hist[j] = 0;
        __syncthreads();
        const int e0 = q * HSL_S;
        for (int i = e0 + threadIdx.x; i < e0 + HSL_S; i += 256) {
            unsigned rr = (unsigned)(src[i] - g0);
            if (rr < (unsigned)N_PER) atomicAdd(&hist[rr], 1u);
        }
        __syncthreads();
        for (int j = threadIdx.x; j < N_PER; j += 256)
            partialS[(size_t)q * N_NODES + g0 + j] = (unsigned short)hist[j];
    } else {                                    // weight packing
        int tid = (b - (NBLK_DB + NBLK_S)) * 256 + threadIdx.x;
        const float* W; int D, base, off;
        if      (tid < 2048) { W = W0; D = 128; base = 0;    off = 0;     }
        else if (tid < 4096) { W = W1; D = 128; base = 2048; off = 16384; }
        else if (tid < 5120) { W = W2; D = 64;  base = 4096; off = 32768; }
        else if (tid < 6144) { W = W3; D = 64;  base = 5120; off = 40960; }
        else                 { W = Wg; D = 128; base = 6144; off = 49152; }
        int t2 = tid - base;
        int KT = D / 32;
        int l = t2 & 63;
        int tt = t2 >> 6;
        int kt = tt % KT, n0 = tt / KT;
        int n = n0 * 16 + (l & 15);
        int kb = kt * 32 + (l >> 4) * 8;
#pragma unroll
        for (int j = 0; j < 8; ++j)
            Wp[(size_t)off + (size_t)t2 * 8 + j] = f2bf(W[(size_t)(kb + j) * 128 + n]);
    }
}

// ---------------------------------------------------------------------------
// P1: per-node exclusive prefix over slice-planes (in place) -> deg,
//     PLUS in-block 256-node scan -> block-local scanD/scanB + block sums.
// ---------------------------------------------------------------------------
__global__ __launch_bounds__(256) void plane_prefix_kernel(
    unsigned short* __restrict__ partialD, unsigned char* __restrict__ partialB,
    int* __restrict__ degD, int* __restrict__ degB,
    int* __restrict__ scanD, int* __restrict__ scanB,
    int* __restrict__ blocksumD, int* __restrict__ blocksumB) {
    const int t = threadIdx.x;
    const int n = blockIdx.x * 256 + t;
    int dD = 0, dB = 0;
    if (n < N_NODES) {
        int run = 0;
#pragma unroll
        for (int q = 0; q < HQD; ++q) {
            size_t ix = (size_t)q * N_NODES + n;
            int c = partialD[ix];
            partialD[ix] = (unsigned short)run;
            run += c;
        }
        dD = run; degD[n] = run;
        run = 0;
#pragma unroll
        for (int q = 0; q < HQD; ++q) {
            size_t ix = (size_t)q * N_NODES + n;
            int c = partialB[ix];
            partialB[ix] = (unsigned char)run;
            run += c;
        }
        dB = run; degB[n] = run;
    }
    __shared__ int sD[256], sB[256];
    sD[t] = dD; sB[t] = dB;
    __syncthreads();
    for (int off = 1; off < 256; off <<= 1) {     // Hillis-Steele inclusive
        int xD = (t >= off) ? sD[t - off] : 0;
        int xB = (t >= off) ? sB[t - off] : 0;
        __syncthreads();
        sD[t] += xD; sB[t] += xB;
        __syncthreads();
    }
    if (n < N_NODES) {
        scanD[n] = sD[t] - dD;                    // block-local exclusive
        scanB[n] = sB[t] - dB;
    }
    if (t == 255) {
        blocksumD[blockIdx.x] = sD[255];
        blocksumB[blockIdx.x] = sB[255];
    }
}

// ---------------------------------------------------------------------------
// P2: scan[n] += sum(blocksum[0..bid)). 196 wide blocks.
// ---------------------------------------------------------------------------
__global__ __launch_bounds__(256) void base_add_kernel(
    const int* __restrict__ blocksumD, const int* __restrict__ blocksumB,
    int* __restrict__ scanD, int* __restrict__ scanB) {
    __shared__ int sD[256], sB[256];
    const int t = threadIdx.x;
    const int bid = blockIdx.x;
    sD[t] = (t < bid) ? blocksumD[t] : 0;
    sB[t] = (t < bid) ? blocksumB[t] : 0;
    __syncthreads();
    for (int off = 128; off >= 1; off >>= 1) {
        if (t < off) { sD[t] += sD[t + off]; sB[t] += sB[t + off]; }
        __syncthreads();
    }
    const int n = bid * 256 + t;
    if (n < N_NODES) { scanD[n] += sD[0]; scanB[n] += sB[0]; }
}

// ---------------------------------------------------------------------------
// K1a: counting-sort scatter. 256 blocks x 1024 threads (16 waves/CU).
//   offP packs ABSOLUTE fwd slot (bits 0..19, < 2^20) | rel bwd slot (20..31).
//   Fwd path: zero global loads beyond the edge arrays. LDS atomics only.
// ---------------------------------------------------------------------------
__global__ __launch_bounds__(1024) void scatter_kernel(
    const int* __restrict__ src, const int* __restrict__ dst,
    const int* __restrict__ ef,
    const unsigned short* __restrict__ prefD,
    const unsigned char*  __restrict__ prefB,
    const int* __restrict__ scanD, const int* __restrict__ scanB,
    int* __restrict__ bucket, int* __restrict__ bucketB)
{
    __shared__ unsigned offP[N_PER];   // absD (20b) | relB (12b)
    const int b = blockIdx.x;
    const int q = b >> 2;
    const int p = b & 3;
    const int g0 = p * N_PER;
    for (int j = threadIdx.x; j < N_PER; j += 1024)
        offP[j] = (unsigned)(scanD[g0 + j] + (int)prefD[(size_t)q * N_NODES + g0 + j])
                | ((unsigned)prefB[(size_t)q * N_NODES + g0 + j] << 20);
    __syncthreads();
    const int e0 = q * HSL_D;
    for (int i = e0 + threadIdx.x; i < e0 + HSL_D; i += 1024) {
        int s = src[i], d = dst[i], t = ef[i];
        unsigned rd = (unsigned)(d - g0);
        if (rd < (unsigned)N_PER) {
            unsigned old = atomicAdd(&offP[rd], 1u);              // LDS atomic
            bucket[old & 0xFFFFFu] = s | ((t <= 4) ? 0x80000000 : 0);
        }
        if (t == 6 || t == 14 || t == 30) {
            unsigned rs = (unsigned)(s - g0);
            if (rs < (unsigned)N_PER) {
                unsigned old = atomicAdd(&offP[rs], 1u << 20);
                bucketB[scanB[s] + (int)(old >> 20)] = d;
            }
        }
    }
}

// ---------------------------------------------------------------------------
// FC MFMA body: out = bf16(X(rows x D) @ W + bias); X fp32.
// ---------------------------------------------------------------------------
template<int D>
__device__ __forceinline__ void fc_body(
    int blk, int tid,
    const float* __restrict__ X,
    const unsigned short* __restrict__ Wp,
    const float* __restrict__ bias,
    unsigned short* __restrict__ outbf,
    int rows)
{
    constexpr int KT = D / 32;
    const int lane = tid & 63;
    const int wave = tid >> 6;
    const int m = lane & 15, q = lane >> 4;
    const int rbase = blk * 64 + wave * 16;
    const int row = rbase + m;

    bfrag afr[KT];
#pragma unroll
    for (int kt = 0; kt < KT; ++kt) {
        bfrag a;
        if (row < rows) {
            const float* xp = X + (size_t)row * D + kt * 32 + q * 8;
            float4 u0 = *(const float4*)xp;
            float4 u1 = *(const float4*)(xp + 4);
            a[0] = (short)f2bf(u0.x); a[1] = (short)f2bf(u0.y);
            a[2] = (short)f2bf(u0.z); a[3] = (short)f2bf(u0.w);
            a[4] = (short)f2bf(u1.x); a[5] = (short)f2bf(u1.y);
            a[6] = (short)f2bf(u1.z); a[7] = (short)f2bf(u1.w);
        } else {
#pragma unroll
            for (int t = 0; t < 8; ++t) a[t] = 0;
        }
        afr[kt] = a;
    }

    ffrag acc[8];
#pragma unroll
    for (int n0 = 0; n0 < 8; ++n0)
#pragma unroll
        for (int t = 0; t < 4; ++t) acc[n0][t] = 0.f;

#pragma unroll
    for (int n0 = 0; n0 < 8; ++n0)
#pragma unroll
        for (int kt = 0; kt < KT; ++kt) {
            bfrag bfr = *(const bfrag*)(Wp + ((size_t)(n0 * KT + kt) * 64 + lane) * 8);
            acc[n0] = __builtin_amdgcn_mfma_f32_16x16x32_bf16(afr[kt], bfr, acc[n0], 0, 0, 0);
        }

#pragma unroll
    for (int n0 = 0; n0 < 8; ++n0) {
        const int col = n0 * 16 + m;
        const float bj = bias[col];
#pragma unroll
        for (int r = 0; r < 4; ++r) {
            int orow = rbase + q * 4 + r;
            if (orow < rows)
                outbf[(size_t)orow * 128 + col] = f2bf(acc[n0][r] + bj);
        }
    }
}

// ---------------------------------------------------------------------------
// K1b: 4 FC GEMMs, no LDS -> 8 blocks/CU.
// ---------------------------------------------------------------------------
__global__ __launch_bounds__(256) void fc_kernel(
    const float* __restrict__ f0, const float* __restrict__ f1,
    const float* __restrict__ f2, const float* __restrict__ f3,
    const unsigned short* __restrict__ Wp,
    const float* __restrict__ b0, const float* __restrict__ b1,
    const float* __restrict__ b2, const float* __restrict__ b3,
    unsigned short* __restrict__ Abf)
{
    int fb = blockIdx.x;
    int which = fb / NBLK_FC;
    int blk = fb - which * NBLK_FC;
    if (which == 0)
        fc_body<128>(blk, threadIdx.x, f0, Wp,         b0, Abf + (size_t)0 * N_PER * HDIM, N_PER);
    else if (which == 1)
        fc_body<128>(blk, threadIdx.x, f1, Wp + 16384, b1, Abf + (size_t)1 * N_PER * HDIM, N_PER);
    else if (which == 2)
        fc_body<64>(blk, threadIdx.x, f2, Wp + 32768, b2, Abf + (size_t)2 * N_PER * HDIM, N_PER);
    else
        fc_body<64>(blk, threadIdx.x, f3, Wp + 40960, b3, Abf + (size_t)3 * N_PER * HDIM, N_PER);
}

// ---------------------------------------------------------------------------
// K2: deg_out[n] = sum of 32 uint16 partials; A[n] *= onrm(deg_out[n]).
// ---------------------------------------------------------------------------
__global__ __launch_bounds__(256) void scale_kernel(
    uint4* __restrict__ A, const unsigned short* __restrict__ partialS,
    float* __restrict__ onrm_buf) {
    int idx = blockIdx.x * blockDim.x + threadIdx.x;
    int n = idx >> 4, j8 = idx & 15;
    int d = (int)partialS[(size_t)j8 * N_NODES + n]
          + (int)partialS[(size_t)(j8 + 16) * N_NODES + n];
    d += __shfl_xor(d, 1);
    d += __shfl_xor(d, 2);
    d += __shfl_xor(d, 4);
    d += __shfl_xor(d, 8);
    float on = onrm_of(d);
    if (j8 == 0) onrm_buf[n] = on;
    uint4 v = A[(size_t)n * 16 + j8];
    uint4 o;
    o.x = pack2(lo_bf(v.x) * on, hi_bf(v.x) * on);
    o.y = pack2(lo_bf(v.y) * on, hi_bf(v.y) * on);
    o.z = pack2(lo_bf(v.z) * on, hi_bf(v.z) * on);
    o.w = pack2(lo_bf(v.w) * on, hi_bf(v.w) * on);
    A[(size_t)n * 16 + j8] = o;
}

// ---------------------------------------------------------------------------
// K3: layer-0 gather from dense CSR (A pre-scaled), unroll-4.
// ---------------------------------------------------------------------------
__global__ __launch_bounds__(256) void agg0_kernel(
    const uint4* __restrict__ A,
    const int* __restrict__ bucket, const int* __restrict__ scanD,
    const int* __restrict__ degD,
    const float* __restrict__ onrm_buf, const float* __restrict__ b_g0,
    uint4* __restrict__ B) {
    int idx = blockIdx.x * blockDim.x + threadIdx.x;
    int n = idx >> 4, j8 = idx & 15;
    const int cnt = degD[n];
    const int* bk = bucket + scanD[n];
    float acc[8] = {0.f, 0.f, 0.f, 0.f, 0.f, 0.f, 0.f, 0.f};
    int i = 0;
    for (; i + 4 <= cnt; i += 4) {
        int s0 = bk[i] & MASK31,     s1 = bk[i + 1] & MASK31;
        int s2 = bk[i + 2] & MASK31, s3 = bk[i + 3] & MASK31;
        uint4 v0 = A[(size_t)s0 * 16 + j8];
        uint4 v1 = A[(size_t)s1 * 16 + j8];
        uint4 v2 = A[(size_t)s2 * 16 + j8];
        uint4 v3 = A[(size_t)s3 * 16 + j8];
        acc8_add(acc, v0); acc8_add(acc, v1);
        acc8_add(acc, v2); acc8_add(acc, v3);
    }
    for (; i < cnt; ++i) {
        int s = bk[i] & MASK31;
        acc8_add(acc, A[(size_t)s * 16 + j8]);
    }
    float inr = onrm_of(cnt);
    float onr = onrm_buf[n];
    const float* bg = b_g0 + j8 * 8;
    float r[8];
#pragma unroll
    for (int k = 0; k < 8; ++k)
        r[k] = fmaxf(acc[k] * inr + bg[k], 0.f) * onr;
    uint4 o;
    o.x = pack2(r[0], r[1]); o.y = pack2(r[2], r[3]);
    o.z = pack2(r[4], r[5]); o.w = pack2(r[6], r[7]);
    B[(size_t)n * 16 + j8] = o;
}

// ---------------------------------------------------------------------------
// K4: fused layer-1 gather (dense CSR, unroll-2) + MFMA GEMM.
// ---------------------------------------------------------------------------
__global__ __launch_bounds__(256) void gemm1_fused_kernel(
    const unsigned short* __restrict__ Bbf,
    const int* __restrict__ bucket, const int* __restrict__ scanD,
    const int* __restrict__ degD,
    const unsigned short* __restrict__ Wp, const float* __restrict__ bias,
    unsigned short* __restrict__ outbf)
{
    const int lane = threadIdx.x & 63;
    const int wave = threadIdx.x >> 6;
    const int m = lane & 15, q = lane >> 4;
    const int rbase = blockIdx.x * 64 + wave * 16;
    const int node = rbase + m;

    float ga[32];
#pragma unroll
    for (int i = 0; i < 32; ++i) ga[i] = 0.f;

    if (node < N_NODES) {
        const int cnt = degD[node];
        const int* bk = bucket + scanD[node];
        int i = 0;
        for (; i + 2 <= cnt; i += 2) {
            int s0 = bk[i] & MASK31, s1 = bk[i + 1] & MASK31;
            const uint4* r0 = (const uint4*)(Bbf + (size_t)s0 * 128);
            const uint4* r1 = (const uint4*)(Bbf + (size_t)s1 * 128);
            uint4 a0 = r0[0 * 4 + q], a1 = r0[1 * 4 + q], a2 = r0[2 * 4 + q], a3 = r0[3 * 4 + q];
            uint4 c0 = r1[0 * 4 + q], c1 = r1[1 * 4 + q], c2 = r1[2 * 4 + q], c3 = r1[3 * 4 + q];
            acc8_add(ga +  0, a0); acc8_add(ga +  8, a1);
            acc8_add(ga + 16, a2); acc8_add(ga + 24, a3);
            acc8_add(ga +  0, c0); acc8_add(ga +  8, c1);
            acc8_add(ga + 16, c2); acc8_add(ga + 24, c3);
        }
        for (; i < cnt; ++i) {
            int s = bk[i] & MASK31;
            const uint4* rp = (const uint4*)(Bbf + (size_t)s * 128);
#pragma unroll
            for (int kt = 0; kt < 4; ++kt) acc8_add(ga + kt * 8, rp[kt * 4 + q]);
        }
    }

    bfrag afr[4];
#pragma unroll
    for (int kt = 0; kt < 4; ++kt)
#pragma unroll
        for (int j = 0; j < 8; ++j)
            afr[kt][j] = (short)f2bf(ga[kt * 8 + j]);

    ffrag acc[8];
#pragma unroll
    for (int n0 = 0; n0 < 8; ++n0)
#pragma unroll
        for (int t = 0; t < 4; ++t) acc[n0][t] = 0.f;

#pragma unroll
    for (int n0 = 0; n0 < 8; ++n0)
#pragma unroll
        for (int kt = 0; kt < 4; ++kt) {
            bfrag bfr = *(const bfrag*)(Wp + ((size_t)(n0 * 4 + kt) * 64 + lane) * 8);
            acc[n0] = __builtin_amdgcn_mfma_f32_16x16x32_bf16(afr[kt], bfr, acc[n0], 0, 0, 0);
        }

    float ir[4];
#pragma unroll
    for (int r = 0; r < 4; ++r) {
        int orow = rbase + q * 4 + r;
        ir[r] = (orow < N_NODES) ? onrm_of(degD[orow]) : 0.f;
    }
#pragma unroll
    for (int n0 = 0; n0 < 8; ++n0) {
        const int col = n0 * 16 + m;
        const float bj = bias[col];
#pragma unroll
        for (int r = 0; r < 4; ++r) {
            int orow = rbase + q * 4 + r;
            if (orow < N_NODES)
                outbf[(size_t)orow * 128 + col] = f2bf(fmaxf(acc[n0][r] * ir[r] + bj, 0.f));
        }
    }
}

// ---------------------------------------------------------------------------
// K5: final edge-typed gather (dense CSR fwd + bwd) -> fp32 out.
// ---------------------------------------------------------------------------
__global__ __launch_bounds__(256) void final_kernel(
    const uint4* __restrict__ H,
    const int* __restrict__ bucket, const int* __restrict__ scanD,
    const int* __restrict__ degD,
    const int* __restrict__ bucketB, const int* __restrict__ scanB,
    const int* __restrict__ degB,
    float4* __restrict__ out4) {
    int idx = blockIdx.x * blockDim.x + threadIdx.x;
    int n = idx >> 4, j8 = idx & 15;
    float acc[8] = {0.f, 0.f, 0.f, 0.f, 0.f, 0.f, 0.f, 0.f};
    const int cnt = degD[n];
    const int* bk = bucket + scanD[n];
    int i = 0;
    for (; i + 4 <= cnt; i += 4) {
        int c0 = bk[i], c1 = bk[i + 1], c2 = bk[i + 2], c3 = bk[i + 3];
        uint4 v0 = H[(size_t)(c0 & MASK31) * 16 + j8];
        uint4 v1 = H[(size_t)(c1 & MASK31) * 16 + j8];
        uint4 v2 = H[(size_t)(c2 & MASK31) * 16 + j8];
        uint4 v3 = H[(size_t)(c3 & MASK31) * 16 + j8];
        acc8_addw(acc, v0, (c0 < 0) ? 2.0f : 1.0f);
        acc8_addw(acc, v1, (c1 < 0) ? 2.0f : 1.0f);
        acc8_addw(acc, v2, (c2 < 0) ? 2.0f : 1.0f);
        acc8_addw(acc, v3, (c3 < 0) ? 2.0f : 1.0f);
    }
    for (; i < cnt; ++i) {
        int c = bk[i];
        acc8_addw(acc, H[(size_t)(c & MASK31) * 16 + j8], (c < 0) ? 2.0f : 1.0f);
    }
    const int cb = degB[n];
    const int* bkB = bucketB + scanB[n];
    for (int k = 0; k < cb; ++k) {
        int d = bkB[k];
        acc8_add(acc, H[(size_t)d * 16 + j8]);
    }
    float4 o0 = {acc[0], acc[1], acc[2], acc[3]};
    float4 o1 = {acc[4], acc[5], acc[6], acc[7]};
    out4[(size_t)n * 32 + j8 * 2]     = o0;
    out4[(size_t)n * 32 + j8 * 2 + 1] = o1;
}

extern "C" void kernel_launch(void* const* d_in, const int* in_sizes, int n_in,
                              void* d_out, int out_size, void* d_ws, size_t ws_size,
                              hipStream_t stream) {
    const float* feat[4]  = {(const float*)d_in[0], (const float*)d_in[3],
                             (const float*)d_in[6], (const float*)d_in[9]};
    const float* W_fc[4]  = {(const float*)d_in[1], (const float*)d_in[4],
                             (const float*)d_in[7], (const float*)d_in[10]};
    const float* b_fc[4]  = {(const float*)d_in[2], (const float*)d_in[5],
                             (const float*)d_in[8], (const float*)d_in[11]};
    const int*   src      = (const int*)d_in[12];
    const int*   dst      = (const int*)d_in[13];
    const int*   efeat    = (const int*)d_in[14];
    const float* b_g0     = (const float*)d_in[15];
    const float* W_g1     = (const float*)d_in[16];
    const float* b_g1     = (const float*)d_in[17];
    float* out = (float*)d_out;

    // ---- workspace layout, ~44 MB ----
    char* p = (char*)d_ws;
    unsigned short* Abf = (unsigned short*)p; p += (size_t)N_NODES * HDIM * 2;  // 12.8 MB
    unsigned short* Bbf = (unsigned short*)p; p += (size_t)N_NODES * HDIM * 2;  // 12.8 MB
    unsigned short* Wp  = (unsigned short*)p; p += (size_t)65536 * 2;           // 128 KB
    int* bucket  = (int*)p; p += (size_t)E_EDGES * 4;            // 2.4 MB (dense CSR)
    int* bucketB = (int*)p; p += (size_t)E_EDGES * 4;            // 2.4 MB (dense CSR)
    unsigned short* partialS = (unsigned short*)p; p += (size_t)HQS * N_NODES * 2; // 3.2 MB
    unsigned short* partialD = (unsigned short*)p; p += (size_t)HQD * N_NODES * 2; // 6.4 MB
    unsigned char*  partialB = (unsigned char*)p;  p += (size_t)HQD * N_NODES;     // 3.2 MB
    int* degD  = (int*)p; p += (size_t)N_NODES * 4;              // 200 KB
    int* degB  = (int*)p; p += (size_t)N_NODES * 4;
    int* scanD = (int*)p; p += (size_t)N_NODES * 4;
    int* scanB = (int*)p; p += (size_t)N_NODES * 4;
    float* onrm_buf = (float*)p; p += (size_t)N_NODES * 4;
    int* blocksumD = (int*)p; p += 256 * 4;
    int* blocksumB = (int*)p; p += 256 * 4;

    const unsigned short* Wpg = Wp + 49152;

    // K0: D|B histogram (HQ=64) + S histogram (HQ=32) + weight packing
    prep_kernel<<<NBLK_DB + NBLK_S + 32, 256, 0, stream>>>(
        W_fc[0], W_fc[1], W_fc[2], W_fc[3], W_g1, src, dst, efeat,
        Wp, partialS, partialD, partialB);

    // P1: plane prefix -> deg; in-block node scan -> local scan + block sums
    plane_prefix_kernel<<<NBLK_NODE, 256, 0, stream>>>(
        partialD, partialB, degD, degB, scanD, scanB, blocksumD, blocksumB);

    // P2: wide base add
    base_add_kernel<<<NBLK_NODE, 256, 0, stream>>>(
        blocksumD, blocksumB, scanD, scanB);

    // K1a: counting-sort scatter (1024 thr, abs-slot LDS table, no dev atomics)
    scatter_kernel<<<NBLK_DB, 1024, 0, stream>>>(
        src, dst, efeat, partialD, partialB, scanD, scanB, bucket, bucketB);

    // K1b: 4 FC GEMMs (no LDS, 8 blocks/CU)
    fc_kernel<<<4 * NBLK_FC, 256, 0, stream>>>(
        feat[0], feat[1], feat[2], feat[3], Wp,
        b_fc[0], b_fc[1], b_fc[2], b_fc[3], Abf);

    const int grid_node = (N_NODES * 16) / 256;   // 3125 exact

    // K2: deg_out partial-sum + A *= onrm(deg_out), cache onrm for K3
    scale_kernel<<<grid_node, 256, 0, stream>>>((uint4*)Abf, partialS, onrm_buf);

    // K3: layer0 CSR gather
    agg0_kernel<<<grid_node, 256, 0, stream>>>(
        (const uint4*)Abf, bucket, scanD, degD, onrm_buf, b_g0, (uint4*)Bbf);

    // K4: fused layer1 CSR gather + GEMM
    gemm1_fused_kernel<<<(N_NODES + 63) / 64, 256, 0, stream>>>(
        Bbf, bucket, scanD, degD, Wpg, b_g1, Abf);

    // K5: final edge-typed CSR gather into fp32 d_out
    final_kernel<<<grid_node, 256, 0, stream>>>(
        (const uint4*)Abf, bucket, scanD, degD, bucketB, scanB, degB, (float4*)out);
}

// Round 6
// 258.786 us; speedup vs baseline: 1.5935x; 1.0624x over previous
//
#include <hip/hip_runtime.h>
#include <hip/hip_bf16.h>

#define N_NODES 50000
#define N_PER   12500
#define E_EDGES 600000
#define HDIM    128

#define NBLK_FC    ((N_PER + 63) / 64)            // 196
#define NBLK_G     ((N_NODES + 63) / 64)          // 782
#define NBLK_NODE  ((N_NODES + 255) / 256)        // 196
#define MASK31  0x7fffffff

// counting-sort tiling: zero device atomics anywhere.
#define HQD 64                   // D|B edge slices
#define HSL_D (E_EDGES / HQD)    // 9375
#define NBLK_DB (HQD * 4)        // 256 scatter/hist blocks
#define HQS 32                   // S (deg_out) edge slices
#define HSL_S (E_EDGES / HQS)    // 18750
#define NBLK_S (HQS * 4)         // 128

typedef __attribute__((ext_vector_type(8))) short bfrag;   // 8 bf16 (4 VGPRs)
typedef __attribute__((ext_vector_type(4))) float ffrag;   // 4 fp32 acc

__device__ __forceinline__ unsigned short f2bf(float f) {
    union { float f; unsigned u; } x; x.f = f;
    unsigned r = x.u + 0x7fffu + ((x.u >> 16) & 1u);   // RTNE
    return (unsigned short)(r >> 16);
}
__device__ __forceinline__ float lo_bf(unsigned v) { return __uint_as_float(v << 16); }
__device__ __forceinline__ float hi_bf(unsigned v) { return __uint_as_float(v & 0xffff0000u); }
__device__ __forceinline__ unsigned pack2(float a, float b) {
    return (unsigned)f2bf(a) | ((unsigned)f2bf(b) << 16);
}
__device__ __forceinline__ float onrm_of(int deg) {
    return rsqrtf(fmaxf((float)deg, 1.0f));
}

__device__ __forceinline__ void acc8_add(float* acc, uint4 v) {
    acc[0] += lo_bf(v.x); acc[1] += hi_bf(v.x);
    acc[2] += lo_bf(v.y); acc[3] += hi_bf(v.y);
    acc[4] += lo_bf(v.z); acc[5] += hi_bf(v.z);
    acc[6] += lo_bf(v.w); acc[7] += hi_bf(v.w);
}
__device__ __forceinline__ void acc8_addw(float* acc, uint4 v, float w) {
    acc[0] += lo_bf(v.x) * w; acc[1] += hi_bf(v.x) * w;
    acc[2] += lo_bf(v.y) * w; acc[3] += hi_bf(v.y) * w;
    acc[4] += lo_bf(v.z) * w; acc[5] += hi_bf(v.z) * w;
    acc[6] += lo_bf(v.w) * w; acc[7] += hi_bf(v.w) * w;
}

// ---------------------------------------------------------------------------
// K0 prep:
//   blocks [0,256):   packed histogram @HQD=64 — dst (low16) | bwd-src (high16)
//   blocks [256,384): src histogram @HQS=32 (deg_out -> partialS)
//   blocks [384,416): weight fragment packing
// ---------------------------------------------------------------------------
__global__ __launch_bounds__(256) void prep_kernel(
    const float* __restrict__ W0, const float* __restrict__ W1,
    const float* __restrict__ W2, const float* __restrict__ W3,
    const float* __restrict__ Wg,
    const int* __restrict__ src, const int* __restrict__ dst,
    const int* __restrict__ ef,
    unsigned short* __restrict__ Wp,
    unsigned short* __restrict__ partialS,
    unsigned short* __restrict__ partialD,
    unsigned char*  __restrict__ partialB) {
    __shared__ unsigned hist[N_PER];            // 50 KB
    int b = blockIdx.x;
    if (b < NBLK_DB) {                          // packed D|B histogram
        const int q = b >> 2;
        const int p = b & 3;
        const int g0 = p * N_PER;
        for (int j = threadIdx.x; j < N_PER; j += 256) hist[j] = 0;
        __syncthreads();
        const int e0 = q * HSL_D;
        for (int i = e0 + threadIdx.x; i < e0 + HSL_D; i += 256) {
            int d = dst[i], t = ef[i], s = src[i];
            unsigned rd = (unsigned)(d - g0);
            if (rd < (unsigned)N_PER) atomicAdd(&hist[rd], 1u);
            if (t == 6 || t == 14 || t == 30) {
                unsigned rs = (unsigned)(s - g0);
                if (rs < (unsigned)N_PER) atomicAdd(&hist[rs], 0x10000u);
            }
        }
        __syncthreads();
        for (int j = threadIdx.x; j < N_PER; j += 256) {
            unsigned h = hist[j];
            partialD[(size_t)q * N_NODES + g0 + j] = (unsigned short)(h & 0xffffu);
            partialB[(size_t)q * N_NODES + g0 + j] = (unsigned char)(h >> 16);
        }
    } else if (b < NBLK_DB + NBLK_S) {          // src histogram (deg_out)
        const int r = b - NBLK_DB;
        const int q = r >> 2;
        const int p = r & 3;
        const int g0 = p * N_PER;
        for (int j = threadIdx.x; j < N_PER; j += 256) hist[j] = 0;
        __syncthreads();
        const int e0 = q * HSL_S;
        for (int i = e0 + threadIdx.x; i < e0 + HSL_S; i += 256) {
            unsigned rr = (unsigned)(src[i] - g0);
            if (rr < (unsigned)N_PER) atomicAdd(&hist[rr], 1u);
        }
        __syncthreads();
        for (int j = threadIdx.x; j < N_PER; j += 256)
            partialS[(size_t)q * N_NODES + g0 + j] = (unsigned short)hist[j];
    } else {                                    // weight packing
        int tid = (b - (NBLK_DB + NBLK_S)) * 256 + threadIdx.x;
        const float* W; int D, base, off;
        if      (tid < 2048) { W = W0; D = 128; base = 0;    off = 0;     }
        else if (tid < 4096) { W = W1; D = 128; base = 2048; off = 16384; }
        else if (tid < 5120) { W = W2; D = 64;  base = 4096; off = 32768; }
        else if (tid < 6144) { W = W3; D = 64;  base = 5120; off = 40960; }
        else                 { W = Wg; D = 128; base = 6144; off = 49152; }
        int t2 = tid - base;
        int KT = D / 32;
        int l = t2 & 63;
        int tt = t2 >> 6;
        int kt = tt % KT, n0 = tt / KT;
        int n = n0 * 16 + (l & 15);
        int kb = kt * 32 + (l >> 4) * 8;
#pragma unroll
        for (int j = 0; j < 8; ++j)
            Wp[(size_t)off + (size_t)t2 * 8 + j] = f2bf(W[(size_t)(kb + j) * 128 + n]);
    }
}

// ---------------------------------------------------------------------------
// P1: per-node exclusive prefix over slice-planes (in place) -> degD/degB,
//     block-local node scan + block sums, AND deg_out sum -> onrm_buf
//     (replaces scale_kernel's reduction; fc epilogue consumes onrm_buf).
// ---------------------------------------------------------------------------
__global__ __launch_bounds__(256) void plane_prefix_kernel(
    unsigned short* __restrict__ partialD, unsigned char* __restrict__ partialB,
    const unsigned short* __restrict__ partialS,
    int* __restrict__ degD, int* __restrict__ degB,
    int* __restrict__ scanD, int* __restrict__ scanB,
    int* __restrict__ blocksumD, int* __restrict__ blocksumB,
    float* __restrict__ onrm_buf) {
    const int t = threadIdx.x;
    const int n = blockIdx.x * 256 + t;
    int dD = 0, dB = 0;
    if (n < N_NODES) {
        int run = 0;
#pragma unroll
        for (int q = 0; q < HQD; ++q) {
            size_t ix = (size_t)q * N_NODES + n;
            int c = partialD[ix];
            partialD[ix] = (unsigned short)run;
            run += c;
        }
        dD = run; degD[n] = run;
        run = 0;
#pragma unroll
        for (int q = 0; q < HQD; ++q) {
            size_t ix = (size_t)q * N_NODES + n;
            int c = partialB[ix];
            partialB[ix] = (unsigned char)run;
            run += c;
        }
        dB = run; degB[n] = run;
        int dS = 0;
#pragma unroll
        for (int q = 0; q < HQS; ++q)
            dS += partialS[(size_t)q * N_NODES + n];
        onrm_buf[n] = onrm_of(dS);
    }
    __shared__ int sD[256], sB[256];
    sD[t] = dD; sB[t] = dB;
    __syncthreads();
    for (int off = 1; off < 256; off <<= 1) {     // Hillis-Steele inclusive
        int xD = (t >= off) ? sD[t - off] : 0;
        int xB = (t >= off) ? sB[t - off] : 0;
        __syncthreads();
        sD[t] += xD; sB[t] += xB;
        __syncthreads();
    }
    if (n < N_NODES) {
        scanD[n] = sD[t] - dD;                    // block-local exclusive
        scanB[n] = sB[t] - dB;
    }
    if (t == 255) {
        blocksumD[blockIdx.x] = sD[255];
        blocksumB[blockIdx.x] = sB[255];
    }
}

// ---------------------------------------------------------------------------
// P2: scan[n] += sum(blocksum[0..bid)). 196 wide blocks.
// ---------------------------------------------------------------------------
__global__ __launch_bounds__(256) void base_add_kernel(
    const int* __restrict__ blocksumD, const int* __restrict__ blocksumB,
    int* __restrict__ scanD, int* __restrict__ scanB) {
    __shared__ int sD[256], sB[256];
    const int t = threadIdx.x;
    const int bid = blockIdx.x;
    sD[t] = (t < bid) ? blocksumD[t] : 0;
    sB[t] = (t < bid) ? blocksumB[t] : 0;
    __syncthreads();
    for (int off = 128; off >= 1; off >>= 1) {
        if (t < off) { sD[t] += sD[t + off]; sB[t] += sB[t + off]; }
        __syncthreads();
    }
    const int n = bid * 256 + t;
    if (n < N_NODES) { scanD[n] += sD[0]; scanB[n] += sB[0]; }
}

// ---------------------------------------------------------------------------
// K1a: counting-sort scatter. 256 blocks x 1024 threads.
//   offP packs ABSOLUTE fwd slot (bits 0..19) | rel bwd slot (20..31).
// ---------------------------------------------------------------------------
__global__ __launch_bounds__(1024) void scatter_kernel(
    const int* __restrict__ src, const int* __restrict__ dst,
    const int* __restrict__ ef,
    const unsigned short* __restrict__ prefD,
    const unsigned char*  __restrict__ prefB,
    const int* __restrict__ scanD, const int* __restrict__ scanB,
    int* __restrict__ bucket, int* __restrict__ bucketB)
{
    __shared__ unsigned offP[N_PER];   // absD (20b) | relB (12b)
    const int b = blockIdx.x;
    const int q = b >> 2;
    const int p = b & 3;
    const int g0 = p * N_PER;
    for (int j = threadIdx.x; j < N_PER; j += 1024)
        offP[j] = (unsigned)(scanD[g0 + j] + (int)prefD[(size_t)q * N_NODES + g0 + j])
                | ((unsigned)prefB[(size_t)q * N_NODES + g0 + j] << 20);
    __syncthreads();
    const int e0 = q * HSL_D;
    for (int i = e0 + threadIdx.x; i < e0 + HSL_D; i += 1024) {
        int s = src[i], d = dst[i], t = ef[i];
        unsigned rd = (unsigned)(d - g0);
        if (rd < (unsigned)N_PER) {
            unsigned old = atomicAdd(&offP[rd], 1u);              // LDS atomic
            bucket[old & 0xFFFFFu] = s | ((t <= 4) ? 0x80000000 : 0);
        }
        if (t == 6 || t == 14 || t == 30) {
            unsigned rs = (unsigned)(s - g0);
            if (rs < (unsigned)N_PER) {
                unsigned old = atomicAdd(&offP[rs], 1u << 20);
                bucketB[scanB[s] + (int)(old >> 20)] = d;
            }
        }
    }
}

// ---------------------------------------------------------------------------
// FC MFMA body: out = bf16( (X(rows x D) @ W + bias) * onrm[row] ); X fp32.
// ---------------------------------------------------------------------------
template<int D>
__device__ __forceinline__ void fc_body(
    int blk, int tid,
    const float* __restrict__ X,
    const unsigned short* __restrict__ Wp,
    const float* __restrict__ bias,
    const float* __restrict__ onrm,
    unsigned short* __restrict__ outbf,
    int rows)
{
    constexpr int KT = D / 32;
    const int lane = tid & 63;
    const int wave = tid >> 6;
    const int m = lane & 15, q = lane >> 4;
    const int rbase = blk * 64 + wave * 16;
    const int row = rbase + m;

    bfrag afr[KT];
#pragma unroll
    for (int kt = 0; kt < KT; ++kt) {
        bfrag a;
        if (row < rows) {
            const float* xp = X + (size_t)row * D + kt * 32 + q * 8;
            float4 u0 = *(const float4*)xp;
            float4 u1 = *(const float4*)(xp + 4);
            a[0] = (short)f2bf(u0.x); a[1] = (short)f2bf(u0.y);
            a[2] = (short)f2bf(u0.z); a[3] = (short)f2bf(u0.w);
            a[4] = (short)f2bf(u1.x); a[5] = (short)f2bf(u1.y);
            a[6] = (short)f2bf(u1.z); a[7] = (short)f2bf(u1.w);
        } else {
#pragma unroll
            for (int t = 0; t < 8; ++t) a[t] = 0;
        }
        afr[kt] = a;
    }

    ffrag acc[8];
#pragma unroll
    for (int n0 = 0; n0 < 8; ++n0)
#pragma unroll
        for (int t = 0; t < 4; ++t) acc[n0][t] = 0.f;

#pragma unroll
    for (int n0 = 0; n0 < 8; ++n0)
#pragma unroll
        for (int kt = 0; kt < KT; ++kt) {
            bfrag bfr = *(const bfrag*)(Wp + ((size_t)(n0 * KT + kt) * 64 + lane) * 8);
            acc[n0] = __builtin_amdgcn_mfma_f32_16x16x32_bf16(afr[kt], bfr, acc[n0], 0, 0, 0);
        }

#pragma unroll
    for (int n0 = 0; n0 < 8; ++n0) {
        const int col = n0 * 16 + m;
        const float bj = bias[col];
#pragma unroll
        for (int r = 0; r < 4; ++r) {
            int orow = rbase + q * 4 + r;
            if (orow < rows)
                outbf[(size_t)orow * 128 + col] =
                    f2bf((acc[n0][r] + bj) * onrm[orow]);
        }
    }
}

// ---------------------------------------------------------------------------
// K1b: 4 FC GEMMs with fused out-norm scaling (scale_kernel deleted).
// ---------------------------------------------------------------------------
__global__ __launch_bounds__(256) void fc_kernel(
    const float* __restrict__ f0, const float* __restrict__ f1,
    const float* __restrict__ f2, const float* __restrict__ f3,
    const unsigned short* __restrict__ Wp,
    const float* __restrict__ b0, const float* __restrict__ b1,
    const float* __restrict__ b2, const float* __restrict__ b3,
    const float* __restrict__ onrm_buf,
    unsigned short* __restrict__ Abf)
{
    int fb = blockIdx.x;
    int which = fb / NBLK_FC;
    int blk = fb - which * NBLK_FC;
    if (which == 0)
        fc_body<128>(blk, threadIdx.x, f0, Wp,         b0, onrm_buf,
                     Abf + (size_t)0 * N_PER * HDIM, N_PER);
    else if (which == 1)
        fc_body<128>(blk, threadIdx.x, f1, Wp + 16384, b1, onrm_buf + N_PER,
                     Abf + (size_t)1 * N_PER * HDIM, N_PER);
    else if (which == 2)
        fc_body<64>(blk, threadIdx.x, f2, Wp + 32768, b2, onrm_buf + 2 * N_PER,
                    Abf + (size_t)2 * N_PER * HDIM, N_PER);
    else
        fc_body<64>(blk, threadIdx.x, f3, Wp + 40960, b3, onrm_buf + 3 * N_PER,
                    Abf + (size_t)3 * N_PER * HDIM, N_PER);
}

// ---------------------------------------------------------------------------
// K3: layer-0 gather from dense CSR (A pre-scaled), unroll-4.
//   B[n] = bf16( relu( (sum A[s]) * inrm(n) + b_g0 ) * onrm(n) )
// ---------------------------------------------------------------------------
__global__ __launch_bounds__(256) void agg0_kernel(
    const uint4* __restrict__ A,
    const int* __restrict__ bucket, const int* __restrict__ scanD,
    const int* __restrict__ degD,
    const float* __restrict__ onrm_buf, const float* __restrict__ b_g0,
    uint4* __restrict__ B) {
    int idx = blockIdx.x * blockDim.x + threadIdx.x;
    int n = idx >> 4, j8 = idx & 15;
    const int cnt = degD[n];
    const int* bk = bucket + scanD[n];
    float acc[8] = {0.f, 0.f, 0.f, 0.f, 0.f, 0.f, 0.f, 0.f};
    int i = 0;
    for (; i + 4 <= cnt; i += 4) {
        int s0 = bk[i] & MASK31,     s1 = bk[i + 1] & MASK31;
        int s2 = bk[i + 2] & MASK31, s3 = bk[i + 3] & MASK31;
        uint4 v0 = A[(size_t)s0 * 16 + j8];
        uint4 v1 = A[(size_t)s1 * 16 + j8];
        uint4 v2 = A[(size_t)s2 * 16 + j8];
        uint4 v3 = A[(size_t)s3 * 16 + j8];
        acc8_add(acc, v0); acc8_add(acc, v1);
        acc8_add(acc, v2); acc8_add(acc, v3);
    }
    for (; i < cnt; ++i) {
        int s = bk[i] & MASK31;
        acc8_add(acc, A[(size_t)s * 16 + j8]);
    }
    float inr = onrm_of(cnt);
    float onr = onrm_buf[n];
    const float* bg = b_g0 + j8 * 8;
    float r[8];
#pragma unroll
    for (int k = 0; k < 8; ++k)
        r[k] = fmaxf(acc[k] * inr + bg[k], 0.f) * onr;
    uint4 o;
    o.x = pack2(r[0], r[1]); o.y = pack2(r[2], r[3]);
    o.z = pack2(r[4], r[5]); o.w = pack2(r[6], r[7]);
    B[(size_t)n * 16 + j8] = o;
}

// ---------------------------------------------------------------------------
// K4a: dense GEMM BW = B @ W_g1 (agg/matmul commute: agg(B)@W = agg(B@W)).
//   Pure streaming MFMA, bf16 in/out, no gather. 782 blocks.
// ---------------------------------------------------------------------------
__global__ __launch_bounds__(256) void gemmg_kernel(
    const unsigned short* __restrict__ Bbf,
    const unsigned short* __restrict__ Wp,
    unsigned short* __restrict__ BWbf)
{
    const int lane = threadIdx.x & 63;
    const int wave = threadIdx.x >> 6;
    const int m = lane & 15, q = lane >> 4;
    const int rbase = blockIdx.x * 64 + wave * 16;
    const int row = rbase + m;

    bfrag afr[4];
#pragma unroll
    for (int kt = 0; kt < 4; ++kt) {
        if (row < N_NODES)
            afr[kt] = *(const bfrag*)(Bbf + (size_t)row * 128 + kt * 32 + q * 8);
        else {
#pragma unroll
            for (int t = 0; t < 8; ++t) afr[kt][t] = 0;
        }
    }

    ffrag acc[8];
#pragma unroll
    for (int n0 = 0; n0 < 8; ++n0)
#pragma unroll
        for (int t = 0; t < 4; ++t) acc[n0][t] = 0.f;

#pragma unroll
    for (int n0 = 0; n0 < 8; ++n0)
#pragma unroll
        for (int kt = 0; kt < 4; ++kt) {
            bfrag bfr = *(const bfrag*)(Wp + ((size_t)(n0 * 4 + kt) * 64 + lane) * 8);
            acc[n0] = __builtin_amdgcn_mfma_f32_16x16x32_bf16(afr[kt], bfr, acc[n0], 0, 0, 0);
        }

#pragma unroll
    for (int n0 = 0; n0 < 8; ++n0) {
        const int col = n0 * 16 + m;
#pragma unroll
        for (int r = 0; r < 4; ++r) {
            int orow = rbase + q * 4 + r;
            if (orow < N_NODES)
                BWbf[(size_t)orow * 128 + col] = f2bf(acc[n0][r]);
        }
    }
}

// ---------------------------------------------------------------------------
// K4b: layer-1 gather over BW (clone of agg0 structure, high TLP).
//   H[n] = bf16( relu( (sum BW[s]) * inrm(n) + b_g1 ) )
// ---------------------------------------------------------------------------
__global__ __launch_bounds__(256) void agg1_kernel(
    const uint4* __restrict__ BW,
    const int* __restrict__ bucket, const int* __restrict__ scanD,
    const int* __restrict__ degD,
    const float* __restrict__ b_g1,
    uint4* __restrict__ H) {
    int idx = blockIdx.x * blockDim.x + threadIdx.x;
    int n = idx >> 4, j8 = idx & 15;
    const int cnt = degD[n];
    const int* bk = bucket + scanD[n];
    float acc[8] = {0.f, 0.f, 0.f, 0.f, 0.f, 0.f, 0.f, 0.f};
    int i = 0;
    for (; i + 4 <= cnt; i += 4) {
        int s0 = bk[i] & MASK31,     s1 = bk[i + 1] & MASK31;
        int s2 = bk[i + 2] & MASK31, s3 = bk[i + 3] & MASK31;
        uint4 v0 = BW[(size_t)s0 * 16 + j8];
        uint4 v1 = BW[(size_t)s1 * 16 + j8];
        uint4 v2 = BW[(size_t)s2 * 16 + j8];
        uint4 v3 = BW[(size_t)s3 * 16 + j8];
        acc8_add(acc, v0); acc8_add(acc, v1);
        acc8_add(acc, v2); acc8_add(acc, v3);
    }
    for (; i < cnt; ++i) {
        int s = bk[i] & MASK31;
        acc8_add(acc, BW[(size_t)s * 16 + j8]);
    }
    float inr = onrm_of(cnt);
    const float* bg = b_g1 + j8 * 8;
    float r[8];
#pragma unroll
    for (int k = 0; k < 8; ++k)
        r[k] = fmaxf(acc[k] * inr + bg[k], 0.f);
    uint4 o;
    o.x = pack2(r[0], r[1]); o.y = pack2(r[2], r[3]);
    o.z = pack2(r[4], r[5]); o.w = pack2(r[6], r[7]);
    H[(size_t)n * 16 + j8] = o;
}

// ---------------------------------------------------------------------------
// K5: final edge-typed gather (dense CSR fwd + bwd) -> fp32 out.
// ---------------------------------------------------------------------------
__global__ __launch_bounds__(256) void final_kernel(
    const uint4* __restrict__ H,
    const int* __restrict__ bucket, const int* __restrict__ scanD,
    const int* __restrict__ degD,
    const int* __restrict__ bucketB, const int* __restrict__ scanB,
    const int* __restrict__ degB,
    float4* __restrict__ out4) {
    int idx = blockIdx.x * blockDim.x + threadIdx.x;
    int n = idx >> 4, j8 = idx & 15;
    float acc[8] = {0.f, 0.f, 0.f, 0.f, 0.f, 0.f, 0.f, 0.f};
    const int cnt = degD[n];
    const int* bk = bucket + scanD[n];
    int i = 0;
    for (; i + 4 <= cnt; i += 4) {
        int c0 = bk[i], c1 = bk[i + 1], c2 = bk[i + 2], c3 = bk[i + 3];
        uint4 v0 = H[(size_t)(c0 & MASK31) * 16 + j8];
        uint4 v1 = H[(size_t)(c1 & MASK31) * 16 + j8];
        uint4 v2 = H[(size_t)(c2 & MASK31) * 16 + j8];
        uint4 v3 = H[(size_t)(c3 & MASK31) * 16 + j8];
        acc8_addw(acc, v0, (c0 < 0) ? 2.0f : 1.0f);
        acc8_addw(acc, v1, (c1 < 0) ? 2.0f : 1.0f);
        acc8_addw(acc, v2, (c2 < 0) ? 2.0f : 1.0f);
        acc8_addw(acc, v3, (c3 < 0) ? 2.0f : 1.0f);
    }
    for (; i < cnt; ++i) {
        int c = bk[i];
        acc8_addw(acc, H[(size_t)(c & MASK31) * 16 + j8], (c < 0) ? 2.0f : 1.0f);
    }
    const int cb = degB[n];
    const int* bkB = bucketB + scanB[n];
    for (int k = 0; k < cb; ++k) {
        int d = bkB[k];
        acc8_add(acc, H[(size_t)d * 16 + j8]);
    }
    float4 o0 = {acc[0], acc[1], acc[2], acc[3]};
    float4 o1 = {acc[4], acc[5], acc[6], acc[7]};
    out4[(size_t)n * 32 + j8 * 2]     = o0;
    out4[(size_t)n * 32 + j8 * 2 + 1] = o1;
}

extern "C" void kernel_launch(void* const* d_in, const int* in_sizes, int n_in,
                              void* d_out, int out_size, void* d_ws, size_t ws_size,
                              hipStream_t stream) {
    const float* feat[4]  = {(const float*)d_in[0], (const float*)d_in[3],
                             (const float*)d_in[6], (const float*)d_in[9]};
    const float* W_fc[4]  = {(const float*)d_in[1], (const float*)d_in[4],
                             (const float*)d_in[7], (const float*)d_in[10]};
    const float* b_fc[4]  = {(const float*)d_in[2], (const float*)d_in[5],
                             (const float*)d_in[8], (const float*)d_in[11]};
    const int*   src      = (const int*)d_in[12];
    const int*   dst      = (const int*)d_in[13];
    const int*   efeat    = (const int*)d_in[14];
    const float* b_g0     = (const float*)d_in[15];
    const float* W_g1     = (const float*)d_in[16];
    const float* b_g1     = (const float*)d_in[17];
    float* out = (float*)d_out;

    // ---- workspace layout, ~44 MB ----
    char* p = (char*)d_ws;
    unsigned short* Abf = (unsigned short*)p; p += (size_t)N_NODES * HDIM * 2;  // 12.8 MB
    unsigned short* Bbf = (unsigned short*)p; p += (size_t)N_NODES * HDIM * 2;  // 12.8 MB
    unsigned short* Wp  = (unsigned short*)p; p += (size_t)65536 * 2;           // 128 KB
    int* bucket  = (int*)p; p += (size_t)E_EDGES * 4;            // 2.4 MB (dense CSR)
    int* bucketB = (int*)p; p += (size_t)E_EDGES * 4;            // 2.4 MB (dense CSR)
    unsigned short* partialS = (unsigned short*)p; p += (size_t)HQS * N_NODES * 2; // 3.2 MB
    unsigned short* partialD = (unsigned short*)p; p += (size_t)HQD * N_NODES * 2; // 6.4 MB
    unsigned char*  partialB = (unsigned char*)p;  p += (size_t)HQD * N_NODES;     // 3.2 MB
    int* degD  = (int*)p; p += (size_t)N_NODES * 4;              // 200 KB
    int* degB  = (int*)p; p += (size_t)N_NODES * 4;
    int* scanD = (int*)p; p += (size_t)N_NODES * 4;
    int* scanB = (int*)p; p += (size_t)N_NODES * 4;
    float* onrm_buf = (float*)p; p += (size_t)N_NODES * 4;
    int* blocksumD = (int*)p; p += 256 * 4;
    int* blocksumB = (int*)p; p += 256 * 4;

    const unsigned short* Wpg = Wp + 49152;

    // K0: D|B histogram (HQ=64) + S histogram (HQ=32) + weight packing
    prep_kernel<<<NBLK_DB + NBLK_S + 32, 256, 0, stream>>>(
        W_fc[0], W_fc[1], W_fc[2], W_fc[3], W_g1, src, dst, efeat,
        Wp, partialS, partialD, partialB);

    // P1: plane prefix -> deg; node scan; deg_out sum -> onrm_buf
    plane_prefix_kernel<<<NBLK_NODE, 256, 0, stream>>>(
        partialD, partialB, partialS, degD, degB, scanD, scanB,
        blocksumD, blocksumB, onrm_buf);

    // P2: wide base add
    base_add_kernel<<<NBLK_NODE, 256, 0, stream>>>(
        blocksumD, blocksumB, scanD, scanB);

    // K1a: counting-sort scatter (1024 thr, abs-slot LDS table, no dev atomics)
    scatter_kernel<<<NBLK_DB, 1024, 0, stream>>>(
        src, dst, efeat, partialD, partialB, scanD, scanB, bucket, bucketB);

    // K1b: 4 FC GEMMs, epilogue fused with out-norm -> Abf (pre-scaled A)
    fc_kernel<<<4 * NBLK_FC, 256, 0, stream>>>(
        feat[0], feat[1], feat[2], feat[3], Wp,
        b_fc[0], b_fc[1], b_fc[2], b_fc[3], onrm_buf, Abf);

    const int grid_node = (N_NODES * 16) / 256;   // 3125 exact

    // K3: layer0 gather: Abf -> Bbf (B, carries out-norm)
    agg0_kernel<<<grid_node, 256, 0, stream>>>(
        (const uint4*)Abf, bucket, scanD, degD, onrm_buf, b_g0, (uint4*)Bbf);

    // K4a: dense BW = B @ W_g1: Bbf -> Abf (A dead after agg0)
    gemmg_kernel<<<NBLK_G, 256, 0, stream>>>(Bbf, Wpg, Abf);

    // K4b: layer1 gather over BW: Abf -> Bbf (H)
    agg1_kernel<<<grid_node, 256, 0, stream>>>(
        (const uint4*)Abf, bucket, scanD, degD, b_g1, (uint4*)Bbf);

    // K5: final edge-typed gather: Bbf (H) -> fp32 out
    final_kernel<<<grid_node, 256, 0, stream>>>(
        (const uint4*)Bbf, bucket, scanD, degD, bucketB, scanB, degB, (float4*)out);
}

// Round 7
// 252.960 us; speedup vs baseline: 1.6302x; 1.0230x over previous
//
#include <hip/hip_runtime.h>
#include <hip/hip_bf16.h>

#define N_NODES 50000
#define N_PER   12500
#define E_EDGES 600000
#define HDIM    128

#define NBLK_FC    ((N_PER + 63) / 64)            // 196
#define NBLK_G     ((N_NODES + 63) / 64)          // 782
#define NBLK_NODE  ((N_NODES + 255) / 256)        // 196
#define MASK31  0x7fffffff

// counting-sort tiling: zero device atomics anywhere.
#define HQD 64                   // edge slices (single fused histogram pass)
#define HSL_D (E_EDGES / HQD)    // 9375
#define NBLK_DB (HQD * 4)        // 256 scatter/hist blocks

typedef __attribute__((ext_vector_type(8))) short bfrag;   // 8 bf16 (4 VGPRs)
typedef __attribute__((ext_vector_type(4))) float ffrag;   // 4 fp32 acc

__device__ __forceinline__ unsigned short f2bf(float f) {
    union { float f; unsigned u; } x; x.f = f;
    unsigned r = x.u + 0x7fffu + ((x.u >> 16) & 1u);   // RTNE
    return (unsigned short)(r >> 16);
}
__device__ __forceinline__ float lo_bf(unsigned v) { return __uint_as_float(v << 16); }
__device__ __forceinline__ float hi_bf(unsigned v) { return __uint_as_float(v & 0xffff0000u); }
__device__ __forceinline__ unsigned pack2(float a, float b) {
    return (unsigned)f2bf(a) | ((unsigned)f2bf(b) << 16);
}
__device__ __forceinline__ float onrm_of(int deg) {
    return rsqrtf(fmaxf((float)deg, 1.0f));
}

__device__ __forceinline__ void acc8_add(float* acc, uint4 v) {
    acc[0] += lo_bf(v.x); acc[1] += hi_bf(v.x);
    acc[2] += lo_bf(v.y); acc[3] += hi_bf(v.y);
    acc[4] += lo_bf(v.z); acc[5] += hi_bf(v.z);
    acc[6] += lo_bf(v.w); acc[7] += hi_bf(v.w);
}
__device__ __forceinline__ void acc8_addw(float* acc, uint4 v, float w) {
    acc[0] += lo_bf(v.x) * w; acc[1] += hi_bf(v.x) * w;
    acc[2] += lo_bf(v.y) * w; acc[3] += hi_bf(v.y) * w;
    acc[4] += lo_bf(v.z) * w; acc[5] += hi_bf(v.z) * w;
    acc[6] += lo_bf(v.w) * w; acc[7] += hi_bf(v.w) * w;
}

// ---------------------------------------------------------------------------
// K0 prep:
//   blocks [0,256):   ONE fused histogram pass — LDS word packs
//                     D count (bits 0..9) | B count (10..15) | S count (16..31).
//                     Per-slice per-node counts are <=~8 (Binom(9375,2e-5)),
//                     so field carries are impossible. S+B share one atomic.
//   blocks [256,288): weight fragment packing
// ---------------------------------------------------------------------------
__global__ __launch_bounds__(256) void prep_kernel(
    const float* __restrict__ W0, const float* __restrict__ W1,
    const float* __restrict__ W2, const float* __restrict__ W3,
    const float* __restrict__ Wg,
    const int* __restrict__ src, const int* __restrict__ dst,
    const int* __restrict__ ef,
    unsigned short* __restrict__ Wp,
    unsigned short* __restrict__ partialS,
    unsigned short* __restrict__ partialD,
    unsigned char*  __restrict__ partialB) {
    __shared__ unsigned hist[N_PER];            // 50 KB
    int b = blockIdx.x;
    if (b < NBLK_DB) {                          // fused D|B|S histogram
        const int q = b >> 2;
        const int p = b & 3;
        const int g0 = p * N_PER;
        for (int j = threadIdx.x; j < N_PER; j += 256) hist[j] = 0;
        __syncthreads();
        const int e0 = q * HSL_D;
        for (int i = e0 + threadIdx.x; i < e0 + HSL_D; i += 256) {
            int d = dst[i], t = ef[i], s = src[i];
            unsigned rd = (unsigned)(d - g0);
            if (rd < (unsigned)N_PER) atomicAdd(&hist[rd], 1u);
            unsigned rs = (unsigned)(s - g0);
            if (rs < (unsigned)N_PER) {
                unsigned inc = 0x10000u
                             + ((t == 6 || t == 14 || t == 30) ? 0x400u : 0u);
                atomicAdd(&hist[rs], inc);
            }
        }
        __syncthreads();
        for (int j = threadIdx.x; j < N_PER; j += 256) {
            unsigned h = hist[j];
            partialD[(size_t)q * N_NODES + g0 + j] = (unsigned short)(h & 0x3FFu);
            partialB[(size_t)q * N_NODES + g0 + j] = (unsigned char)((h >> 10) & 0x3Fu);
            partialS[(size_t)q * N_NODES + g0 + j] = (unsigned short)(h >> 16);
        }
    } else {                                    // weight packing
        int tid = (b - NBLK_DB) * 256 + threadIdx.x;
        const float* W; int D, base, off;
        if      (tid < 2048) { W = W0; D = 128; base = 0;    off = 0;     }
        else if (tid < 4096) { W = W1; D = 128; base = 2048; off = 16384; }
        else if (tid < 5120) { W = W2; D = 64;  base = 4096; off = 32768; }
        else if (tid < 6144) { W = W3; D = 64;  base = 5120; off = 40960; }
        else                 { W = Wg; D = 128; base = 6144; off = 49152; }
        int t2 = tid - base;
        int KT = D / 32;
        int l = t2 & 63;
        int tt = t2 >> 6;
        int kt = tt % KT, n0 = tt / KT;
        int n = n0 * 16 + (l & 15);
        int kb = kt * 32 + (l >> 4) * 8;
#pragma unroll
        for (int j = 0; j < 8; ++j)
            Wp[(size_t)off + (size_t)t2 * 8 + j] = f2bf(W[(size_t)(kb + j) * 128 + n]);
    }
}

// ---------------------------------------------------------------------------
// P1: per-node exclusive prefix over slice-planes (in place) -> degD/degB,
//     block-local node scan + block sums, AND deg_out sum -> onrm_buf.
// ---------------------------------------------------------------------------
__global__ __launch_bounds__(256) void plane_prefix_kernel(
    unsigned short* __restrict__ partialD, unsigned char* __restrict__ partialB,
    const unsigned short* __restrict__ partialS,
    int* __restrict__ degD, int* __restrict__ degB,
    int* __restrict__ scanD, int* __restrict__ scanB,
    int* __restrict__ blocksumD, int* __restrict__ blocksumB,
    float* __restrict__ onrm_buf) {
    const int t = threadIdx.x;
    const int n = blockIdx.x * 256 + t;
    int dD = 0, dB = 0;
    if (n < N_NODES) {
        int run = 0;
#pragma unroll
        for (int q = 0; q < HQD; ++q) {
            size_t ix = (size_t)q * N_NODES + n;
            int c = partialD[ix];
            partialD[ix] = (unsigned short)run;
            run += c;
        }
        dD = run; degD[n] = run;
        run = 0;
#pragma unroll
        for (int q = 0; q < HQD; ++q) {
            size_t ix = (size_t)q * N_NODES + n;
            int c = partialB[ix];
            partialB[ix] = (unsigned char)run;
            run += c;
        }
        dB = run; degB[n] = run;
        int dS = 0;
#pragma unroll
        for (int q = 0; q < HQD; ++q)
            dS += partialS[(size_t)q * N_NODES + n];
        onrm_buf[n] = onrm_of(dS);
    }
    __shared__ int sD[256], sB[256];
    sD[t] = dD; sB[t] = dB;
    __syncthreads();
    for (int off = 1; off < 256; off <<= 1) {     // Hillis-Steele inclusive
        int xD = (t >= off) ? sD[t - off] : 0;
        int xB = (t >= off) ? sB[t - off] : 0;
        __syncthreads();
        sD[t] += xD; sB[t] += xB;
        __syncthreads();
    }
    if (n < N_NODES) {
        scanD[n] = sD[t] - dD;                    // block-local exclusive
        scanB[n] = sB[t] - dB;
    }
    if (t == 255) {
        blocksumD[blockIdx.x] = sD[255];
        blocksumB[blockIdx.x] = sB[255];
    }
}

// ---------------------------------------------------------------------------
// P2: scan[n] += sum(blocksum[0..bid)). 196 wide blocks.
// ---------------------------------------------------------------------------
__global__ __launch_bounds__(256) void base_add_kernel(
    const int* __restrict__ blocksumD, const int* __restrict__ blocksumB,
    int* __restrict__ scanD, int* __restrict__ scanB) {
    __shared__ int sD[256], sB[256];
    const int t = threadIdx.x;
    const int bid = blockIdx.x;
    sD[t] = (t < bid) ? blocksumD[t] : 0;
    sB[t] = (t < bid) ? blocksumB[t] : 0;
    __syncthreads();
    for (int off = 128; off >= 1; off >>= 1) {
        if (t < off) { sD[t] += sD[t + off]; sB[t] += sB[t + off]; }
        __syncthreads();
    }
    const int n = bid * 256 + t;
    if (n < N_NODES) { scanD[n] += sD[0]; scanB[n] += sB[0]; }
}

// ---------------------------------------------------------------------------
// FC MFMA body: out = bf16( (X(rows x D) @ W + bias) * onrm[row] ); X fp32.
// tid must be in [0,256). No LDS, no sync — safe inside mixed blocks.
// ---------------------------------------------------------------------------
template<int D>
__device__ __forceinline__ void fc_body(
    int blk, int tid,
    const float* __restrict__ X,
    const unsigned short* __restrict__ Wp,
    const float* __restrict__ bias,
    const float* __restrict__ onrm,
    unsigned short* __restrict__ outbf,
    int rows)
{
    constexpr int KT = D / 32;
    const int lane = tid & 63;
    const int wave = tid >> 6;
    const int m = lane & 15, q = lane >> 4;
    const int rbase = blk * 64 + wave * 16;
    const int row = rbase + m;

    bfrag afr[KT];
#pragma unroll
    for (int kt = 0; kt < KT; ++kt) {
        bfrag a;
        if (row < rows) {
            const float* xp = X + (size_t)row * D + kt * 32 + q * 8;
            float4 u0 = *(const float4*)xp;
            float4 u1 = *(const float4*)(xp + 4);
            a[0] = (short)f2bf(u0.x); a[1] = (short)f2bf(u0.y);
            a[2] = (short)f2bf(u0.z); a[3] = (short)f2bf(u0.w);
            a[4] = (short)f2bf(u1.x); a[5] = (short)f2bf(u1.y);
            a[6] = (short)f2bf(u1.z); a[7] = (short)f2bf(u1.w);
        } else {
#pragma unroll
            for (int t = 0; t < 8; ++t) a[t] = 0;
        }
        afr[kt] = a;
    }

    ffrag acc[8];
#pragma unroll
    for (int n0 = 0; n0 < 8; ++n0)
#pragma unroll
        for (int t = 0; t < 4; ++t) acc[n0][t] = 0.f;

#pragma unroll
    for (int n0 = 0; n0 < 8; ++n0)
#pragma unroll
        for (int kt = 0; kt < KT; ++kt) {
            bfrag bfr = *(const bfrag*)(Wp + ((size_t)(n0 * KT + kt) * 64 + lane) * 8);
            acc[n0] = __builtin_amdgcn_mfma_f32_16x16x32_bf16(afr[kt], bfr, acc[n0], 0, 0, 0);
        }

#pragma unroll
    for (int n0 = 0; n0 < 8; ++n0) {
        const int col = n0 * 16 + m;
        const float bj = bias[col];
#pragma unroll
        for (int r = 0; r < 4; ++r) {
            int orow = rbase + q * 4 + r;
            if (orow < rows)
                outbf[(size_t)orow * 128 + col] =
                    f2bf((acc[n0][r] + bj) * onrm[orow]);
        }
    }
}

// ---------------------------------------------------------------------------
// K1: fused scatter + FC. 1024-thread blocks.
//   blocks [0,256):   counting-sort scatter (LDS atomics, 50 KB offP)
//   blocks [256,452): 4 FC 64-row tiles each (tid>>8 selects tile; fc_body
//                     is LDS/sync-free so mixed tiles per block are safe).
//   Overlaps the latency-bound scatter with the MFMA-bound FC GEMMs.
// ---------------------------------------------------------------------------
__global__ __launch_bounds__(1024) void scatfc_kernel(
    const int* __restrict__ src, const int* __restrict__ dst,
    const int* __restrict__ ef,
    const unsigned short* __restrict__ prefD,
    const unsigned char*  __restrict__ prefB,
    const int* __restrict__ scanD, const int* __restrict__ scanB,
    int* __restrict__ bucket, int* __restrict__ bucketB,
    const float* __restrict__ f0, const float* __restrict__ f1,
    const float* __restrict__ f2, const float* __restrict__ f3,
    const unsigned short* __restrict__ Wp,
    const float* __restrict__ b0, const float* __restrict__ b1,
    const float* __restrict__ b2, const float* __restrict__ b3,
    const float* __restrict__ onrm_buf,
    unsigned short* __restrict__ Abf)
{
    __shared__ unsigned offP[N_PER];   // absD (20b) | relB (12b)
    const int b = blockIdx.x;
    if (b < NBLK_DB) {
        const int q = b >> 2;
        const int p = b & 3;
        const int g0 = p * N_PER;
        for (int j = threadIdx.x; j < N_PER; j += 1024)
            offP[j] = (unsigned)(scanD[g0 + j] + (int)prefD[(size_t)q * N_NODES + g0 + j])
                    | ((unsigned)prefB[(size_t)q * N_NODES + g0 + j] << 20);
        __syncthreads();
        const int e0 = q * HSL_D;
        for (int i = e0 + threadIdx.x; i < e0 + HSL_D; i += 1024) {
            int s = src[i], d = dst[i], t = ef[i];
            unsigned rd = (unsigned)(d - g0);
            if (rd < (unsigned)N_PER) {
                unsigned old = atomicAdd(&offP[rd], 1u);          // LDS atomic
                bucket[old & 0xFFFFFu] = s | ((t <= 4) ? 0x80000000 : 0);
            }
            if (t == 6 || t == 14 || t == 30) {
                unsigned rs = (unsigned)(s - g0);
                if (rs < (unsigned)N_PER) {
                    unsigned old = atomicAdd(&offP[rs], 1u << 20);
                    bucketB[scanB[s] + (int)(old >> 20)] = d;
                }
            }
        }
    } else {
        int ft = (b - NBLK_DB) * 4 + (threadIdx.x >> 8);   // 0..783
        int tid = threadIdx.x & 255;
        int which = ft / NBLK_FC;
        int blk = ft - which * NBLK_FC;
        if (which == 0)
            fc_body<128>(blk, tid, f0, Wp,         b0, onrm_buf,
                         Abf + (size_t)0 * N_PER * HDIM, N_PER);
        else if (which == 1)
            fc_body<128>(blk, tid, f1, Wp + 16384, b1, onrm_buf + N_PER,
                         Abf + (size_t)1 * N_PER * HDIM, N_PER);
        else if (which == 2)
            fc_body<64>(blk, tid, f2, Wp + 32768, b2, onrm_buf + 2 * N_PER,
                        Abf + (size_t)2 * N_PER * HDIM, N_PER);
        else
            fc_body<64>(blk, tid, f3, Wp + 40960, b3, onrm_buf + 3 * N_PER,
                        Abf + (size_t)3 * N_PER * HDIM, N_PER);
    }
}

// ---------------------------------------------------------------------------
// K3: layer-0 gather from dense CSR (A pre-scaled), unroll-8 for MLP.
//   B[n] = bf16( relu( (sum A[s]) * inrm(n) + b_g0 ) * onrm(n) )
// ---------------------------------------------------------------------------
__global__ __launch_bounds__(256) void agg0_kernel(
    const uint4* __restrict__ A,
    const int* __restrict__ bucket, const int* __restrict__ scanD,
    const int* __restrict__ degD,
    const float* __restrict__ onrm_buf, const float* __restrict__ b_g0,
    uint4* __restrict__ B) {
    int idx = blockIdx.x * blockDim.x + threadIdx.x;
    int n = idx >> 4, j8 = idx & 15;
    const int cnt = degD[n];
    const int* bk = bucket + scanD[n];
    float acc[8] = {0.f, 0.f, 0.f, 0.f, 0.f, 0.f, 0.f, 0.f};
    int i = 0;
    for (; i + 8 <= cnt; i += 8) {
        uint4 v[8];
#pragma unroll
        for (int k = 0; k < 8; ++k)
            v[k] = A[(size_t)(bk[i + k] & MASK31) * 16 + j8];
#pragma unroll
        for (int k = 0; k < 8; ++k) acc8_add(acc, v[k]);
    }
    if (i + 4 <= cnt) {
        uint4 v[4];
#pragma unroll
        for (int k = 0; k < 4; ++k)
            v[k] = A[(size_t)(bk[i + k] & MASK31) * 16 + j8];
#pragma unroll
        for (int k = 0; k < 4; ++k) acc8_add(acc, v[k]);
        i += 4;
    }
    for (; i < cnt; ++i)
        acc8_add(acc, A[(size_t)(bk[i] & MASK31) * 16 + j8]);
    float inr = onrm_of(cnt);
    float onr = onrm_buf[n];
    const float* bg = b_g0 + j8 * 8;
    float r[8];
#pragma unroll
    for (int k = 0; k < 8; ++k)
        r[k] = fmaxf(acc[k] * inr + bg[k], 0.f) * onr;
    uint4 o;
    o.x = pack2(r[0], r[1]); o.y = pack2(r[2], r[3]);
    o.z = pack2(r[4], r[5]); o.w = pack2(r[6], r[7]);
    B[(size_t)n * 16 + j8] = o;
}

// ---------------------------------------------------------------------------
// K4a: dense GEMM BW = B @ W_g1 (agg/matmul commute). Pure streaming MFMA.
// ---------------------------------------------------------------------------
__global__ __launch_bounds__(256) void gemmg_kernel(
    const unsigned short* __restrict__ Bbf,
    const unsigned short* __restrict__ Wp,
    unsigned short* __restrict__ BWbf)
{
    const int lane = threadIdx.x & 63;
    const int wave = threadIdx.x >> 6;
    const int m = lane & 15, q = lane >> 4;
    const int rbase = blockIdx.x * 64 + wave * 16;
    const int row = rbase + m;

    bfrag afr[4];
#pragma unroll
    for (int kt = 0; kt < 4; ++kt) {
        if (row < N_NODES)
            afr[kt] = *(const bfrag*)(Bbf + (size_t)row * 128 + kt * 32 + q * 8);
        else {
#pragma unroll
            for (int t = 0; t < 8; ++t) afr[kt][t] = 0;
        }
    }

    ffrag acc[8];
#pragma unroll
    for (int n0 = 0; n0 < 8; ++n0)
#pragma unroll
        for (int t = 0; t < 4; ++t) acc[n0][t] = 0.f;

#pragma unroll
    for (int n0 = 0; n0 < 8; ++n0)
#pragma unroll
        for (int kt = 0; kt < 4; ++kt) {
            bfrag bfr = *(const bfrag*)(Wp + ((size_t)(n0 * 4 + kt) * 64 + lane) * 8);
            acc[n0] = __builtin_amdgcn_mfma_f32_16x16x32_bf16(afr[kt], bfr, acc[n0], 0, 0, 0);
        }

#pragma unroll
    for (int n0 = 0; n0 < 8; ++n0) {
        const int col = n0 * 16 + m;
#pragma unroll
        for (int r = 0; r < 4; ++r) {
            int orow = rbase + q * 4 + r;
            if (orow < N_NODES)
                BWbf[(size_t)orow * 128 + col] = f2bf(acc[n0][r]);
        }
    }
}

// ---------------------------------------------------------------------------
// K4b: layer-1 gather over BW, unroll-8.
//   H[n] = bf16( relu( (sum BW[s]) * inrm(n) + b_g1 ) )
// ---------------------------------------------------------------------------
__global__ __launch_bounds__(256) void agg1_kernel(
    const uint4* __restrict__ BW,
    const int* __restrict__ bucket, const int* __restrict__ scanD,
    const int* __restrict__ degD,
    const float* __restrict__ b_g1,
    uint4* __restrict__ H) {
    int idx = blockIdx.x * blockDim.x + threadIdx.x;
    int n = idx >> 4, j8 = idx & 15;
    const int cnt = degD[n];
    const int* bk = bucket + scanD[n];
    float acc[8] = {0.f, 0.f, 0.f, 0.f, 0.f, 0.f, 0.f, 0.f};
    int i = 0;
    for (; i + 8 <= cnt; i += 8) {
        uint4 v[8];
#pragma unroll
        for (int k = 0; k < 8; ++k)
            v[k] = BW[(size_t)(bk[i + k] & MASK31) * 16 + j8];
#pragma unroll
        for (int k = 0; k < 8; ++k) acc8_add(acc, v[k]);
    }
    if (i + 4 <= cnt) {
        uint4 v[4];
#pragma unroll
        for (int k = 0; k < 4; ++k)
            v[k] = BW[(size_t)(bk[i + k] & MASK31) * 16 + j8];
#pragma unroll
        for (int k = 0; k < 4; ++k) acc8_add(acc, v[k]);
        i += 4;
    }
    for (; i < cnt; ++i)
        acc8_add(acc, BW[(size_t)(bk[i] & MASK31) * 16 + j8]);
    float inr = onrm_of(cnt);
    const float* bg = b_g1 + j8 * 8;
    float r[8];
#pragma unroll
    for (int k = 0; k < 8; ++k)
        r[k] = fmaxf(acc[k] * inr + bg[k], 0.f);
    uint4 o;
    o.x = pack2(r[0], r[1]); o.y = pack2(r[2], r[3]);
    o.z = pack2(r[4], r[5]); o.w = pack2(r[6], r[7]);
    H[(size_t)n * 16 + j8] = o;
}

// ---------------------------------------------------------------------------
// K5: final edge-typed gather (dense CSR fwd + bwd), unroll-8 -> fp32 out.
// ---------------------------------------------------------------------------
__global__ __launch_bounds__(256) void final_kernel(
    const uint4* __restrict__ H,
    const int* __restrict__ bucket, const int* __restrict__ scanD,
    const int* __restrict__ degD,
    const int* __restrict__ bucketB, const int* __restrict__ scanB,
    const int* __restrict__ degB,
    float4* __restrict__ out4) {
    int idx = blockIdx.x * blockDim.x + threadIdx.x;
    int n = idx >> 4, j8 = idx & 15;
    float acc[8] = {0.f, 0.f, 0.f, 0.f, 0.f, 0.f, 0.f, 0.f};
    const int cnt = degD[n];
    const int* bk = bucket + scanD[n];
    int i = 0;
    for (; i + 8 <= cnt; i += 8) {
        int c[8]; uint4 v[8];
#pragma unroll
        for (int k = 0; k < 8; ++k) c[k] = bk[i + k];
#pragma unroll
        for (int k = 0; k < 8; ++k)
            v[k] = H[(size_t)(c[k] & MASK31) * 16 + j8];
#pragma unroll
        for (int k = 0; k < 8; ++k)
            acc8_addw(acc, v[k], (c[k] < 0) ? 2.0f : 1.0f);
    }
    if (i + 4 <= cnt) {
        int c[4]; uint4 v[4];
#pragma unroll
        for (int k = 0; k < 4; ++k) c[k] = bk[i + k];
#pragma unroll
        for (int k = 0; k < 4; ++k)
            v[k] = H[(size_t)(c[k] & MASK31) * 16 + j8];
#pragma unroll
        for (int k = 0; k < 4; ++k)
            acc8_addw(acc, v[k], (c[k] < 0) ? 2.0f : 1.0f);
        i += 4;
    }
    for (; i < cnt; ++i) {
        int c = bk[i];
        acc8_addw(acc, H[(size_t)(c & MASK31) * 16 + j8], (c < 0) ? 2.0f : 1.0f);
    }
    const int cb = degB[n];
    const int* bkB = bucketB + scanB[n];
    for (int k = 0; k < cb; ++k) {
        int d = bkB[k];
        acc8_add(acc, H[(size_t)d * 16 + j8]);
    }
    float4 o0 = {acc[0], acc[1], acc[2], acc[3]};
    float4 o1 = {acc[4], acc[5], acc[6], acc[7]};
    out4[(size_t)n * 32 + j8 * 2]     = o0;
    out4[(size_t)n * 32 + j8 * 2 + 1] = o1;
}

extern "C" void kernel_launch(void* const* d_in, const int* in_sizes, int n_in,
                              void* d_out, int out_size, void* d_ws, size_t ws_size,
                              hipStream_t stream) {
    const float* feat[4]  = {(const float*)d_in[0], (const float*)d_in[3],
                             (const float*)d_in[6], (const float*)d_in[9]};
    const float* W_fc[4]  = {(const float*)d_in[1], (const float*)d_in[4],
                             (const float*)d_in[7], (const float*)d_in[10]};
    const float* b_fc[4]  = {(const float*)d_in[2], (const float*)d_in[5],
                             (const float*)d_in[8], (const float*)d_in[11]};
    const int*   src      = (const int*)d_in[12];
    const int*   dst      = (const int*)d_in[13];
    const int*   efeat    = (const int*)d_in[14];
    const float* b_g0     = (const float*)d_in[15];
    const float* W_g1     = (const float*)d_in[16];
    const float* b_g1     = (const float*)d_in[17];
    float* out = (float*)d_out;

    // ---- workspace layout, ~49 MB ----
    char* p = (char*)d_ws;
    unsigned short* Abf = (unsigned short*)p; p += (size_t)N_NODES * HDIM * 2;  // 12.8 MB
    unsigned short* Bbf = (unsigned short*)p; p += (size_t)N_NODES * HDIM * 2;  // 12.8 MB
    unsigned short* Wp  = (unsigned short*)p; p += (size_t)65536 * 2;           // 128 KB
    int* bucket  = (int*)p; p += (size_t)E_EDGES * 4;            // 2.4 MB (dense CSR)
    int* bucketB = (int*)p; p += (size_t)E_EDGES * 4;            // 2.4 MB (dense CSR)
    unsigned short* partialS = (unsigned short*)p; p += (size_t)HQD * N_NODES * 2; // 6.4 MB
    unsigned short* partialD = (unsigned short*)p; p += (size_t)HQD * N_NODES * 2; // 6.4 MB
    unsigned char*  partialB = (unsigned char*)p;  p += (size_t)HQD * N_NODES;     // 3.2 MB
    int* degD  = (int*)p; p += (size_t)N_NODES * 4;              // 200 KB
    int* degB  = (int*)p; p += (size_t)N_NODES * 4;
    int* scanD = (int*)p; p += (size_t)N_NODES * 4;
    int* scanB = (int*)p; p += (size_t)N_NODES * 4;
    float* onrm_buf = (float*)p; p += (size_t)N_NODES * 4;
    int* blocksumD = (int*)p; p += 256 * 4;
    int* blocksumB = (int*)p; p += 256 * 4;

    const unsigned short* Wpg = Wp + 49152;

    // K0: fused D|B|S histogram (one edge pass) + weight packing
    prep_kernel<<<NBLK_DB + 32, 256, 0, stream>>>(
        W_fc[0], W_fc[1], W_fc[2], W_fc[3], W_g1, src, dst, efeat,
        Wp, partialS, partialD, partialB);

    // P1: plane prefix -> deg; node scan; deg_out sum -> onrm_buf
    plane_prefix_kernel<<<NBLK_NODE, 256, 0, stream>>>(
        partialD, partialB, partialS, degD, degB, scanD, scanB,
        blocksumD, blocksumB, onrm_buf);

    // P2: wide base add
    base_add_kernel<<<NBLK_NODE, 256, 0, stream>>>(
        blocksumD, blocksumB, scanD, scanB);

    // K1: fused counting-sort scatter + 4 FC GEMMs (mem/MFMA overlap)
    scatfc_kernel<<<NBLK_DB + NBLK_FC, 1024, 0, stream>>>(
        src, dst, efeat, partialD, partialB, scanD, scanB, bucket, bucketB,
        feat[0], feat[1], feat[2], feat[3], Wp,
        b_fc[0], b_fc[1], b_fc[2], b_fc[3], onrm_buf, Abf);

    const int grid_node = (N_NODES * 16) / 256;   // 3125 exact

    // K3: layer0 gather: Abf -> Bbf (B, carries out-norm)
    agg0_kernel<<<grid_node, 256, 0, stream>>>(
        (const uint4*)Abf, bucket, scanD, degD, onrm_buf, b_g0, (uint4*)Bbf);

    // K4a: dense BW = B @ W_g1: Bbf -> Abf (A dead after agg0)
    gemmg_kernel<<<NBLK_G, 256, 0, stream>>>(Bbf, Wpg, Abf);

    // K4b: layer1 gather over BW: Abf -> Bbf (H)
    agg1_kernel<<<grid_node, 256, 0, stream>>>(
        (const uint4*)Abf, bucket, scanD, degD, b_g1, (uint4*)Bbf);

    // K5: final edge-typed gather: Bbf (H) -> fp32 out
    final_kernel<<<grid_node, 256, 0, stream>>>(
        (const uint4*)Bbf, bucket, scanD, degD, bucketB, scanB, degB, (float4*)out);
}

// Round 8
// 233.640 us; speedup vs baseline: 1.7650x; 1.0827x over previous
//
#include <hip/hip_runtime.h>
#include <hip/hip_bf16.h>

#define N_NODES 50000
#define N_PER   12500
#define E_EDGES 600000
#define HDIM    128

#define NBLK_FC    ((N_PER + 63) / 64)            // 196
#define NBLK_NODE  ((N_NODES + 255) / 256)        // 196
#define MASK31  0x7fffffff

// counting-sort tiling: zero device atomics anywhere.
#define HQD 64                   // edge slices (single fused histogram pass)
#define HSL_D (E_EDGES / HQD)    // 9375
#define NBLK_DB (HQD * 4)        // 256 scatter/hist blocks

typedef __attribute__((ext_vector_type(8))) short bfrag;   // 8 bf16 (4 VGPRs)
typedef __attribute__((ext_vector_type(4))) float ffrag;   // 4 fp32 acc

__device__ __forceinline__ unsigned short f2bf(float f) {
    union { float f; unsigned u; } x; x.f = f;
    unsigned r = x.u + 0x7fffu + ((x.u >> 16) & 1u);   // RTNE
    return (unsigned short)(r >> 16);
}
__device__ __forceinline__ float lo_bf(unsigned v) { return __uint_as_float(v << 16); }
__device__ __forceinline__ float hi_bf(unsigned v) { return __uint_as_float(v & 0xffff0000u); }
__device__ __forceinline__ unsigned pack2(float a, float b) {
    return (unsigned)f2bf(a) | ((unsigned)f2bf(b) << 16);
}
__device__ __forceinline__ float onrm_of(int deg) {
    return rsqrtf(fmaxf((float)deg, 1.0f));
}

__device__ __forceinline__ void acc8_add(float* acc, uint4 v) {
    acc[0] += lo_bf(v.x); acc[1] += hi_bf(v.x);
    acc[2] += lo_bf(v.y); acc[3] += hi_bf(v.y);
    acc[4] += lo_bf(v.z); acc[5] += hi_bf(v.z);
    acc[6] += lo_bf(v.w); acc[7] += hi_bf(v.w);
}
__device__ __forceinline__ void acc8_addw(float* acc, uint4 v, float w) {
    acc[0] += lo_bf(v.x) * w; acc[1] += hi_bf(v.x) * w;
    acc[2] += lo_bf(v.y) * w; acc[3] += hi_bf(v.y) * w;
    acc[4] += lo_bf(v.z) * w; acc[5] += hi_bf(v.z) * w;
    acc[6] += lo_bf(v.w) * w; acc[7] += hi_bf(v.w) * w;
}

// ---------------------------------------------------------------------------
// K0 prep (1024 threads — hist blocks were 1 blk/CU at 256 thr, 4 waves):
//   blocks [0,256):   ONE fused histogram pass — LDS word packs
//                     D (bits 0..9) | B (10..15) | S (16..31).
//   blocks [256,264): weight fragment packing (same tid mapping as before)
// ---------------------------------------------------------------------------
__global__ __launch_bounds__(1024) void prep_kernel(
    const float* __restrict__ W0, const float* __restrict__ W1,
    const float* __restrict__ W2, const float* __restrict__ W3,
    const float* __restrict__ Wg,
    const int* __restrict__ src, const int* __restrict__ dst,
    const int* __restrict__ ef,
    unsigned short* __restrict__ Wp,
    unsigned short* __restrict__ partialS,
    unsigned short* __restrict__ partialD,
    unsigned char*  __restrict__ partialB) {
    __shared__ unsigned hist[N_PER];            // 50 KB
    int b = blockIdx.x;
    if (b < NBLK_DB) {                          // fused D|B|S histogram
        const int q = b >> 2;
        const int p = b & 3;
        const int g0 = p * N_PER;
        for (int j = threadIdx.x; j < N_PER; j += 1024) hist[j] = 0;
        __syncthreads();
        const int e0 = q * HSL_D;
        for (int i = e0 + threadIdx.x; i < e0 + HSL_D; i += 1024) {
            int d = dst[i], t = ef[i], s = src[i];
            unsigned rd = (unsigned)(d - g0);
            if (rd < (unsigned)N_PER) atomicAdd(&hist[rd], 1u);
            unsigned rs = (unsigned)(s - g0);
            if (rs < (unsigned)N_PER) {
                unsigned inc = 0x10000u
                             + ((t == 6 || t == 14 || t == 30) ? 0x400u : 0u);
                atomicAdd(&hist[rs], inc);
            }
        }
        __syncthreads();
        for (int j = threadIdx.x; j < N_PER; j += 1024) {
            unsigned h = hist[j];
            partialD[(size_t)q * N_NODES + g0 + j] = (unsigned short)(h & 0x3FFu);
            partialB[(size_t)q * N_NODES + g0 + j] = (unsigned char)((h >> 10) & 0x3Fu);
            partialS[(size_t)q * N_NODES + g0 + j] = (unsigned short)(h >> 16);
        }
    } else {                                    // weight packing
        int tid = (b - NBLK_DB) * 1024 + threadIdx.x;   // [0, 8192)
        const float* W; int D, base, off;
        if      (tid < 2048) { W = W0; D = 128; base = 0;    off = 0;     }
        else if (tid < 4096) { W = W1; D = 128; base = 2048; off = 16384; }
        else if (tid < 5120) { W = W2; D = 64;  base = 4096; off = 32768; }
        else if (tid < 6144) { W = W3; D = 64;  base = 5120; off = 40960; }
        else                 { W = Wg; D = 128; base = 6144; off = 49152; }
        int t2 = tid - base;
        int KT = D / 32;
        int l = t2 & 63;
        int tt = t2 >> 6;
        int kt = tt % KT, n0 = tt / KT;
        int n = n0 * 16 + (l & 15);
        int kb = kt * 32 + (l >> 4) * 8;
#pragma unroll
        for (int j = 0; j < 8; ++j)
            Wp[(size_t)off + (size_t)t2 * 8 + j] = f2bf(W[(size_t)(kb + j) * 128 + n]);
    }
}

// ---------------------------------------------------------------------------
// P1: per-node exclusive prefix over slice-planes (in place) -> degD/degB,
//     block-local node scan + block sums, AND deg_out sum -> onrm_buf.
// ---------------------------------------------------------------------------
__global__ __launch_bounds__(256) void plane_prefix_kernel(
    unsigned short* __restrict__ partialD, unsigned char* __restrict__ partialB,
    const unsigned short* __restrict__ partialS,
    int* __restrict__ degD, int* __restrict__ degB,
    int* __restrict__ scanD, int* __restrict__ scanB,
    int* __restrict__ blocksumD, int* __restrict__ blocksumB,
    float* __restrict__ onrm_buf) {
    const int t = threadIdx.x;
    const int n = blockIdx.x * 256 + t;
    int dD = 0, dB = 0;
    if (n < N_NODES) {
        int run = 0;
#pragma unroll
        for (int q = 0; q < HQD; ++q) {
            size_t ix = (size_t)q * N_NODES + n;
            int c = partialD[ix];
            partialD[ix] = (unsigned short)run;
            run += c;
        }
        dD = run; degD[n] = run;
        run = 0;
#pragma unroll
        for (int q = 0; q < HQD; ++q) {
            size_t ix = (size_t)q * N_NODES + n;
            int c = partialB[ix];
            partialB[ix] = (unsigned char)run;
            run += c;
        }
        dB = run; degB[n] = run;
        int dS = 0;
#pragma unroll
        for (int q = 0; q < HQD; ++q)
            dS += partialS[(size_t)q * N_NODES + n];
        onrm_buf[n] = onrm_of(dS);
    }
    __shared__ int sD[256], sB[256];
    sD[t] = dD; sB[t] = dB;
    __syncthreads();
    for (int off = 1; off < 256; off <<= 1) {     // Hillis-Steele inclusive
        int xD = (t >= off) ? sD[t - off] : 0;
        int xB = (t >= off) ? sB[t - off] : 0;
        __syncthreads();
        sD[t] += xD; sB[t] += xB;
        __syncthreads();
    }
    if (n < N_NODES) {
        scanD[n] = sD[t] - dD;                    // block-local exclusive
        scanB[n] = sB[t] - dB;
    }
    if (t == 255) {
        blocksumD[blockIdx.x] = sD[255];
        blocksumB[blockIdx.x] = sB[255];
    }
}

// ---------------------------------------------------------------------------
// P2: scan[n] += sum(blocksum[0..bid)). 196 wide blocks.
// ---------------------------------------------------------------------------
__global__ __launch_bounds__(256) void base_add_kernel(
    const int* __restrict__ blocksumD, const int* __restrict__ blocksumB,
    int* __restrict__ scanD, int* __restrict__ scanB) {
    __shared__ int sD[256], sB[256];
    const int t = threadIdx.x;
    const int bid = blockIdx.x;
    sD[t] = (t < bid) ? blocksumD[t] : 0;
    sB[t] = (t < bid) ? blocksumB[t] : 0;
    __syncthreads();
    for (int off = 128; off >= 1; off >>= 1) {
        if (t < off) { sD[t] += sD[t + off]; sB[t] += sB[t + off]; }
        __syncthreads();
    }
    const int n = bid * 256 + t;
    if (n < N_NODES) { scanD[n] += sD[0]; scanB[n] += sB[0]; }
}

// ---------------------------------------------------------------------------
// FC MFMA body: out = bf16( (X(rows x D) @ W + bias) * onrm[row] ); X fp32.
// tid must be in [0,256). No LDS, no sync — safe inside mixed blocks.
// ---------------------------------------------------------------------------
template<int D>
__device__ __forceinline__ void fc_body(
    int blk, int tid,
    const float* __restrict__ X,
    const unsigned short* __restrict__ Wp,
    const float* __restrict__ bias,
    const float* __restrict__ onrm,
    unsigned short* __restrict__ outbf,
    int rows)
{
    constexpr int KT = D / 32;
    const int lane = tid & 63;
    const int wave = tid >> 6;
    const int m = lane & 15, q = lane >> 4;
    const int rbase = blk * 64 + wave * 16;
    const int row = rbase + m;

    bfrag afr[KT];
#pragma unroll
    for (int kt = 0; kt < KT; ++kt) {
        bfrag a;
        if (row < rows) {
            const float* xp = X + (size_t)row * D + kt * 32 + q * 8;
            float4 u0 = *(const float4*)xp;
            float4 u1 = *(const float4*)(xp + 4);
            a[0] = (short)f2bf(u0.x); a[1] = (short)f2bf(u0.y);
            a[2] = (short)f2bf(u0.z); a[3] = (short)f2bf(u0.w);
            a[4] = (short)f2bf(u1.x); a[5] = (short)f2bf(u1.y);
            a[6] = (short)f2bf(u1.z); a[7] = (short)f2bf(u1.w);
        } else {
#pragma unroll
            for (int t = 0; t < 8; ++t) a[t] = 0;
        }
        afr[kt] = a;
    }

    ffrag acc[8];
#pragma unroll
    for (int n0 = 0; n0 < 8; ++n0)
#pragma unroll
        for (int t = 0; t < 4; ++t) acc[n0][t] = 0.f;

#pragma unroll
    for (int n0 = 0; n0 < 8; ++n0)
#pragma unroll
        for (int kt = 0; kt < KT; ++kt) {
            bfrag bfr = *(const bfrag*)(Wp + ((size_t)(n0 * KT + kt) * 64 + lane) * 8);
            acc[n0] = __builtin_amdgcn_mfma_f32_16x16x32_bf16(afr[kt], bfr, acc[n0], 0, 0, 0);
        }

#pragma unroll
    for (int n0 = 0; n0 < 8; ++n0) {
        const int col = n0 * 16 + m;
        const float bj = bias[col];
#pragma unroll
        for (int r = 0; r < 4; ++r) {
            int orow = rbase + q * 4 + r;
            if (orow < rows)
                outbf[(size_t)orow * 128 + col] =
                    f2bf((acc[n0][r] + bj) * onrm[orow]);
        }
    }
}

// ---------------------------------------------------------------------------
// K1: fused scatter + FC. 1024-thread blocks.
//   blocks [0,256):   counting-sort scatter (LDS atomics, 50 KB offP)
//   blocks [256,452): 4 FC 64-row tiles each (tid>>8 selects tile).
// ---------------------------------------------------------------------------
__global__ __launch_bounds__(1024) void scatfc_kernel(
    const int* __restrict__ src, const int* __restrict__ dst,
    const int* __restrict__ ef,
    const unsigned short* __restrict__ prefD,
    const unsigned char*  __restrict__ prefB,
    const int* __restrict__ scanD, const int* __restrict__ scanB,
    int* __restrict__ bucket, int* __restrict__ bucketB,
    const float* __restrict__ f0, const float* __restrict__ f1,
    const float* __restrict__ f2, const float* __restrict__ f3,
    const unsigned short* __restrict__ Wp,
    const float* __restrict__ b0, const float* __restrict__ b1,
    const float* __restrict__ b2, const float* __restrict__ b3,
    const float* __restrict__ onrm_buf,
    unsigned short* __restrict__ Abf)
{
    __shared__ unsigned offP[N_PER];   // absD (20b) | relB (12b)
    const int b = blockIdx.x;
    if (b < NBLK_DB) {
        const int q = b >> 2;
        const int p = b & 3;
        const int g0 = p * N_PER;
        for (int j = threadIdx.x; j < N_PER; j += 1024)
            offP[j] = (unsigned)(scanD[g0 + j] + (int)prefD[(size_t)q * N_NODES + g0 + j])
                    | ((unsigned)prefB[(size_t)q * N_NODES + g0 + j] << 20);
        __syncthreads();
        const int e0 = q * HSL_D;
        for (int i = e0 + threadIdx.x; i < e0 + HSL_D; i += 1024) {
            int s = src[i], d = dst[i], t = ef[i];
            unsigned rd = (unsigned)(d - g0);
            if (rd < (unsigned)N_PER) {
                unsigned old = atomicAdd(&offP[rd], 1u);          // LDS atomic
                bucket[old & 0xFFFFFu] = s | ((t <= 4) ? 0x80000000 : 0);
            }
            if (t == 6 || t == 14 || t == 30) {
                unsigned rs = (unsigned)(s - g0);
                if (rs < (unsigned)N_PER) {
                    unsigned old = atomicAdd(&offP[rs], 1u << 20);
                    bucketB[scanB[s] + (int)(old >> 20)] = d;
                }
            }
        }
    } else {
        int ft = (b - NBLK_DB) * 4 + (threadIdx.x >> 8);   // 0..783
        int tid = threadIdx.x & 255;
        int which = ft / NBLK_FC;
        int blk = ft - which * NBLK_FC;
        if (which == 0)
            fc_body<128>(blk, tid, f0, Wp,         b0, onrm_buf,
                         Abf + (size_t)0 * N_PER * HDIM, N_PER);
        else if (which == 1)
            fc_body<128>(blk, tid, f1, Wp + 16384, b1, onrm_buf + N_PER,
                         Abf + (size_t)1 * N_PER * HDIM, N_PER);
        else if (which == 2)
            fc_body<64>(blk, tid, f2, Wp + 32768, b2, onrm_buf + 2 * N_PER,
                        Abf + (size_t)2 * N_PER * HDIM, N_PER);
        else
            fc_body<64>(blk, tid, f3, Wp + 40960, b3, onrm_buf + 3 * N_PER,
                        Abf + (size_t)3 * N_PER * HDIM, N_PER);
    }
}

// ---------------------------------------------------------------------------
// K3: FUSED layer-0 gather + dense GEMM with W_g1 (agg/matmul commute).
//   Block = 16 nodes. Gather phase (j8 layout, unroll-8) computes B rows,
//   stages the 16x128 bf16 tile in LDS ([j8][node] 16B-block layout:
//   both the write and the MFMA A-frag ds_read_b128 are contiguous 256B,
//   conflict-free). MFMA phase: 4 waves x 2 col-tiles x 4 kt.
//   Writes BW = B @ W_g1 directly — kills the B round-trip + gemmg launch.
// ---------------------------------------------------------------------------
__global__ __launch_bounds__(256) void agg0g_kernel(
    const uint4* __restrict__ A,
    const int* __restrict__ bucket, const int* __restrict__ scanD,
    const int* __restrict__ degD,
    const float* __restrict__ onrm_buf, const float* __restrict__ b_g0,
    const unsigned short* __restrict__ Wp,
    unsigned short* __restrict__ BW) {
    __shared__ uint4 Bt[256];          // 4 KB: idx = j8*16 + node_local
    const int tdx = threadIdx.x;
    const int nloc = tdx >> 4, j8 = tdx & 15;
    const int n = blockIdx.x * 16 + nloc;

    const int cnt = degD[n];
    const int* bk = bucket + scanD[n];
    float acc[8] = {0.f, 0.f, 0.f, 0.f, 0.f, 0.f, 0.f, 0.f};
    int i = 0;
    for (; i + 8 <= cnt; i += 8) {
        uint4 v[8];
#pragma unroll
        for (int k = 0; k < 8; ++k)
            v[k] = A[(size_t)(bk[i + k] & MASK31) * 16 + j8];
#pragma unroll
        for (int k = 0; k < 8; ++k) acc8_add(acc, v[k]);
    }
    if (i + 4 <= cnt) {
        uint4 v[4];
#pragma unroll
        for (int k = 0; k < 4; ++k)
            v[k] = A[(size_t)(bk[i + k] & MASK31) * 16 + j8];
#pragma unroll
        for (int k = 0; k < 4; ++k) acc8_add(acc, v[k]);
        i += 4;
    }
    for (; i < cnt; ++i)
        acc8_add(acc, A[(size_t)(bk[i] & MASK31) * 16 + j8]);

    float inr = onrm_of(cnt);
    float onr = onrm_buf[n];
    const float* bg = b_g0 + j8 * 8;
    float r[8];
#pragma unroll
    for (int k = 0; k < 8; ++k)
        r[k] = fmaxf(acc[k] * inr + bg[k], 0.f) * onr;
    uint4 o;
    o.x = pack2(r[0], r[1]); o.y = pack2(r[2], r[3]);
    o.z = pack2(r[4], r[5]); o.w = pack2(r[6], r[7]);
    Bt[j8 * 16 + nloc] = o;
    __syncthreads();

    // MFMA phase: wave w -> col tiles n0 = 2w, 2w+1
    const int lane = tdx & 63;
    const int wave = tdx >> 6;
    const int m = lane & 15, q = lane >> 4;

    bfrag afr[4];
#pragma unroll
    for (int kt = 0; kt < 4; ++kt)
        afr[kt] = *(const bfrag*)(Bt + (kt * 4 + q) * 16 + m);

    ffrag acc2[2];
#pragma unroll
    for (int t2 = 0; t2 < 2; ++t2) {
#pragma unroll
        for (int t = 0; t < 4; ++t) acc2[t2][t] = 0.f;
        const int n0 = wave * 2 + t2;
#pragma unroll
        for (int kt = 0; kt < 4; ++kt) {
            bfrag bfr = *(const bfrag*)(Wp + ((size_t)(n0 * 4 + kt) * 64 + lane) * 8);
            acc2[t2] = __builtin_amdgcn_mfma_f32_16x16x32_bf16(afr[kt], bfr, acc2[t2], 0, 0, 0);
        }
    }

    const int rowbase = blockIdx.x * 16;
#pragma unroll
    for (int t2 = 0; t2 < 2; ++t2) {
        const int col = (wave * 2 + t2) * 16 + m;
#pragma unroll
        for (int rr = 0; rr < 4; ++rr) {
            const int row = rowbase + q * 4 + rr;
            BW[(size_t)row * 128 + col] = f2bf(acc2[t2][rr]);
        }
    }
}

// ---------------------------------------------------------------------------
// K4: layer-1 gather over BW, unroll-8.
//   H[n] = bf16( relu( (sum BW[s]) * inrm(n) + b_g1 ) )
// ---------------------------------------------------------------------------
__global__ __launch_bounds__(256) void agg1_kernel(
    const uint4* __restrict__ BW,
    const int* __restrict__ bucket, const int* __restrict__ scanD,
    const int* __restrict__ degD,
    const float* __restrict__ b_g1,
    uint4* __restrict__ H) {
    int idx = blockIdx.x * blockDim.x + threadIdx.x;
    int n = idx >> 4, j8 = idx & 15;
    const int cnt = degD[n];
    const int* bk = bucket + scanD[n];
    float acc[8] = {0.f, 0.f, 0.f, 0.f, 0.f, 0.f, 0.f, 0.f};
    int i = 0;
    for (; i + 8 <= cnt; i += 8) {
        uint4 v[8];
#pragma unroll
        for (int k = 0; k < 8; ++k)
            v[k] = BW[(size_t)(bk[i + k] & MASK31) * 16 + j8];
#pragma unroll
        for (int k = 0; k < 8; ++k) acc8_add(acc, v[k]);
    }
    if (i + 4 <= cnt) {
        uint4 v[4];
#pragma unroll
        for (int k = 0; k < 4; ++k)
            v[k] = BW[(size_t)(bk[i + k] & MASK31) * 16 + j8];
#pragma unroll
        for (int k = 0; k < 4; ++k) acc8_add(acc, v[k]);
        i += 4;
    }
    for (; i < cnt; ++i)
        acc8_add(acc, BW[(size_t)(bk[i] & MASK31) * 16 + j8]);
    float inr = onrm_of(cnt);
    const float* bg = b_g1 + j8 * 8;
    float r[8];
#pragma unroll
    for (int k = 0; k < 8; ++k)
        r[k] = fmaxf(acc[k] * inr + bg[k], 0.f);
    uint4 o;
    o.x = pack2(r[0], r[1]); o.y = pack2(r[2], r[3]);
    o.z = pack2(r[4], r[5]); o.w = pack2(r[6], r[7]);
    H[(size_t)n * 16 + j8] = o;
}

// ---------------------------------------------------------------------------
// K5: final edge-typed gather (dense CSR fwd + bwd), unroll-8 -> fp32 out.
// ---------------------------------------------------------------------------
__global__ __launch_bounds__(256) void final_kernel(
    const uint4* __restrict__ H,
    const int* __restrict__ bucket, const int* __restrict__ scanD,
    const int* __restrict__ degD,
    const int* __restrict__ bucketB, const int* __restrict__ scanB,
    const int* __restrict__ degB,
    float4* __restrict__ out4) {
    int idx = blockIdx.x * blockDim.x + threadIdx.x;
    int n = idx >> 4, j8 = idx & 15;
    float acc[8] = {0.f, 0.f, 0.f, 0.f, 0.f, 0.f, 0.f, 0.f};
    const int cnt = degD[n];
    const int* bk = bucket + scanD[n];
    int i = 0;
    for (; i + 8 <= cnt; i += 8) {
        int c[8]; uint4 v[8];
#pragma unroll
        for (int k = 0; k < 8; ++k) c[k] = bk[i + k];
#pragma unroll
        for (int k = 0; k < 8; ++k)
            v[k] = H[(size_t)(c[k] & MASK31) * 16 + j8];
#pragma unroll
        for (int k = 0; k < 8; ++k)
            acc8_addw(acc, v[k], (c[k] < 0) ? 2.0f : 1.0f);
    }
    if (i + 4 <= cnt) {
        int c[4]; uint4 v[4];
#pragma unroll
        for (int k = 0; k < 4; ++k) c[k] = bk[i + k];
#pragma unroll
        for (int k = 0; k < 4; ++k)
            v[k] = H[(size_t)(c[k] & MASK31) * 16 + j8];
#pragma unroll
        for (int k = 0; k < 4; ++k)
            acc8_addw(acc, v[k], (c[k] < 0) ? 2.0f : 1.0f);
        i += 4;
    }
    for (; i < cnt; ++i) {
        int c = bk[i];
        acc8_addw(acc, H[(size_t)(c & MASK31) * 16 + j8], (c < 0) ? 2.0f : 1.0f);
    }
    const int cb = degB[n];
    const int* bkB = bucketB + scanB[n];
    for (int k = 0; k < cb; ++k) {
        int d = bkB[k];
        acc8_add(acc, H[(size_t)d * 16 + j8]);
    }
    float4 o0 = {acc[0], acc[1], acc[2], acc[3]};
    float4 o1 = {acc[4], acc[5], acc[6], acc[7]};
    out4[(size_t)n * 32 + j8 * 2]     = o0;
    out4[(size_t)n * 32 + j8 * 2 + 1] = o1;
}

extern "C" void kernel_launch(void* const* d_in, const int* in_sizes, int n_in,
                              void* d_out, int out_size, void* d_ws, size_t ws_size,
                              hipStream_t stream) {
    const float* feat[4]  = {(const float*)d_in[0], (const float*)d_in[3],
                             (const float*)d_in[6], (const float*)d_in[9]};
    const float* W_fc[4]  = {(const float*)d_in[1], (const float*)d_in[4],
                             (const float*)d_in[7], (const float*)d_in[10]};
    const float* b_fc[4]  = {(const float*)d_in[2], (const float*)d_in[5],
                             (const float*)d_in[8], (const float*)d_in[11]};
    const int*   src      = (const int*)d_in[12];
    const int*   dst      = (const int*)d_in[13];
    const int*   efeat    = (const int*)d_in[14];
    const float* b_g0     = (const float*)d_in[15];
    const float* W_g1     = (const float*)d_in[16];
    const float* b_g1     = (const float*)d_in[17];
    float* out = (float*)d_out;

    // ---- workspace layout, ~49 MB ----
    char* p = (char*)d_ws;
    unsigned short* Abf = (unsigned short*)p; p += (size_t)N_NODES * HDIM * 2;  // 12.8 MB
    unsigned short* Bbf = (unsigned short*)p; p += (size_t)N_NODES * HDIM * 2;  // 12.8 MB
    unsigned short* Wp  = (unsigned short*)p; p += (size_t)65536 * 2;           // 128 KB
    int* bucket  = (int*)p; p += (size_t)E_EDGES * 4;            // 2.4 MB (dense CSR)
    int* bucketB = (int*)p; p += (size_t)E_EDGES * 4;            // 2.4 MB (dense CSR)
    unsigned short* partialS = (unsigned short*)p; p += (size_t)HQD * N_NODES * 2; // 6.4 MB
    unsigned short* partialD = (unsigned short*)p; p += (size_t)HQD * N_NODES * 2; // 6.4 MB
    unsigned char*  partialB = (unsigned char*)p;  p += (size_t)HQD * N_NODES;     // 3.2 MB
    int* degD  = (int*)p; p += (size_t)N_NODES * 4;              // 200 KB
    int* degB  = (int*)p; p += (size_t)N_NODES * 4;
    int* scanD = (int*)p; p += (size_t)N_NODES * 4;
    int* scanB = (int*)p; p += (size_t)N_NODES * 4;
    float* onrm_buf = (float*)p; p += (size_t)N_NODES * 4;
    int* blocksumD = (int*)p; p += 256 * 4;
    int* blocksumB = (int*)p; p += 256 * 4;

    const unsigned short* Wpg = Wp + 49152;

    // K0: fused D|B|S histogram (one edge pass, 1024 thr) + weight packing
    prep_kernel<<<NBLK_DB + 8, 1024, 0, stream>>>(
        W_fc[0], W_fc[1], W_fc[2], W_fc[3], W_g1, src, dst, efeat,
        Wp, partialS, partialD, partialB);

    // P1: plane prefix -> deg; node scan; deg_out sum -> onrm_buf
    plane_prefix_kernel<<<NBLK_NODE, 256, 0, stream>>>(
        partialD, partialB, partialS, degD, degB, scanD, scanB,
        blocksumD, blocksumB, onrm_buf);

    // P2: wide base add
    base_add_kernel<<<NBLK_NODE, 256, 0, stream>>>(
        blocksumD, blocksumB, scanD, scanB);

    // K1: fused counting-sort scatter + 4 FC GEMMs (mem/MFMA overlap)
    scatfc_kernel<<<NBLK_DB + NBLK_FC, 1024, 0, stream>>>(
        src, dst, efeat, partialD, partialB, scanD, scanB, bucket, bucketB,
        feat[0], feat[1], feat[2], feat[3], Wp,
        b_fc[0], b_fc[1], b_fc[2], b_fc[3], onrm_buf, Abf);

    const int grid_node = (N_NODES * 16) / 256;   // 3125 exact

    // K3: fused layer0 gather + GEMM(W_g1): Abf -> Bbf (BW)
    agg0g_kernel<<<grid_node, 256, 0, stream>>>(
        (const uint4*)Abf, bucket, scanD, degD, onrm_buf, b_g0, Wpg,
        Bbf);

    // K4: layer1 gather over BW: Bbf -> Abf (H)
    agg1_kernel<<<grid_node, 256, 0, stream>>>(
        (const uint4*)Bbf, bucket, scanD, degD, b_g1, (uint4*)Abf);

    // K5: final edge-typed gather: Abf (H) -> fp32 out
    final_kernel<<<grid_node, 256, 0, stream>>>(
        (const uint4*)Abf, bucket, scanD, degD, bucketB, scanB, degB, (float4*)out);
}

// Round 9
// 226.192 us; speedup vs baseline: 1.8231x; 1.0329x over previous
//
#include <hip/hip_runtime.h>
#include <hip/hip_bf16.h>

#define N_NODES 50000
#define N_PER   12500
#define E_EDGES 600000
#define HDIM    128

#define NBLK_FC    ((N_PER + 63) / 64)            // 196
#define NBLK_NODE  ((N_NODES + 255) / 256)        // 196
#define MASK31  0x7fffffff

// counting-sort tiling: zero device atomics anywhere.
#define HQD 64                   // edge slices (single fused histogram pass)
#define HSL_D (E_EDGES / HQD)    // 9375
#define NBLK_DB (HQD * 4)        // 256 scatter/hist blocks

typedef __attribute__((ext_vector_type(8))) short bfrag;   // 8 bf16 (4 VGPRs)
typedef __attribute__((ext_vector_type(4))) float ffrag;   // 4 fp32 acc

__device__ __forceinline__ unsigned short f2bf(float f) {
    union { float f; unsigned u; } x; x.f = f;
    unsigned r = x.u + 0x7fffu + ((x.u >> 16) & 1u);   // RTNE
    return (unsigned short)(r >> 16);
}
__device__ __forceinline__ float lo_bf(unsigned v) { return __uint_as_float(v << 16); }
__device__ __forceinline__ float hi_bf(unsigned v) { return __uint_as_float(v & 0xffff0000u); }
__device__ __forceinline__ unsigned pack2(float a, float b) {
    return (unsigned)f2bf(a) | ((unsigned)f2bf(b) << 16);
}
__device__ __forceinline__ float onrm_of(int deg) {
    return rsqrtf(fmaxf((float)deg, 1.0f));
}

__device__ __forceinline__ void acc8_add(float* acc, uint4 v) {
    acc[0] += lo_bf(v.x); acc[1] += hi_bf(v.x);
    acc[2] += lo_bf(v.y); acc[3] += hi_bf(v.y);
    acc[4] += lo_bf(v.z); acc[5] += hi_bf(v.z);
    acc[6] += lo_bf(v.w); acc[7] += hi_bf(v.w);
}
__device__ __forceinline__ void acc8_addw(float* acc, uint4 v, float w) {
    acc[0] += lo_bf(v.x) * w; acc[1] += hi_bf(v.x) * w;
    acc[2] += lo_bf(v.y) * w; acc[3] += hi_bf(v.y) * w;
    acc[4] += lo_bf(v.z) * w; acc[5] += hi_bf(v.z) * w;
    acc[6] += lo_bf(v.w) * w; acc[7] += hi_bf(v.w) * w;
}

// ---------------------------------------------------------------------------
// K0 prep (1024 threads):
//   blocks [0,256):   fused histogram — ONE packed uint32 plane array:
//                     D (bits 0..9) | B (10..15) | S (16..31). Per-slice
//                     per-node counts <= ~10, so field carries impossible.
//   blocks [256,264): weight fragment packing
// ---------------------------------------------------------------------------
__global__ __launch_bounds__(1024) void prep_kernel(
    const float* __restrict__ W0, const float* __restrict__ W1,
    const float* __restrict__ W2, const float* __restrict__ W3,
    const float* __restrict__ Wg,
    const int* __restrict__ src, const int* __restrict__ dst,
    const int* __restrict__ ef,
    unsigned short* __restrict__ Wp,
    unsigned* __restrict__ partial) {
    __shared__ unsigned hist[N_PER];            // 50 KB
    int b = blockIdx.x;
    if (b < NBLK_DB) {                          // fused D|B|S histogram
        const int q = b >> 2;
        const int p = b & 3;
        const int g0 = p * N_PER;
        for (int j = threadIdx.x; j < N_PER; j += 1024) hist[j] = 0;
        __syncthreads();
        const int e0 = q * HSL_D;
        for (int i = e0 + threadIdx.x; i < e0 + HSL_D; i += 1024) {
            int d = dst[i], t = ef[i], s = src[i];
            unsigned rd = (unsigned)(d - g0);
            if (rd < (unsigned)N_PER) atomicAdd(&hist[rd], 1u);
            unsigned rs = (unsigned)(s - g0);
            if (rs < (unsigned)N_PER) {
                unsigned inc = 0x10000u
                             + ((t == 6 || t == 14 || t == 30) ? 0x400u : 0u);
                atomicAdd(&hist[rs], inc);
            }
        }
        __syncthreads();
        for (int j = threadIdx.x; j < N_PER; j += 1024)
            partial[(size_t)q * N_NODES + g0 + j] = hist[j];
    } else {                                    // weight packing
        int tid = (b - NBLK_DB) * 1024 + threadIdx.x;   // [0, 8192)
        const float* W; int D, base, off;
        if      (tid < 2048) { W = W0; D = 128; base = 0;    off = 0;     }
        else if (tid < 4096) { W = W1; D = 128; base = 2048; off = 16384; }
        else if (tid < 5120) { W = W2; D = 64;  base = 4096; off = 32768; }
        else if (tid < 6144) { W = W3; D = 64;  base = 5120; off = 40960; }
        else                 { W = Wg; D = 128; base = 6144; off = 49152; }
        int t2 = tid - base;
        int KT = D / 32;
        int l = t2 & 63;
        int tt = t2 >> 6;
        int kt = tt % KT, n0 = tt / KT;
        int n = n0 * 16 + (l & 15);
        int kb = kt * 32 + (l >> 4) * 8;
#pragma unroll
        for (int j = 0; j < 8; ++j)
            Wp[(size_t)off + (size_t)t2 * 8 + j] = f2bf(W[(size_t)(kb + j) * 128 + n]);
    }
}

// ---------------------------------------------------------------------------
// P1: ONE pass over the 64 packed planes: in-place rewrite to per-slice
//     exclusive prefixes (relD | relB<<10; S field zeroed), true degD/degB,
//     deg_out sum -> onrm_buf, 16B-ALIGNED block-local scan for D
//     (degA=(deg+3)&~3 -> every CSR segment starts on a 16B boundary),
//     plain scan for B, per-block sums.
// ---------------------------------------------------------------------------
__global__ __launch_bounds__(256) void plane_prefix_kernel(
    unsigned* __restrict__ partial,
    int* __restrict__ degD, int* __restrict__ degB,
    int* __restrict__ scanD, int* __restrict__ scanB,
    int* __restrict__ blocksumD, int* __restrict__ blocksumB,
    float* __restrict__ onrm_buf) {
    const int t = threadIdx.x;
    const int n = blockIdx.x * 256 + t;
    int dA = 0, dD = 0, dB = 0;
    if (n < N_NODES) {
        int runD = 0, runB = 0, dS = 0;
#pragma unroll
        for (int q = 0; q < HQD; ++q) {
            size_t ix = (size_t)q * N_NODES + n;
            unsigned w = partial[ix];
            partial[ix] = (unsigned)runD | ((unsigned)runB << 10);
            runD += (int)(w & 0x3FFu);
            runB += (int)((w >> 10) & 0x3Fu);
            dS   += (int)(w >> 16);
        }
        dD = runD; dB = runB;
        degD[n] = dD; degB[n] = dB;
        onrm_buf[n] = onrm_of(dS);
        dA = (dD + 3) & ~3;                      // 16B-aligned segment size
    }
    __shared__ int sD[256], sB[256];
    sD[t] = dA; sB[t] = dB;
    __syncthreads();
    for (int off = 1; off < 256; off <<= 1) {     // Hillis-Steele inclusive
        int xD = (t >= off) ? sD[t - off] : 0;
        int xB = (t >= off) ? sB[t - off] : 0;
        __syncthreads();
        sD[t] += xD; sB[t] += xB;
        __syncthreads();
    }
    if (n < N_NODES) {
        scanD[n] = sD[t] - dA;                    // block-local exclusive
        scanB[n] = sB[t] - dB;
    }
    if (t == 255) {
        blocksumD[blockIdx.x] = sD[255];
        blocksumB[blockIdx.x] = sB[255];
    }
}

// ---------------------------------------------------------------------------
// P2: add block bases and emit interleaved CSR descriptors
//     csrD[n] = {abs base (16B-aligned), true deg}; csrB likewise.
// ---------------------------------------------------------------------------
__global__ __launch_bounds__(256) void base_add_kernel(
    const int* __restrict__ blocksumD, const int* __restrict__ blocksumB,
    const int* __restrict__ scanD, const int* __restrict__ scanB,
    const int* __restrict__ degD, const int* __restrict__ degB,
    int2* __restrict__ csrD, int2* __restrict__ csrB) {
    __shared__ int sD[256], sB[256];
    const int t = threadIdx.x;
    const int bid = blockIdx.x;
    sD[t] = (t < bid) ? blocksumD[t] : 0;
    sB[t] = (t < bid) ? blocksumB[t] : 0;
    __syncthreads();
    for (int off = 128; off >= 1; off >>= 1) {
        if (t < off) { sD[t] += sD[t + off]; sB[t] += sB[t + off]; }
        __syncthreads();
    }
    const int n = bid * 256 + t;
    if (n < N_NODES) {
        csrD[n] = make_int2(scanD[n] + sD[0], degD[n]);
        csrB[n] = make_int2(scanB[n] + sB[0], degB[n]);
    }
}

// ---------------------------------------------------------------------------
// FC MFMA body: out = bf16( (X(rows x D) @ W + bias) * onrm[row] ); X fp32.
// tid must be in [0,256). No LDS, no sync — safe inside mixed blocks.
// ---------------------------------------------------------------------------
template<int D>
__device__ __forceinline__ void fc_body(
    int blk, int tid,
    const float* __restrict__ X,
    const unsigned short* __restrict__ Wp,
    const float* __restrict__ bias,
    const float* __restrict__ onrm,
    unsigned short* __restrict__ outbf,
    int rows)
{
    constexpr int KT = D / 32;
    const int lane = tid & 63;
    const int wave = tid >> 6;
    const int m = lane & 15, q = lane >> 4;
    const int rbase = blk * 64 + wave * 16;
    const int row = rbase + m;

    bfrag afr[KT];
#pragma unroll
    for (int kt = 0; kt < KT; ++kt) {
        bfrag a;
        if (row < rows) {
            const float* xp = X + (size_t)row * D + kt * 32 + q * 8;
            float4 u0 = *(const float4*)xp;
            float4 u1 = *(const float4*)(xp + 4);
            a[0] = (short)f2bf(u0.x); a[1] = (short)f2bf(u0.y);
            a[2] = (short)f2bf(u0.z); a[3] = (short)f2bf(u0.w);
            a[4] = (short)f2bf(u1.x); a[5] = (short)f2bf(u1.y);
            a[6] = (short)f2bf(u1.z); a[7] = (short)f2bf(u1.w);
        } else {
#pragma unroll
            for (int t = 0; t < 8; ++t) a[t] = 0;
        }
        afr[kt] = a;
    }

    ffrag acc[8];
#pragma unroll
    for (int n0 = 0; n0 < 8; ++n0)
#pragma unroll
        for (int t = 0; t < 4; ++t) acc[n0][t] = 0.f;

#pragma unroll
    for (int n0 = 0; n0 < 8; ++n0)
#pragma unroll
        for (int kt = 0; kt < KT; ++kt) {
            bfrag bfr = *(const bfrag*)(Wp + ((size_t)(n0 * KT + kt) * 64 + lane) * 8);
            acc[n0] = __builtin_amdgcn_mfma_f32_16x16x32_bf16(afr[kt], bfr, acc[n0], 0, 0, 0);
        }

#pragma unroll
    for (int n0 = 0; n0 < 8; ++n0) {
        const int col = n0 * 16 + m;
        const float bj = bias[col];
#pragma unroll
        for (int r = 0; r < 4; ++r) {
            int orow = rbase + q * 4 + r;
            if (orow < rows)
                outbf[(size_t)orow * 128 + col] =
                    f2bf((acc[n0][r] + bj) * onrm[orow]);
        }
    }
}

// ---------------------------------------------------------------------------
// K1: fused scatter + FC. 1024-thread blocks.
//   blocks [0,256):   counting-sort scatter (LDS atomics, 50 KB offP;
//                     offP = abs 16B-aligned D slot (20b, max 750k) | relB (12b))
//   blocks [256,452): 4 FC 64-row tiles each (tid>>8 selects tile).
// ---------------------------------------------------------------------------
__global__ __launch_bounds__(1024) void scatfc_kernel(
    const int* __restrict__ src, const int* __restrict__ dst,
    const int* __restrict__ ef,
    const unsigned* __restrict__ partial,
    const int2* __restrict__ csrD, const int2* __restrict__ csrB,
    int* __restrict__ bucket, int* __restrict__ bucketB,
    const float* __restrict__ f0, const float* __restrict__ f1,
    const float* __restrict__ f2, const float* __restrict__ f3,
    const unsigned short* __restrict__ Wp,
    const float* __restrict__ b0, const float* __restrict__ b1,
    const float* __restrict__ b2, const float* __restrict__ b3,
    const float* __restrict__ onrm_buf,
    unsigned short* __restrict__ Abf)
{
    __shared__ unsigned offP[N_PER];   // absD (20b) | relB (12b)
    const int b = blockIdx.x;
    if (b < NBLK_DB) {
        const int q = b >> 2;
        const int p = b & 3;
        const int g0 = p * N_PER;
        for (int j = threadIdx.x; j < N_PER; j += 1024) {
            unsigned w = partial[(size_t)q * N_NODES + g0 + j];
            offP[j] = (unsigned)(csrD[g0 + j].x + (int)(w & 0x3FFu))
                    | (((w >> 10) & 0x3Fu) << 20);
        }
        __syncthreads();
        const int e0 = q * HSL_D;
        for (int i = e0 + threadIdx.x; i < e0 + HSL_D; i += 1024) {
            int s = src[i], d = dst[i], t = ef[i];
            unsigned rd = (unsigned)(d - g0);
            if (rd < (unsigned)N_PER) {
                unsigned old = atomicAdd(&offP[rd], 1u);          // LDS atomic
                bucket[old & 0xFFFFFu] = s | ((t <= 4) ? 0x80000000 : 0);
            }
            if (t == 6 || t == 14 || t == 30) {
                unsigned rs = (unsigned)(s - g0);
                if (rs < (unsigned)N_PER) {
                    unsigned old = atomicAdd(&offP[rs], 1u << 20);
                    bucketB[csrB[s].x + (int)(old >> 20)] = d;
                }
            }
        }
    } else {
        int ft = (b - NBLK_DB) * 4 + (threadIdx.x >> 8);   // 0..783
        int tid = threadIdx.x & 255;
        int which = ft / NBLK_FC;
        int blk = ft - which * NBLK_FC;
        if (which == 0)
            fc_body<128>(blk, tid, f0, Wp,         b0, onrm_buf,
                         Abf + (size_t)0 * N_PER * HDIM, N_PER);
        else if (which == 1)
            fc_body<128>(blk, tid, f1, Wp + 16384, b1, onrm_buf + N_PER,
                         Abf + (size_t)1 * N_PER * HDIM, N_PER);
        else if (which == 2)
            fc_body<64>(blk, tid, f2, Wp + 32768, b2, onrm_buf + 2 * N_PER,
                        Abf + (size_t)2 * N_PER * HDIM, N_PER);
        else
            fc_body<64>(blk, tid, f3, Wp + 40960, b3, onrm_buf + 3 * N_PER,
                        Abf + (size_t)3 * N_PER * HDIM, N_PER);
    }
}

// ---------------------------------------------------------------------------
// Gather core: 16B-aligned CSR base -> int4 index loads (2 per 8 edges).
// ---------------------------------------------------------------------------
#define GATHER8(DSTARR)                                                       \
    for (; i + 8 <= cnt; i += 8) {                                            \
        int4 c0 = *(const int4*)(bk + i);                                     \
        int4 c1 = *(const int4*)(bk + i + 4);                                 \
        int cc[8] = {c0.x, c0.y, c0.z, c0.w, c1.x, c1.y, c1.z, c1.w};         \
        uint4 v[8];                                                           \
        _Pragma("unroll")                                                     \
        for (int k = 0; k < 8; ++k)                                           \
            v[k] = DSTARR[(size_t)(cc[k] & MASK31) * 16 + j8];                \
        _Pragma("unroll")                                                     \
        for (int k = 0; k < 8; ++k) acc8_add(acc, v[k]);                      \
    }                                                                         \
    if (i + 4 <= cnt) {                                                       \
        int4 c0 = *(const int4*)(bk + i);                                     \
        int cc[4] = {c0.x, c0.y, c0.z, c0.w};                                 \
        uint4 v[4];                                                           \
        _Pragma("unroll")                                                     \
        for (int k = 0; k < 4; ++k)                                           \
            v[k] = DSTARR[(size_t)(cc[k] & MASK31) * 16 + j8];                \
        _Pragma("unroll")                                                     \
        for (int k = 0; k < 4; ++k) acc8_add(acc, v[k]);                      \
        i += 4;                                                               \
    }                                                                         \
    for (; i < cnt; ++i)                                                      \
        acc8_add(acc, DSTARR[(size_t)(bk[i] & MASK31) * 16 + j8]);

// ---------------------------------------------------------------------------
// K3: FUSED layer-0 gather + dense GEMM with W_g1 (agg/matmul commute).
//   Block = 16 nodes. Writes BW = B @ W_g1 directly.
// ---------------------------------------------------------------------------
__global__ __launch_bounds__(256) void agg0g_kernel(
    const uint4* __restrict__ A,
    const int* __restrict__ bucket, const int2* __restrict__ csrD,
    const float* __restrict__ onrm_buf, const float* __restrict__ b_g0,
    const unsigned short* __restrict__ Wp,
    unsigned short* __restrict__ BW) {
    __shared__ uint4 Bt[256];          // 4 KB: idx = j8*16 + node_local
    const int tdx = threadIdx.x;
    const int nloc = tdx >> 4, j8 = tdx & 15;
    const int n = blockIdx.x * 16 + nloc;

    const int2 cd = csrD[n];
    const int cnt = cd.y;
    const int* bk = bucket + cd.x;
    float acc[8] = {0.f, 0.f, 0.f, 0.f, 0.f, 0.f, 0.f, 0.f};
    int i = 0;
    GATHER8(A)

    float inr = onrm_of(cnt);
    float onr = onrm_buf[n];
    const float* bg = b_g0 + j8 * 8;
    float r[8];
#pragma unroll
    for (int k = 0; k < 8; ++k)
        r[k] = fmaxf(acc[k] * inr + bg[k], 0.f) * onr;
    uint4 o;
    o.x = pack2(r[0], r[1]); o.y = pack2(r[2], r[3]);
    o.z = pack2(r[4], r[5]); o.w = pack2(r[6], r[7]);
    Bt[j8 * 16 + nloc] = o;
    __syncthreads();

    // MFMA phase: wave w -> col tiles n0 = 2w, 2w+1
    const int lane = tdx & 63;
    const int wave = tdx >> 6;
    const int m = lane & 15, q = lane >> 4;

    bfrag afr[4];
#pragma unroll
    for (int kt = 0; kt < 4; ++kt)
        afr[kt] = *(const bfrag*)(Bt + (kt * 4 + q) * 16 + m);

    ffrag acc2[2];
#pragma unroll
    for (int t2 = 0; t2 < 2; ++t2) {
#pragma unroll
        for (int t = 0; t < 4; ++t) acc2[t2][t] = 0.f;
        const int n0 = wave * 2 + t2;
#pragma unroll
        for (int kt = 0; kt < 4; ++kt) {
            bfrag bfr = *(const bfrag*)(Wp + ((size_t)(n0 * 4 + kt) * 64 + lane) * 8);
            acc2[t2] = __builtin_amdgcn_mfma_f32_16x16x32_bf16(afr[kt], bfr, acc2[t2], 0, 0, 0);
        }
    }

    const int rowbase = blockIdx.x * 16;
#pragma unroll
    for (int t2 = 0; t2 < 2; ++t2) {
        const int col = (wave * 2 + t2) * 16 + m;
#pragma unroll
        for (int rr = 0; rr < 4; ++rr) {
            const int row = rowbase + q * 4 + rr;
            BW[(size_t)row * 128 + col] = f2bf(acc2[t2][rr]);
        }
    }
}

// ---------------------------------------------------------------------------
// K4: layer-1 gather over BW.  H[n] = bf16( relu( agg*inrm + b_g1 ) )
// ---------------------------------------------------------------------------
__global__ __launch_bounds__(256) void agg1_kernel(
    const uint4* __restrict__ BW,
    const int* __restrict__ bucket, const int2* __restrict__ csrD,
    const float* __restrict__ b_g1,
    uint4* __restrict__ H) {
    int idx = blockIdx.x * blockDim.x + threadIdx.x;
    int n = idx >> 4, j8 = idx & 15;
    const int2 cd = csrD[n];
    const int cnt = cd.y;
    const int* bk = bucket + cd.x;
    float acc[8] = {0.f, 0.f, 0.f, 0.f, 0.f, 0.f, 0.f, 0.f};
    int i = 0;
    GATHER8(BW)
    float inr = onrm_of(cnt);
    const float* bg = b_g1 + j8 * 8;
    float r[8];
#pragma unroll
    for (int k = 0; k < 8; ++k)
        r[k] = fmaxf(acc[k] * inr + bg[k], 0.f);
    uint4 o;
    o.x = pack2(r[0], r[1]); o.y = pack2(r[2], r[3]);
    o.z = pack2(r[4], r[5]); o.w = pack2(r[6], r[7]);
    H[(size_t)n * 16 + j8] = o;
}

// ---------------------------------------------------------------------------
// K5: final edge-typed gather (fwd weighted + bwd) -> fp32 out.
// ---------------------------------------------------------------------------
__global__ __launch_bounds__(256) void final_kernel(
    const uint4* __restrict__ H,
    const int* __restrict__ bucket, const int2* __restrict__ csrD,
    const int* __restrict__ bucketB, const int2* __restrict__ csrB,
    float4* __restrict__ out4) {
    int idx = blockIdx.x * blockDim.x + threadIdx.x;
    int n = idx >> 4, j8 = idx & 15;
    float acc[8] = {0.f, 0.f, 0.f, 0.f, 0.f, 0.f, 0.f, 0.f};
    const int2 cd = csrD[n];
    const int cnt = cd.y;
    const int* bk = bucket + cd.x;
    int i = 0;
    for (; i + 8 <= cnt; i += 8) {
        int4 c0 = *(const int4*)(bk + i);
        int4 c1 = *(const int4*)(bk + i + 4);
        int cc[8] = {c0.x, c0.y, c0.z, c0.w, c1.x, c1.y, c1.z, c1.w};
        uint4 v[8];
#pragma unroll
        for (int k = 0; k < 8; ++k)
            v[k] = H[(size_t)(cc[k] & MASK31) * 16 + j8];
#pragma unroll
        for (int k = 0; k < 8; ++k)
            acc8_addw(acc, v[k], (cc[k] < 0) ? 2.0f : 1.0f);
    }
    if (i + 4 <= cnt) {
        int4 c0 = *(const int4*)(bk + i);
        int cc[4] = {c0.x, c0.y, c0.z, c0.w};
        uint4 v[4];
#pragma unroll
        for (int k = 0; k < 4; ++k)
            v[k] = H[(size_t)(cc[k] & MASK31) * 16 + j8];
#pragma unroll
        for (int k = 0; k < 4; ++k)
            acc8_addw(acc, v[k], (cc[k] < 0) ? 2.0f : 1.0f);
        i += 4;
    }
    for (; i < cnt; ++i) {
        int c = bk[i];
        acc8_addw(acc, H[(size_t)(c & MASK31) * 16 + j8], (c < 0) ? 2.0f : 1.0f);
    }
    const int2 cb = csrB[n];
    const int* bkB = bucketB + cb.x;
    for (int k = 0; k < cb.y; ++k)
        acc8_add(acc, H[(size_t)bkB[k] * 16 + j8]);
    float4 o0 = {acc[0], acc[1], acc[2], acc[3]};
    float4 o1 = {acc[4], acc[5], acc[6], acc[7]};
    out4[(size_t)n * 32 + j8 * 2]     = o0;
    out4[(size_t)n * 32 + j8 * 2 + 1] = o1;
}

extern "C" void kernel_launch(void* const* d_in, const int* in_sizes, int n_in,
                              void* d_out, int out_size, void* d_ws, size_t ws_size,
                              hipStream_t stream) {
    const float* feat[4]  = {(const float*)d_in[0], (const float*)d_in[3],
                             (const float*)d_in[6], (const float*)d_in[9]};
    const float* W_fc[4]  = {(const float*)d_in[1], (const float*)d_in[4],
                             (const float*)d_in[7], (const float*)d_in[10]};
    const float* b_fc[4]  = {(const float*)d_in[2], (const float*)d_in[5],
                             (const float*)d_in[8], (const float*)d_in[11]};
    const int*   src      = (const int*)d_in[12];
    const int*   dst      = (const int*)d_in[13];
    const int*   efeat    = (const int*)d_in[14];
    const float* b_g0     = (const float*)d_in[15];
    const float* W_g1     = (const float*)d_in[16];
    const float* b_g1     = (const float*)d_in[17];
    float* out = (float*)d_out;

    // ---- workspace layout, ~48 MB ----
    char* p = (char*)d_ws;
    unsigned short* Abf = (unsigned short*)p; p += (size_t)N_NODES * HDIM * 2;  // 12.8 MB
    unsigned short* Bbf = (unsigned short*)p; p += (size_t)N_NODES * HDIM * 2;  // 12.8 MB
    unsigned short* Wp  = (unsigned short*)p; p += (size_t)65536 * 2;           // 128 KB
    int* bucket  = (int*)p; p += (size_t)(E_EDGES + 4 * N_NODES) * 4; // 3.2 MB (aligned CSR)
    int* bucketB = (int*)p; p += (size_t)E_EDGES * 4;                 // 2.4 MB
    unsigned* partial = (unsigned*)p; p += (size_t)HQD * N_NODES * 4; // 12.8 MB packed
    int* degD  = (int*)p; p += (size_t)N_NODES * 4;              // 200 KB
    int* degB  = (int*)p; p += (size_t)N_NODES * 4;
    int* scanD = (int*)p; p += (size_t)N_NODES * 4;
    int* scanB = (int*)p; p += (size_t)N_NODES * 4;
    int2* csrD = (int2*)p; p += (size_t)N_NODES * 8;             // 400 KB
    int2* csrB = (int2*)p; p += (size_t)N_NODES * 8;
    float* onrm_buf = (float*)p; p += (size_t)N_NODES * 4;
    int* blocksumD = (int*)p; p += 256 * 4;
    int* blocksumB = (int*)p; p += 256 * 4;

    const unsigned short* Wpg = Wp + 49152;

    // K0: fused packed histogram (one edge pass, 1024 thr) + weight packing
    prep_kernel<<<NBLK_DB + 8, 1024, 0, stream>>>(
        W_fc[0], W_fc[1], W_fc[2], W_fc[3], W_g1, src, dst, efeat,
        Wp, partial);

    // P1: single packed plane pass -> deg/onrm; aligned block scan
    plane_prefix_kernel<<<NBLK_NODE, 256, 0, stream>>>(
        partial, degD, degB, scanD, scanB, blocksumD, blocksumB, onrm_buf);

    // P2: base add -> interleaved CSR descriptors
    base_add_kernel<<<NBLK_NODE, 256, 0, stream>>>(
        blocksumD, blocksumB, scanD, scanB, degD, degB, csrD, csrB);

    // K1: fused counting-sort scatter + 4 FC GEMMs (mem/MFMA overlap)
    scatfc_kernel<<<NBLK_DB + NBLK_FC, 1024, 0, stream>>>(
        src, dst, efeat, partial, csrD, csrB, bucket, bucketB,
        feat[0], feat[1], feat[2], feat[3], Wp,
        b_fc[0], b_fc[1], b_fc[2], b_fc[3], onrm_buf, Abf);

    const int grid_node = (N_NODES * 16) / 256;   // 3125 exact

    // K3: fused layer0 gather + GEMM(W_g1): Abf -> Bbf (BW)
    agg0g_kernel<<<grid_node, 256, 0, stream>>>(
        (const uint4*)Abf, bucket, csrD, onrm_buf, b_g0, Wpg, Bbf);

    // K4: layer1 gather over BW: Bbf -> Abf (H)
    agg1_kernel<<<grid_node, 256, 0, stream>>>(
        (const uint4*)Bbf, bucket, csrD, b_g1, (uint4*)Abf);

    // K5: final edge-typed gather: Abf (H) -> fp32 out
    final_kernel<<<grid_node, 256, 0, stream>>>(
        (const uint4*)Abf, bucket, csrD, bucketB, csrB, (float4*)out);
}